// Round 1
// baseline (2121.915 us; speedup 1.0000x reference)
//
#include <hip/hip_runtime.h>

// ---------------------------------------------------------------------------
// Longformer (2-layer) forward, MI355X. Round 0: correctness-first.
// bf16 MFMA GEMMs (16x16x32), fp32 softmax/LN/residual paths.
// ---------------------------------------------------------------------------

#define Bb 2
#define Ss 4096
#define Dd 768
#define Hh 12
#define Gg 33
#define NSEPn 32
#define Ll 2
#define SPAD 4640   // S + 544 (PADL=256 left, 288 right)
#define PADL 256
#define NCLSn 5

typedef unsigned short u16;
typedef __attribute__((ext_vector_type(8))) short bv8;   // 8 x bf16
typedef __attribute__((ext_vector_type(4))) short sv4;   // 4 x bf16
typedef __attribute__((ext_vector_type(4))) float f32x4;

__device__ __forceinline__ float bf2f(u16 u) {
  unsigned v = ((unsigned)u) << 16;
  return __builtin_bit_cast(float, v);
}
__device__ __forceinline__ u16 f2bf(float f) {
  unsigned u = __builtin_bit_cast(unsigned, f);
  u += 0x7fffu + ((u >> 16) & 1u);
  return (u16)(u >> 16);
}

// ---------------- sep finding --------------------------------------------
__global__ void sep_find_kernel(const int* __restrict__ ids, int* __restrict__ cnt,
                                int* __restrict__ list) {
  int i = blockIdx.x * 256 + threadIdx.x;
  if (i >= Bb * Ss) return;
  int b = i >> 12;
  if (ids[i] == 2) {
    int idx = atomicAdd(&cnt[b], 1);
    if (idx < 64) list[b * 64 + idx] = i & (Ss - 1);
  }
}

__global__ void sep_sort_kernel(const int* __restrict__ cnt, const int* __restrict__ list,
                                int* __restrict__ gpos) {
  int b = blockIdx.x;
  int t = threadIdx.x;
  int n = cnt[b]; if (n > 64) n = 64;
  if (t < Gg) gpos[b * Gg + t] = (t == 0) ? 0 : (Ss - 1);
  __syncthreads();
  if (t < n) {
    int v = list[b * 64 + t];
    int rank = 0;
    for (int j = 0; j < n; ++j) rank += (list[b * 64 + j] < v) ? 1 : 0;
    if (rank < NSEPn) gpos[b * Gg + 1 + rank] = v;
  }
}

// ---------------- weight fp32 (K,N) -> bf16 (N,K) --------------------------
__global__ __launch_bounds__(256)
void wconv_kernel(const float* __restrict__ src, u16* __restrict__ dst, int K, int N) {
  __shared__ float t[32][33];
  int n0 = blockIdx.x * 32, k0 = blockIdx.y * 32;
  int tx = threadIdx.x & 31, ty = threadIdx.x >> 5;  // ty 0..7
  #pragma unroll
  for (int i = 0; i < 4; ++i)
    t[ty + i * 8][tx] = src[(size_t)(k0 + ty + i * 8) * N + n0 + tx];
  __syncthreads();
  #pragma unroll
  for (int i = 0; i < 4; ++i)
    dst[(size_t)(n0 + ty + i * 8) * K + k0 + tx] = f2bf(t[tx][ty + i * 8]);
}

// ---------------- embedding + LN -------------------------------------------
__global__ __launch_bounds__(256)
void embed_ln_kernel(const int* __restrict__ ids, const float* __restrict__ we,
                     const float* __restrict__ pe, const float* __restrict__ te,
                     const float* __restrict__ lnp, float* __restrict__ x,
                     u16* __restrict__ xb) {
  int row = blockIdx.x;
  int s = row & (Ss - 1);
  int id = ids[row];
  int tid = threadIdx.x;
  float v[3]; float sm = 0.f, s2 = 0.f;
  #pragma unroll
  for (int i = 0; i < 3; ++i) {
    int c = tid + i * 256;
    float t = we[(size_t)id * Dd + c] + pe[(size_t)(s + 2) * Dd + c] + te[c];
    v[i] = t; sm += t; s2 += t * t;
  }
  __shared__ float r1[256], r2[256];
  r1[tid] = sm; r2[tid] = s2; __syncthreads();
  for (int o = 128; o; o >>= 1) {
    if (tid < o) { r1[tid] += r1[tid + o]; r2[tid] += r2[tid + o]; }
    __syncthreads();
  }
  float mean = r1[0] * (1.f / 768.f);
  float var  = r2[0] * (1.f / 768.f) - mean * mean;
  float rs = rsqrtf(var + 1e-5f);
  #pragma unroll
  for (int i = 0; i < 3; ++i) {
    int c = tid + i * 256;
    float o = (v[i] - mean) * rs * lnp[c] + lnp[Dd + c];
    x[(size_t)row * Dd + c] = o;
    xb[(size_t)row * Dd + c] = f2bf(o);
  }
}

// ---------------- residual + LN --------------------------------------------
__global__ __launch_bounds__(256)
void add_ln_kernel(const float* __restrict__ xin, const float* __restrict__ y,
                   const float* __restrict__ lnp, float* __restrict__ xout,
                   u16* __restrict__ xbout) {
  int row = blockIdx.x;
  int tid = threadIdx.x;
  float v[3]; float sm = 0.f, s2 = 0.f;
  #pragma unroll
  for (int i = 0; i < 3; ++i) {
    int c = tid + i * 256;
    float t = xin[(size_t)row * Dd + c] + y[(size_t)row * Dd + c];
    v[i] = t; sm += t; s2 += t * t;
  }
  __shared__ float r1[256], r2[256];
  r1[tid] = sm; r2[tid] = s2; __syncthreads();
  for (int o = 128; o; o >>= 1) {
    if (tid < o) { r1[tid] += r1[tid + o]; r2[tid] += r2[tid + o]; }
    __syncthreads();
  }
  float mean = r1[0] * (1.f / 768.f);
  float var  = r2[0] * (1.f / 768.f) - mean * mean;
  float rs = rsqrtf(var + 1e-5f);
  #pragma unroll
  for (int i = 0; i < 3; ++i) {
    int c = tid + i * 256;
    float o = (v[i] - mean) * rs * lnp[c] + lnp[Dd + c];
    xout[(size_t)row * Dd + c] = o;
    xbout[(size_t)row * Dd + c] = f2bf(o);
  }
}

// ---------------- GEMM: C = (A(bf16 MxK) @ Bt(bf16 NxK)^T + bias) * scale ---
// MODE 0: fp32 [M][N]; 1: bf16 [M][N]; 2: bf16 packed [b][h][s][64];
// 3: bf16 packed padded [b][h][PADL+s][64]; 4: bf16 packed-T padded [b][h][64][PADL+s]
#define LDAP 40
template <int MODE, bool GELU_>
__global__ __launch_bounds__(256)
void gemm_kernel(const u16* __restrict__ A, const u16* __restrict__ Bt,
                 const float* __restrict__ bias, float* __restrict__ outf,
                 u16* __restrict__ outb, int M, int N, int K, float scale) {
  __shared__ u16 la[128 * LDAP], lb[128 * LDAP];
  int tid = threadIdx.x;
  int wave = tid >> 6, lane = tid & 63;
  int wr = wave >> 1, wc = wave & 1;
  int lg = lane >> 4, lc = lane & 15;
  int row0 = blockIdx.y * 128, col0 = blockIdx.x * 128;
  f32x4 acc[4][4];
  #pragma unroll
  for (int m = 0; m < 4; ++m)
    #pragma unroll
    for (int n = 0; n < 4; ++n) acc[m][n] = (f32x4){0.f, 0.f, 0.f, 0.f};
  int sr = tid >> 2, sc = tid & 3;

  for (int k0 = 0; k0 < K; k0 += 32) {
    #pragma unroll
    for (int i = 0; i < 2; ++i) {
      int r = sr + 64 * i;
      int gr = row0 + r;
      bv8 va = (bv8)0;
      if (gr < M) va = *reinterpret_cast<const bv8*>(A + (size_t)gr * K + k0 + sc * 8);
      *reinterpret_cast<bv8*>(la + r * LDAP + sc * 8) = va;
      bv8 vb = *reinterpret_cast<const bv8*>(Bt + (size_t)(col0 + r) * K + k0 + sc * 8);
      *reinterpret_cast<bv8*>(lb + r * LDAP + sc * 8) = vb;
    }
    __syncthreads();
    bv8 af[4], bfr[4];
    #pragma unroll
    for (int m = 0; m < 4; ++m)
      af[m] = *reinterpret_cast<const bv8*>(la + (wr * 64 + m * 16 + lc) * LDAP + lg * 8);
    #pragma unroll
    for (int n = 0; n < 4; ++n)
      bfr[n] = *reinterpret_cast<const bv8*>(lb + (wc * 64 + n * 16 + lc) * LDAP + lg * 8);
    #pragma unroll
    for (int m = 0; m < 4; ++m)
      #pragma unroll
      for (int n = 0; n < 4; ++n)
        acc[m][n] = __builtin_amdgcn_mfma_f32_16x16x32_bf16(af[m], bfr[n], acc[m][n], 0, 0, 0);
    __syncthreads();
  }

  #pragma unroll
  for (int m = 0; m < 4; ++m) {
    int grow0 = row0 + wr * 64 + m * 16 + lg * 4;
    #pragma unroll
    for (int n = 0; n < 4; ++n) {
      int gcol = col0 + wc * 64 + n * 16 + lc;
      float bvl = bias[gcol];
      if (MODE == 4) {
        if (grow0 + 3 < M) {
          int bb = grow0 >> 12, s = grow0 & (Ss - 1);
          int hh = gcol >> 6, d = gcol & 63;
          sv4 pk;
          #pragma unroll
          for (int r = 0; r < 4; ++r) {
            float v = (acc[m][n][r] + bvl) * scale;
            pk[r] = (short)f2bf(v);
          }
          *reinterpret_cast<sv4*>(outb + (((size_t)(bb * Hh + hh)) * 64 + d) * SPAD + PADL + s) = pk;
        }
      } else {
        #pragma unroll
        for (int r = 0; r < 4; ++r) {
          int grow = grow0 + r;
          if (grow >= M) continue;
          float v = (acc[m][n][r] + bvl) * scale;
          if (GELU_) v = 0.5f * v * (1.0f + erff(v * 0.70710678118654752f));
          if (MODE == 0) {
            outf[(size_t)grow * N + gcol] = v;
          } else if (MODE == 1) {
            outb[(size_t)grow * N + gcol] = f2bf(v);
          } else {
            int bb = grow >> 12, s = grow & (Ss - 1);
            int hh = gcol >> 6, d = gcol & 63;
            if (MODE == 2)
              outb[(((size_t)(bb * Hh + hh)) * Ss + s) * 64 + d] = f2bf(v);
            else
              outb[(((size_t)(bb * Hh + hh)) * SPAD + PADL + s) * 64 + d] = f2bf(v);
          }
        }
      }
    }
  }
}

// ---------------- gathers ---------------------------------------------------
__global__ __launch_bounds__(256)
void gather_glob_kernel(const u16* __restrict__ kpk, const u16* __restrict__ vtpk,
                        const int* __restrict__ gpos, u16* __restrict__ kg,
                        u16* __restrict__ vgt) {
  int bh = blockIdx.x;
  int b = bh / Hh;
  int tid = threadIdx.x;
  for (int idx = tid; idx < 64 * 64; idx += 256) {
    int g = idx >> 6, d = idx & 63;
    u16 kv = 0, vv = 0;
    if (g < Gg) {
      int p = gpos[b * Gg + g];
      kv = kpk[((size_t)bh * SPAD + PADL + p) * 64 + d];
      vv = vtpk[((size_t)bh * 64 + d) * SPAD + PADL + p];
    }
    kg[(size_t)bh * 4096 + idx] = kv;
    vgt[((size_t)bh * 64 + d) * 64 + g] = vv;
  }
}

__global__ __launch_bounds__(256)
void gather_xg_kernel(const u16* __restrict__ xb, const int* __restrict__ gpos,
                      u16* __restrict__ xg) {
  int rg = blockIdx.x;  // b*G+g
  int b = rg / Gg;
  int p = gpos[rg];
  int tid = threadIdx.x;
  for (int c = tid; c < Dd; c += 256)
    xg[(size_t)rg * Dd + c] = xb[((size_t)b * Ss + p) * Dd + c];
}

// ---------------- local (sliding window + global-key) attention -------------
__global__ __launch_bounds__(64)
void attn_local_kernel(const u16* __restrict__ qpk, const u16* __restrict__ kpk,
                       const u16* __restrict__ vtpk, const u16* __restrict__ kg,
                       const u16* __restrict__ vgt, const int* __restrict__ amask,
                       u16* __restrict__ ctx) {
  __shared__ u16 Plds[16 * 32];
  int blk = blockIdx.x;
  int qt = blk & 255;
  int bh = blk >> 8;
  int b = bh / Hh;
  int h = bh - b * Hh;
  int q0 = qt << 4;
  int lane = threadIdx.x;
  int lg = lane >> 4, lc = lane & 15;

  const u16* qbase = qpk + (((size_t)bh) * Ss + q0) * 64;
  bv8 aq0 = *reinterpret_cast<const bv8*>(qbase + (size_t)lc * 64 + lg * 8);
  bv8 aq1 = *reinterpret_cast<const bv8*>(qbase + (size_t)lc * 64 + 32 + lg * 8);

  f32x4 o[4];
  float mrun[4], lrun[4];
  #pragma unroll
  for (int i = 0; i < 4; ++i) { o[i] = (f32x4){0.f,0.f,0.f,0.f}; mrun[i] = -1e30f; lrun[i] = 0.f; }

  const u16* kgb = kg + ((size_t)bh) * 64 * 64;
  const u16* vgb = vgt + ((size_t)bh) * 64 * 64;
  const u16* kb = kpk + ((size_t)bh) * SPAD * 64;
  const u16* vb = vtpk + ((size_t)bh) * 64 * SPAD;
  const int* amb = amask + b * Ss;

  for (int step = 0; step < 19; ++step) {
    bool isg = (step < 2);
    int ks = isg ? (step * 32) : (q0 - 256 + (step - 2) * 32);
    f32x4 sc0, sc1;
    {
      const u16* kr0 = isg ? (kgb + (size_t)(ks + lc) * 64)
                           : (kb + (size_t)(PADL + ks + lc) * 64);
      const u16* kr1 = kr0 + 16 * 64;
      bv8 b00 = *reinterpret_cast<const bv8*>(kr0 + lg * 8);
      bv8 b01 = *reinterpret_cast<const bv8*>(kr0 + 32 + lg * 8);
      bv8 b10 = *reinterpret_cast<const bv8*>(kr1 + lg * 8);
      bv8 b11 = *reinterpret_cast<const bv8*>(kr1 + 32 + lg * 8);
      f32x4 z = (f32x4){0.f,0.f,0.f,0.f};
      sc0 = __builtin_amdgcn_mfma_f32_16x16x32_bf16(aq0, b00, z, 0, 0, 0);
      sc0 = __builtin_amdgcn_mfma_f32_16x16x32_bf16(aq1, b01, sc0, 0, 0, 0);
      sc1 = __builtin_amdgcn_mfma_f32_16x16x32_bf16(aq0, b10, z, 0, 0, 0);
      sc1 = __builtin_amdgcn_mfma_f32_16x16x32_bf16(aq1, b11, sc1, 0, 0, 0);
    }
    int ka0 = ks + lc, ka1 = ks + 16 + lc;
    bool v0, v1;
    if (isg) {
      v0 = ka0 < Gg; v1 = ka1 < Gg;
    } else {
      v0 = (ka0 >= 0 && ka0 < Ss) ? (amb[ka0] > 0) : false;
      v1 = (ka1 >= 0 && ka1 < Ss) ? (amb[ka1] > 0) : false;
    }
    #pragma unroll
    for (int r = 0; r < 4; ++r) {
      int q = q0 + lg * 4 + r;
      float s0 = sc0[r], s1 = sc1[r];
      bool b0 = v0, b1 = v1;
      if (!isg) {
        b0 = b0 && (ka0 - q >= -256) && (ka0 - q <= 256);
        b1 = b1 && (ka1 - q >= -256) && (ka1 - q <= 256);
      }
      s0 = b0 ? s0 : -1e9f;
      s1 = b1 ? s1 : -1e9f;
      float rm = fmaxf(s0, s1);
      #pragma unroll
      for (int off = 1; off < 16; off <<= 1) rm = fmaxf(rm, __shfl_xor(rm, off));
      float nm = fmaxf(mrun[r], rm);
      float scal = __expf(mrun[r] - nm);
      float p0 = __expf(s0 - nm);
      float p1 = __expf(s1 - nm);
      float ps = p0 + p1;
      #pragma unroll
      for (int off = 1; off < 16; off <<= 1) ps += __shfl_xor(ps, off);
      lrun[r] = lrun[r] * scal + ps;
      mrun[r] = nm;
      #pragma unroll
      for (int nt = 0; nt < 4; ++nt) o[nt][r] *= scal;
      int prow = lg * 4 + r;
      Plds[prow * 32 + lc] = f2bf(p0);
      Plds[prow * 32 + 16 + lc] = f2bf(p1);
    }
    bv8 ap = *reinterpret_cast<const bv8*>(Plds + lc * 32 + lg * 8);
    #pragma unroll
    for (int nt = 0; nt < 4; ++nt) {
      const u16* vr = isg ? (vgb + (size_t)(nt * 16 + lc) * 64 + ks)
                          : (vb + (size_t)(nt * 16 + lc) * SPAD + PADL + ks);
      bv8 bvv = *reinterpret_cast<const bv8*>(vr + lg * 8);
      o[nt] = __builtin_amdgcn_mfma_f32_16x16x32_bf16(ap, bvv, o[nt], 0, 0, 0);
    }
  }
  #pragma unroll
  for (int r = 0; r < 4; ++r) {
    float inv = 1.0f / lrun[r];
    size_t rowoff = ((size_t)b * Ss + q0 + lg * 4 + r) * Dd + h * 64;
    #pragma unroll
    for (int nt = 0; nt < 4; ++nt)
      ctx[rowoff + nt * 16 + lc] = f2bf(o[nt][r] * inv);
  }
}

// ---------------- global-query attention ------------------------------------
__global__ __launch_bounds__(256)
void attn_global_kernel(const float* __restrict__ qg, const u16* __restrict__ kgf,
                        const u16* __restrict__ vgf, const int* __restrict__ amask,
                        const int* __restrict__ gpos, u16* __restrict__ ctx) {
  __shared__ float qs[64];
  __shared__ float sarr[Ss];
  __shared__ float red[256];
  int blk = blockIdx.x;
  int g = blk % Gg;
  int bh = blk / Gg;
  int b = bh / Hh, h = bh % Hh;
  int tid = threadIdx.x;
  if (tid < 64) qs[tid] = qg[((size_t)b * Gg + g) * Dd + h * 64 + tid];
  __syncthreads();
  const u16* kb = kgf + ((size_t)bh) * Ss * 64;
  const u16* vb = vgf + ((size_t)bh) * Ss * 64;
  float lmax = -1e30f;
  for (int i = 0; i < Ss / 256; ++i) {
    int s = tid + i * 256;
    const u16* kr = kb + (size_t)s * 64;
    float acc = 0.f;
    #pragma unroll
    for (int j = 0; j < 8; ++j) {
      bv8 kv = *reinterpret_cast<const bv8*>(kr + j * 8);
      #pragma unroll
      for (int e = 0; e < 8; ++e) acc += qs[j * 8 + e] * bf2f((u16)kv[e]);
    }
    acc = (amask[b * Ss + s] > 0) ? acc : -1e9f;
    sarr[s] = acc;
    lmax = fmaxf(lmax, acc);
  }
  red[tid] = lmax; __syncthreads();
  for (int o = 128; o; o >>= 1) {
    if (tid < o) red[tid] = fmaxf(red[tid], red[tid + o]);
    __syncthreads();
  }
  float mx = red[0]; __syncthreads();
  float lp = 0.f;
  for (int i = 0; i < Ss / 256; ++i) {
    int s = tid + i * 256;
    float p = __expf(sarr[s] - mx);
    sarr[s] = p; lp += p;
  }
  red[tid] = lp; __syncthreads();
  for (int o = 128; o; o >>= 1) {
    if (tid < o) red[tid] += red[tid + o];
    __syncthreads();
  }
  float denom = red[0]; __syncthreads();
  int wave = tid >> 6, lane = tid & 63;
  float acc = 0.f;
  for (int s = wave; s < Ss; s += 4)
    acc += sarr[s] * bf2f(vb[(size_t)s * 64 + lane]);
  red[tid] = acc; __syncthreads();
  if (tid < 64) {
    float ov = (red[tid] + red[tid + 64] + red[tid + 128] + red[tid + 192]) / denom;
    int pos = gpos[b * Gg + g];
    ctx[((size_t)b * Ss + pos) * Dd + h * 64 + tid] = f2bf(ov);
  }
}

// ---------------- classifier ------------------------------------------------
__global__ __launch_bounds__(64)
void cls_kernel(const float* __restrict__ x, const float* __restrict__ W,
                const float* __restrict__ bias, const int* __restrict__ gpos,
                float* __restrict__ out) {
  int r = blockIdx.x;  // b*32 + i
  int b = r >> 5, i = r & 31;
  int pos = gpos[b * Gg + 1 + i];
  int lane = threadIdx.x;
  const float* xr = x + ((size_t)b * Ss + pos) * Dd;
  float acc[NCLSn] = {0.f, 0.f, 0.f, 0.f, 0.f};
  for (int k = lane; k < Dd; k += 64) {
    float xv = xr[k];
    #pragma unroll
    for (int c = 0; c < NCLSn; ++c) acc[c] += xv * W[c * Dd + k];
  }
  #pragma unroll
  for (int c = 0; c < NCLSn; ++c) {
    #pragma unroll
    for (int off = 1; off < 64; off <<= 1) acc[c] += __shfl_xor(acc[c], off);
  }
  if (lane == 0) {
    #pragma unroll
    for (int c = 0; c < NCLSn; ++c) out[r * NCLSn + c] = acc[c] + bias[c];
  }
}

// ---------------------------------------------------------------------------
extern "C" void kernel_launch(void* const* d_in, const int* in_sizes, int n_in,
                              void* d_out, int out_size, void* d_ws, size_t ws_size,
                              hipStream_t stream) {
  const int* ids     = (const int*)d_in[0];
  const int* amask   = (const int*)d_in[1];
  const float* we    = (const float*)d_in[2];
  const float* pe    = (const float*)d_in[3];
  const float* te    = (const float*)d_in[4];
  const float* embln = (const float*)d_in[5];
  const float* Wqkv  = (const float*)d_in[6];
  const float* bqkv  = (const float*)d_in[7];
  const float* Wqkvg = (const float*)d_in[8];
  const float* bqkvg = (const float*)d_in[9];
  const float* Wo    = (const float*)d_in[10];
  const float* bo    = (const float*)d_in[11];
  const float* ln1   = (const float*)d_in[12];
  const float* Wff1  = (const float*)d_in[13];
  const float* bff1  = (const float*)d_in[14];
  const float* Wff2  = (const float*)d_in[15];
  const float* bff2  = (const float*)d_in[16];
  const float* ln2   = (const float*)d_in[17];
  const float* clsW  = (const float*)d_in[18];
  const float* clsb  = (const float*)d_in[19];
  float* out = (float*)d_out;

  char* ws = (char*)d_ws;
  size_t off = 0;
  auto alloc = [&](size_t bytes) { size_t o = off; off += (bytes + 255) & ~(size_t)255; return o; };

  const size_t DD = (size_t)Dd * Dd;        // 589824
  const size_t DF = (size_t)Dd * 4 * Dd;    // 2359296
  const size_t WL = 7 * DD + 2 * DF;        // elems per layer

  size_t o_cnt  = alloc(Bb * 4);
  size_t o_list = alloc(Bb * 64 * 4);
  size_t o_gpos = alloc(Bb * Gg * 4);
  size_t o_w    = alloc(WL * Ll * 2);
  size_t o_x    = alloc((size_t)Bb * Ss * Dd * 4);
  size_t o_xb   = alloc((size_t)Bb * Ss * Dd * 2);
  size_t o_qpk  = alloc((size_t)Bb * Hh * Ss * 64 * 2);
  size_t o_kpk  = alloc((size_t)Bb * Hh * SPAD * 64 * 2);
  size_t o_vtpk = alloc((size_t)Bb * Hh * 64 * SPAD * 2);
  size_t o_kg   = alloc((size_t)Bb * Hh * 64 * 64 * 2);
  size_t o_vgt  = alloc((size_t)Bb * Hh * 64 * 64 * 2);
  size_t o_xg   = alloc((size_t)128 * Dd * 2);
  size_t o_qg   = alloc((size_t)128 * Dd * 4);
  size_t o_kgf  = alloc((size_t)Bb * Hh * Ss * 64 * 2);
  size_t o_vgf  = alloc((size_t)Bb * Hh * Ss * 64 * 2);
  size_t o_f1b  = o_qpk;  // FFN hidden aliases the (dead-by-then) attention buffers
  {
    size_t f1b_bytes = (size_t)Bb * Ss * 4 * Dd * 2;
    if (off - o_qpk < f1b_bytes) off = o_qpk + ((f1b_bytes + 255) & ~(size_t)255);
  }
  size_t o_ctx = alloc((size_t)Bb * Ss * Dd * 2);
  size_t o_acc = alloc((size_t)Bb * Ss * Dd * 4);
  if (ws_size < off) return;  // workspace too small -> fail visibly

  u16* Wb = (u16*)(ws + o_w);
  int* gposp = (int*)(ws + o_gpos);

  (void)hipMemsetAsync(ws + o_cnt, 0, Bb * 4, stream);
  // zero padded K / V^T so first-call pads are finite (later calls: finite stale bf16)
  (void)hipMemsetAsync(ws + o_kpk, 0, (size_t)Bb * Hh * SPAD * 64 * 2, stream);
  (void)hipMemsetAsync(ws + o_vtpk, 0, (size_t)Bb * Hh * 64 * SPAD * 2, stream);

  sep_find_kernel<<<(Bb * Ss + 255) / 256, 256, 0, stream>>>(ids, (int*)(ws + o_cnt), (int*)(ws + o_list));
  sep_sort_kernel<<<Bb, 64, 0, stream>>>((int*)(ws + o_cnt), (int*)(ws + o_list), gposp);

  // weight conversions
  for (int l = 0; l < Ll; ++l) {
    size_t wb = (size_t)l * WL;
    for (int i = 0; i < 3; ++i)
      wconv_kernel<<<dim3(Dd / 32, Dd / 32), 256, 0, stream>>>(Wqkv + ((size_t)l * 3 + i) * DD, Wb + wb + i * DD, Dd, Dd);
    for (int i = 0; i < 3; ++i)
      wconv_kernel<<<dim3(Dd / 32, Dd / 32), 256, 0, stream>>>(Wqkvg + ((size_t)l * 3 + i) * DD, Wb + wb + (3 + i) * DD, Dd, Dd);
    wconv_kernel<<<dim3(Dd / 32, Dd / 32), 256, 0, stream>>>(Wo + (size_t)l * DD, Wb + wb + 6 * DD, Dd, Dd);
    wconv_kernel<<<dim3(4 * Dd / 32, Dd / 32), 256, 0, stream>>>(Wff1 + (size_t)l * DF, Wb + wb + 7 * DD, Dd, 4 * Dd);
    wconv_kernel<<<dim3(Dd / 32, 4 * Dd / 32), 256, 0, stream>>>(Wff2 + (size_t)l * DF, Wb + wb + 7 * DD + DF, 4 * Dd, Dd);
  }

  embed_ln_kernel<<<Bb * Ss, 256, 0, stream>>>(ids, we, pe, te, embln, (float*)(ws + o_x), (u16*)(ws + o_xb));

  for (int l = 0; l < Ll; ++l) {
    size_t wb = (size_t)l * WL;
    u16* xb = (u16*)(ws + o_xb);
    // Q/K/V projections
    gemm_kernel<2, false><<<dim3(6, 64), 256, 0, stream>>>(xb, Wb + wb + 0 * DD, bqkv + (size_t)(l * 3 + 0) * Dd, nullptr, (u16*)(ws + o_qpk), Bb * Ss, Dd, Dd, 0.125f);
    gemm_kernel<3, false><<<dim3(6, 64), 256, 0, stream>>>(xb, Wb + wb + 1 * DD, bqkv + (size_t)(l * 3 + 1) * Dd, nullptr, (u16*)(ws + o_kpk), Bb * Ss, Dd, Dd, 1.0f);
    gemm_kernel<4, false><<<dim3(6, 64), 256, 0, stream>>>(xb, Wb + wb + 2 * DD, bqkv + (size_t)(l * 3 + 2) * Dd, nullptr, (u16*)(ws + o_vtpk), Bb * Ss, Dd, Dd, 1.0f);
    gather_glob_kernel<<<Bb * Hh, 256, 0, stream>>>((u16*)(ws + o_kpk), (u16*)(ws + o_vtpk), gposp, (u16*)(ws + o_kg), (u16*)(ws + o_vgt));
    gather_xg_kernel<<<Bb * Gg, 256, 0, stream>>>(xb, gposp, (u16*)(ws + o_xg));
    // global projections
    gemm_kernel<0, false><<<dim3(6, 1), 256, 0, stream>>>((u16*)(ws + o_xg), Wb + wb + 3 * DD, bqkvg + (size_t)(l * 3 + 0) * Dd, (float*)(ws + o_qg), nullptr, Bb * Gg, Dd, Dd, 0.125f);
    gemm_kernel<2, false><<<dim3(6, 64), 256, 0, stream>>>(xb, Wb + wb + 4 * DD, bqkvg + (size_t)(l * 3 + 1) * Dd, nullptr, (u16*)(ws + o_kgf), Bb * Ss, Dd, Dd, 1.0f);
    gemm_kernel<2, false><<<dim3(6, 64), 256, 0, stream>>>(xb, Wb + wb + 5 * DD, bqkvg + (size_t)(l * 3 + 2) * Dd, nullptr, (u16*)(ws + o_vgf), Bb * Ss, Dd, Dd, 1.0f);
    // attention
    attn_local_kernel<<<Bb * Hh * (Ss / 16), 64, 0, stream>>>((u16*)(ws + o_qpk), (u16*)(ws + o_kpk), (u16*)(ws + o_vtpk), (u16*)(ws + o_kg), (u16*)(ws + o_vgt), amask, (u16*)(ws + o_ctx));
    attn_global_kernel<<<Bb * Hh * Gg, 256, 0, stream>>>((float*)(ws + o_qg), (u16*)(ws + o_kgf), (u16*)(ws + o_vgf), amask, gposp, (u16*)(ws + o_ctx));
    // output projection + LN
    gemm_kernel<0, false><<<dim3(6, 64), 256, 0, stream>>>((u16*)(ws + o_ctx), Wb + wb + 6 * DD, bo + (size_t)l * Dd, (float*)(ws + o_acc), nullptr, Bb * Ss, Dd, Dd, 1.0f);
    add_ln_kernel<<<Bb * Ss, 256, 0, stream>>>((float*)(ws + o_x), (float*)(ws + o_acc), ln1 + (size_t)l * 2 * Dd, (float*)(ws + o_x), xb);
    // FFN
    gemm_kernel<1, true><<<dim3(24, 64), 256, 0, stream>>>(xb, Wb + wb + 7 * DD, bff1 + (size_t)l * 4 * Dd, nullptr, (u16*)(ws + o_f1b), Bb * Ss, 4 * Dd, Dd, 1.0f);
    gemm_kernel<0, false><<<dim3(6, 64), 256, 0, stream>>>((u16*)(ws + o_f1b), Wb + wb + 7 * DD + DF, bff2 + (size_t)l * Dd, (float*)(ws + o_acc), nullptr, Bb * Ss, Dd, 4 * Dd, 1.0f);
    add_ln_kernel<<<Bb * Ss, 256, 0, stream>>>((float*)(ws + o_x), (float*)(ws + o_acc), ln2 + (size_t)l * 2 * Dd, (float*)(ws + o_x), xb);
  }

  cls_kernel<<<Bb * NSEPn, 64, 0, stream>>>((float*)(ws + o_x), clsW, clsb, gposp, out);
}

// Round 2
// 1442.281 us; speedup vs baseline: 1.4712x; 1.4712x over previous
//
#include <hip/hip_runtime.h>

// ---------------------------------------------------------------------------
// Longformer (2-layer) forward, MI355X.
// R1: global-query attention rewritten as chunked flash-MFMA + merge.
// ---------------------------------------------------------------------------

#define Bb 2
#define Ss 4096
#define Dd 768
#define Hh 12
#define Gg 33
#define NSEPn 32
#define Ll 2
#define SPAD 4640   // S + 544 (PADL=256 left, 288 right)
#define PADL 256
#define NCLSn 5
#define NCH 16      // key chunks for global-q attention (256 keys each)
#define PARTF 1056  // floats per (bh,qt,chunk) partial: 16*64 o + 16 m + 16 l

typedef unsigned short u16;
typedef __attribute__((ext_vector_type(8))) short bv8;   // 8 x bf16
typedef __attribute__((ext_vector_type(4))) short sv4;   // 4 x bf16
typedef __attribute__((ext_vector_type(4))) float f32x4;

__device__ __forceinline__ float bf2f(u16 u) {
  unsigned v = ((unsigned)u) << 16;
  return __builtin_bit_cast(float, v);
}
__device__ __forceinline__ u16 f2bf(float f) {
  unsigned u = __builtin_bit_cast(unsigned, f);
  u += 0x7fffu + ((u >> 16) & 1u);
  return (u16)(u >> 16);
}

// ---------------- sep finding --------------------------------------------
__global__ void sep_find_kernel(const int* __restrict__ ids, int* __restrict__ cnt,
                                int* __restrict__ list) {
  int i = blockIdx.x * 256 + threadIdx.x;
  if (i >= Bb * Ss) return;
  int b = i >> 12;
  if (ids[i] == 2) {
    int idx = atomicAdd(&cnt[b], 1);
    if (idx < 64) list[b * 64 + idx] = i & (Ss - 1);
  }
}

__global__ void sep_sort_kernel(const int* __restrict__ cnt, const int* __restrict__ list,
                                int* __restrict__ gpos) {
  int b = blockIdx.x;
  int t = threadIdx.x;
  int n = cnt[b]; if (n > 64) n = 64;
  if (t < Gg) gpos[b * Gg + t] = (t == 0) ? 0 : (Ss - 1);
  __syncthreads();
  if (t < n) {
    int v = list[b * 64 + t];
    int rank = 0;
    for (int j = 0; j < n; ++j) rank += (list[b * 64 + j] < v) ? 1 : 0;
    if (rank < NSEPn) gpos[b * Gg + 1 + rank] = v;
  }
}

// ---------------- weight fp32 (K,N) -> bf16 (N,K) --------------------------
__global__ __launch_bounds__(256)
void wconv_kernel(const float* __restrict__ src, u16* __restrict__ dst, int K, int N) {
  __shared__ float t[32][33];
  int n0 = blockIdx.x * 32, k0 = blockIdx.y * 32;
  int tx = threadIdx.x & 31, ty = threadIdx.x >> 5;  // ty 0..7
  #pragma unroll
  for (int i = 0; i < 4; ++i)
    t[ty + i * 8][tx] = src[(size_t)(k0 + ty + i * 8) * N + n0 + tx];
  __syncthreads();
  #pragma unroll
  for (int i = 0; i < 4; ++i)
    dst[(size_t)(n0 + ty + i * 8) * K + k0 + tx] = f2bf(t[tx][ty + i * 8]);
}

// ---------------- embedding + LN -------------------------------------------
__global__ __launch_bounds__(256)
void embed_ln_kernel(const int* __restrict__ ids, const float* __restrict__ we,
                     const float* __restrict__ pe, const float* __restrict__ te,
                     const float* __restrict__ lnp, float* __restrict__ x,
                     u16* __restrict__ xb) {
  int row = blockIdx.x;
  int s = row & (Ss - 1);
  int id = ids[row];
  int tid = threadIdx.x;
  float v[3]; float sm = 0.f, s2 = 0.f;
  #pragma unroll
  for (int i = 0; i < 3; ++i) {
    int c = tid + i * 256;
    float t = we[(size_t)id * Dd + c] + pe[(size_t)(s + 2) * Dd + c] + te[c];
    v[i] = t; sm += t; s2 += t * t;
  }
  __shared__ float r1[256], r2[256];
  r1[tid] = sm; r2[tid] = s2; __syncthreads();
  for (int o = 128; o; o >>= 1) {
    if (tid < o) { r1[tid] += r1[tid + o]; r2[tid] += r2[tid + o]; }
    __syncthreads();
  }
  float mean = r1[0] * (1.f / 768.f);
  float var  = r2[0] * (1.f / 768.f) - mean * mean;
  float rs = rsqrtf(var + 1e-5f);
  #pragma unroll
  for (int i = 0; i < 3; ++i) {
    int c = tid + i * 256;
    float o = (v[i] - mean) * rs * lnp[c] + lnp[Dd + c];
    x[(size_t)row * Dd + c] = o;
    xb[(size_t)row * Dd + c] = f2bf(o);
  }
}

// ---------------- residual + LN --------------------------------------------
__global__ __launch_bounds__(256)
void add_ln_kernel(const float* __restrict__ xin, const float* __restrict__ y,
                   const float* __restrict__ lnp, float* __restrict__ xout,
                   u16* __restrict__ xbout) {
  int row = blockIdx.x;
  int tid = threadIdx.x;
  float v[3]; float sm = 0.f, s2 = 0.f;
  #pragma unroll
  for (int i = 0; i < 3; ++i) {
    int c = tid + i * 256;
    float t = xin[(size_t)row * Dd + c] + y[(size_t)row * Dd + c];
    v[i] = t; sm += t; s2 += t * t;
  }
  __shared__ float r1[256], r2[256];
  r1[tid] = sm; r2[tid] = s2; __syncthreads();
  for (int o = 128; o; o >>= 1) {
    if (tid < o) { r1[tid] += r1[tid + o]; r2[tid] += r2[tid + o]; }
    __syncthreads();
  }
  float mean = r1[0] * (1.f / 768.f);
  float var  = r2[0] * (1.f / 768.f) - mean * mean;
  float rs = rsqrtf(var + 1e-5f);
  #pragma unroll
  for (int i = 0; i < 3; ++i) {
    int c = tid + i * 256;
    float o = (v[i] - mean) * rs * lnp[c] + lnp[Dd + c];
    xout[(size_t)row * Dd + c] = o;
    xbout[(size_t)row * Dd + c] = f2bf(o);
  }
}

// ---------------- GEMM: C = (A(bf16 MxK) @ Bt(bf16 NxK)^T + bias) * scale ---
// MODE 0: fp32 [M][N]; 1: bf16 [M][N]; 2: bf16 packed [b][h][s][64];
// 3: bf16 packed padded [b][h][PADL+s][64]; 4: bf16 packed-T padded [b][h][64][PADL+s]
// 5: bf16 packed-T non-padded [b][h][64][Ss]
#define LDAP 40
template <int MODE, bool GELU_>
__global__ __launch_bounds__(256)
void gemm_kernel(const u16* __restrict__ A, const u16* __restrict__ Bt,
                 const float* __restrict__ bias, float* __restrict__ outf,
                 u16* __restrict__ outb, int M, int N, int K, float scale) {
  __shared__ u16 la[128 * LDAP], lb[128 * LDAP];
  int tid = threadIdx.x;
  int wave = tid >> 6, lane = tid & 63;
  int wr = wave >> 1, wc = wave & 1;
  int lg = lane >> 4, lc = lane & 15;
  int row0 = blockIdx.y * 128, col0 = blockIdx.x * 128;
  f32x4 acc[4][4];
  #pragma unroll
  for (int m = 0; m < 4; ++m)
    #pragma unroll
    for (int n = 0; n < 4; ++n) acc[m][n] = (f32x4){0.f, 0.f, 0.f, 0.f};
  int sr = tid >> 2, sc = tid & 3;

  for (int k0 = 0; k0 < K; k0 += 32) {
    #pragma unroll
    for (int i = 0; i < 2; ++i) {
      int r = sr + 64 * i;
      int gr = row0 + r;
      bv8 va = (bv8)0;
      if (gr < M) va = *reinterpret_cast<const bv8*>(A + (size_t)gr * K + k0 + sc * 8);
      *reinterpret_cast<bv8*>(la + r * LDAP + sc * 8) = va;
      bv8 vb = *reinterpret_cast<const bv8*>(Bt + (size_t)(col0 + r) * K + k0 + sc * 8);
      *reinterpret_cast<bv8*>(lb + r * LDAP + sc * 8) = vb;
    }
    __syncthreads();
    bv8 af[4], bfr[4];
    #pragma unroll
    for (int m = 0; m < 4; ++m)
      af[m] = *reinterpret_cast<const bv8*>(la + (wr * 64 + m * 16 + lc) * LDAP + lg * 8);
    #pragma unroll
    for (int n = 0; n < 4; ++n)
      bfr[n] = *reinterpret_cast<const bv8*>(lb + (wc * 64 + n * 16 + lc) * LDAP + lg * 8);
    #pragma unroll
    for (int m = 0; m < 4; ++m)
      #pragma unroll
      for (int n = 0; n < 4; ++n)
        acc[m][n] = __builtin_amdgcn_mfma_f32_16x16x32_bf16(af[m], bfr[n], acc[m][n], 0, 0, 0);
    __syncthreads();
  }

  #pragma unroll
  for (int m = 0; m < 4; ++m) {
    int grow0 = row0 + wr * 64 + m * 16 + lg * 4;
    #pragma unroll
    for (int n = 0; n < 4; ++n) {
      int gcol = col0 + wc * 64 + n * 16 + lc;
      float bvl = bias[gcol];
      if (MODE == 4 || MODE == 5) {
        if (grow0 + 3 < M) {
          int bb = grow0 >> 12, s = grow0 & (Ss - 1);
          int hh = gcol >> 6, d = gcol & 63;
          sv4 pk;
          #pragma unroll
          for (int r = 0; r < 4; ++r) {
            float v = (acc[m][n][r] + bvl) * scale;
            pk[r] = (short)f2bf(v);
          }
          if (MODE == 4)
            *reinterpret_cast<sv4*>(outb + (((size_t)(bb * Hh + hh)) * 64 + d) * SPAD + PADL + s) = pk;
          else
            *reinterpret_cast<sv4*>(outb + (((size_t)(bb * Hh + hh)) * 64 + d) * Ss + s) = pk;
        }
      } else {
        #pragma unroll
        for (int r = 0; r < 4; ++r) {
          int grow = grow0 + r;
          if (grow >= M) continue;
          float v = (acc[m][n][r] + bvl) * scale;
          if (GELU_) v = 0.5f * v * (1.0f + erff(v * 0.70710678118654752f));
          if (MODE == 0) {
            outf[(size_t)grow * N + gcol] = v;
          } else if (MODE == 1) {
            outb[(size_t)grow * N + gcol] = f2bf(v);
          } else {
            int bb = grow >> 12, s = grow & (Ss - 1);
            int hh = gcol >> 6, d = gcol & 63;
            if (MODE == 2)
              outb[(((size_t)(bb * Hh + hh)) * Ss + s) * 64 + d] = f2bf(v);
            else
              outb[(((size_t)(bb * Hh + hh)) * SPAD + PADL + s) * 64 + d] = f2bf(v);
          }
        }
      }
    }
  }
}

// ---------------- gathers ---------------------------------------------------
__global__ __launch_bounds__(256)
void gather_glob_kernel(const u16* __restrict__ kpk, const u16* __restrict__ vtpk,
                        const int* __restrict__ gpos, u16* __restrict__ kg,
                        u16* __restrict__ vgt) {
  int bh = blockIdx.x;
  int b = bh / Hh;
  int tid = threadIdx.x;
  for (int idx = tid; idx < 64 * 64; idx += 256) {
    int g = idx >> 6, d = idx & 63;
    u16 kv = 0, vv = 0;
    if (g < Gg) {
      int p = gpos[b * Gg + g];
      kv = kpk[((size_t)bh * SPAD + PADL + p) * 64 + d];
      vv = vtpk[((size_t)bh * 64 + d) * SPAD + PADL + p];
    }
    kg[(size_t)bh * 4096 + idx] = kv;
    vgt[((size_t)bh * 64 + d) * 64 + g] = vv;
  }
}

__global__ __launch_bounds__(256)
void gather_xg_kernel(const u16* __restrict__ xb, const int* __restrict__ gpos,
                      u16* __restrict__ xg) {
  int rg = blockIdx.x;  // b*G+g
  int b = rg / Gg;
  int p = gpos[rg];
  int tid = threadIdx.x;
  for (int c = tid; c < Dd; c += 256)
    xg[(size_t)rg * Dd + c] = xb[((size_t)b * Ss + p) * Dd + c];
}

// ---------------- local (sliding window + global-key) attention -------------
__global__ __launch_bounds__(64)
void attn_local_kernel(const u16* __restrict__ qpk, const u16* __restrict__ kpk,
                       const u16* __restrict__ vtpk, const u16* __restrict__ kg,
                       const u16* __restrict__ vgt, const int* __restrict__ amask,
                       u16* __restrict__ ctx) {
  __shared__ u16 Plds[16 * 32];
  int blk = blockIdx.x;
  int qt = blk & 255;
  int bh = blk >> 8;
  int b = bh / Hh;
  int h = bh - b * Hh;
  int q0 = qt << 4;
  int lane = threadIdx.x;
  int lg = lane >> 4, lc = lane & 15;

  const u16* qbase = qpk + (((size_t)bh) * Ss + q0) * 64;
  bv8 aq0 = *reinterpret_cast<const bv8*>(qbase + (size_t)lc * 64 + lg * 8);
  bv8 aq1 = *reinterpret_cast<const bv8*>(qbase + (size_t)lc * 64 + 32 + lg * 8);

  f32x4 o[4];
  float mrun[4], lrun[4];
  #pragma unroll
  for (int i = 0; i < 4; ++i) { o[i] = (f32x4){0.f,0.f,0.f,0.f}; mrun[i] = -1e30f; lrun[i] = 0.f; }

  const u16* kgb = kg + ((size_t)bh) * 64 * 64;
  const u16* vgb = vgt + ((size_t)bh) * 64 * 64;
  const u16* kb = kpk + ((size_t)bh) * SPAD * 64;
  const u16* vb = vtpk + ((size_t)bh) * 64 * SPAD;
  const int* amb = amask + b * Ss;

  for (int step = 0; step < 19; ++step) {
    bool isg = (step < 2);
    int ks = isg ? (step * 32) : (q0 - 256 + (step - 2) * 32);
    f32x4 sc0, sc1;
    {
      const u16* kr0 = isg ? (kgb + (size_t)(ks + lc) * 64)
                           : (kb + (size_t)(PADL + ks + lc) * 64);
      const u16* kr1 = kr0 + 16 * 64;
      bv8 b00 = *reinterpret_cast<const bv8*>(kr0 + lg * 8);
      bv8 b01 = *reinterpret_cast<const bv8*>(kr0 + 32 + lg * 8);
      bv8 b10 = *reinterpret_cast<const bv8*>(kr1 + lg * 8);
      bv8 b11 = *reinterpret_cast<const bv8*>(kr1 + 32 + lg * 8);
      f32x4 z = (f32x4){0.f,0.f,0.f,0.f};
      sc0 = __builtin_amdgcn_mfma_f32_16x16x32_bf16(aq0, b00, z, 0, 0, 0);
      sc0 = __builtin_amdgcn_mfma_f32_16x16x32_bf16(aq1, b01, sc0, 0, 0, 0);
      sc1 = __builtin_amdgcn_mfma_f32_16x16x32_bf16(aq0, b10, z, 0, 0, 0);
      sc1 = __builtin_amdgcn_mfma_f32_16x16x32_bf16(aq1, b11, sc1, 0, 0, 0);
    }
    int ka0 = ks + lc, ka1 = ks + 16 + lc;
    bool v0, v1;
    if (isg) {
      v0 = ka0 < Gg; v1 = ka1 < Gg;
    } else {
      v0 = (ka0 >= 0 && ka0 < Ss) ? (amb[ka0] > 0) : false;
      v1 = (ka1 >= 0 && ka1 < Ss) ? (amb[ka1] > 0) : false;
    }
    #pragma unroll
    for (int r = 0; r < 4; ++r) {
      int q = q0 + lg * 4 + r;
      float s0 = sc0[r], s1 = sc1[r];
      bool b0 = v0, b1 = v1;
      if (!isg) {
        b0 = b0 && (ka0 - q >= -256) && (ka0 - q <= 256);
        b1 = b1 && (ka1 - q >= -256) && (ka1 - q <= 256);
      }
      s0 = b0 ? s0 : -1e9f;
      s1 = b1 ? s1 : -1e9f;
      float rm = fmaxf(s0, s1);
      #pragma unroll
      for (int off = 1; off < 16; off <<= 1) rm = fmaxf(rm, __shfl_xor(rm, off));
      float nm = fmaxf(mrun[r], rm);
      float scal = __expf(mrun[r] - nm);
      float p0 = __expf(s0 - nm);
      float p1 = __expf(s1 - nm);
      float ps = p0 + p1;
      #pragma unroll
      for (int off = 1; off < 16; off <<= 1) ps += __shfl_xor(ps, off);
      lrun[r] = lrun[r] * scal + ps;
      mrun[r] = nm;
      #pragma unroll
      for (int nt = 0; nt < 4; ++nt) o[nt][r] *= scal;
      int prow = lg * 4 + r;
      Plds[prow * 32 + lc] = f2bf(p0);
      Plds[prow * 32 + 16 + lc] = f2bf(p1);
    }
    bv8 ap = *reinterpret_cast<const bv8*>(Plds + lc * 32 + lg * 8);
    #pragma unroll
    for (int nt = 0; nt < 4; ++nt) {
      const u16* vr = isg ? (vgb + (size_t)(nt * 16 + lc) * 64 + ks)
                          : (vb + (size_t)(nt * 16 + lc) * SPAD + PADL + ks);
      bv8 bvv = *reinterpret_cast<const bv8*>(vr + lg * 8);
      o[nt] = __builtin_amdgcn_mfma_f32_16x16x32_bf16(ap, bvv, o[nt], 0, 0, 0);
    }
  }
  #pragma unroll
  for (int r = 0; r < 4; ++r) {
    float inv = 1.0f / lrun[r];
    size_t rowoff = ((size_t)b * Ss + q0 + lg * 4 + r) * Dd + h * 64;
    #pragma unroll
    for (int nt = 0; nt < 4; ++nt)
      ctx[rowoff + nt * 16 + lc] = f2bf(o[nt][r] * inv);
  }
}

// ---------------- global-query attention: chunked flash MFMA ----------------
// grid: bh * NCH; block 192 (3 waves, one 16-q-row tile each; rows>=33 padded)
__global__ __launch_bounds__(192)
void attn_globalq_kernel(const u16* __restrict__ qgb, const u16* __restrict__ kgf,
                         const u16* __restrict__ vgt, const int* __restrict__ amask,
                         float* __restrict__ part) {
  __shared__ u16 Plds[3][16 * 32];
  int blk = blockIdx.x;
  int ch = blk & (NCH - 1);
  int bh = blk / NCH;
  int b = bh / Hh, h = bh - b * Hh;
  int wv = threadIdx.x >> 6;  // q-tile 0..2
  int lane = threadIdx.x & 63;
  int lg = lane >> 4, lc = lane & 15;

  int qrow = wv * 16 + lc;
  bv8 aq0 = (bv8)0, aq1 = (bv8)0;
  if (qrow < Gg) {
    const u16* qr = qgb + (size_t)(b * Gg + qrow) * Dd + h * 64;
    aq0 = *reinterpret_cast<const bv8*>(qr + lg * 8);
    aq1 = *reinterpret_cast<const bv8*>(qr + 32 + lg * 8);
  }

  f32x4 o[4];
  float mrun[4], lrun[4];
  #pragma unroll
  for (int i = 0; i < 4; ++i) { o[i] = (f32x4){0.f,0.f,0.f,0.f}; mrun[i] = -1e30f; lrun[i] = 0.f; }

  const u16* kb = kgf + ((size_t)bh) * Ss * 64;
  const u16* vb = vgt + ((size_t)bh) * 64 * Ss;
  const int* amb = amask + b * Ss;
  int ks0 = ch * (Ss / NCH);

  for (int st = 0; st < (Ss / NCH) / 32; ++st) {
    int ks = ks0 + st * 32;
    f32x4 sc0, sc1;
    {
      const u16* kr0 = kb + (size_t)(ks + lc) * 64;
      const u16* kr1 = kr0 + 16 * 64;
      bv8 b00 = *reinterpret_cast<const bv8*>(kr0 + lg * 8);
      bv8 b01 = *reinterpret_cast<const bv8*>(kr0 + 32 + lg * 8);
      bv8 b10 = *reinterpret_cast<const bv8*>(kr1 + lg * 8);
      bv8 b11 = *reinterpret_cast<const bv8*>(kr1 + 32 + lg * 8);
      f32x4 z = (f32x4){0.f,0.f,0.f,0.f};
      sc0 = __builtin_amdgcn_mfma_f32_16x16x32_bf16(aq0, b00, z, 0, 0, 0);
      sc0 = __builtin_amdgcn_mfma_f32_16x16x32_bf16(aq1, b01, sc0, 0, 0, 0);
      sc1 = __builtin_amdgcn_mfma_f32_16x16x32_bf16(aq0, b10, z, 0, 0, 0);
      sc1 = __builtin_amdgcn_mfma_f32_16x16x32_bf16(aq1, b11, sc1, 0, 0, 0);
    }
    bool v0 = amb[ks + lc] > 0;
    bool v1 = amb[ks + 16 + lc] > 0;
    #pragma unroll
    for (int r = 0; r < 4; ++r) {
      float s0 = v0 ? sc0[r] : -1e9f;
      float s1 = v1 ? sc1[r] : -1e9f;
      float rm = fmaxf(s0, s1);
      #pragma unroll
      for (int off = 1; off < 16; off <<= 1) rm = fmaxf(rm, __shfl_xor(rm, off));
      float nm = fmaxf(mrun[r], rm);
      float scal = __expf(mrun[r] - nm);
      float p0 = __expf(s0 - nm);
      float p1 = __expf(s1 - nm);
      float ps = p0 + p1;
      #pragma unroll
      for (int off = 1; off < 16; off <<= 1) ps += __shfl_xor(ps, off);
      lrun[r] = lrun[r] * scal + ps;
      mrun[r] = nm;
      #pragma unroll
      for (int nt = 0; nt < 4; ++nt) o[nt][r] *= scal;
      int prow = lg * 4 + r;
      Plds[wv][prow * 32 + lc] = f2bf(p0);
      Plds[wv][prow * 32 + 16 + lc] = f2bf(p1);
    }
    bv8 ap = *reinterpret_cast<const bv8*>(&Plds[wv][lc * 32 + lg * 8]);
    #pragma unroll
    for (int nt = 0; nt < 4; ++nt) {
      const u16* vr = vb + (size_t)(nt * 16 + lc) * Ss + ks;
      bv8 bvv = *reinterpret_cast<const bv8*>(vr + lg * 8);
      o[nt] = __builtin_amdgcn_mfma_f32_16x16x32_bf16(ap, bvv, o[nt], 0, 0, 0);
    }
  }

  float* pb = part + ((size_t)(bh * 3 + wv) * NCH + ch) * PARTF;
  #pragma unroll
  for (int r = 0; r < 4; ++r) {
    int row = lg * 4 + r;
    #pragma unroll
    for (int nt = 0; nt < 4; ++nt)
      pb[row * 64 + nt * 16 + lc] = o[nt][r];
    if (lc == 0) {
      pb[1024 + row] = mrun[r];
      pb[1040 + row] = lrun[r];
    }
  }
}

// merge NCH chunk-partials and scatter into ctx rows at gpos
__global__ __launch_bounds__(256)
void attn_gmerge_kernel(const float* __restrict__ part, const int* __restrict__ gpos,
                        u16* __restrict__ ctx) {
  __shared__ float wgt[Gg][NCH];
  __shared__ float sinvl[Gg];
  int bh = blockIdx.x;
  int b = bh / Hh, h = bh - b * Hh;
  int tid = threadIdx.x;
  if (tid < Gg) {
    int qt = tid >> 4, rr = tid & 15;
    const float* pb = part + ((size_t)(bh * 3 + qt) * NCH) * PARTF;
    float mx = -1e30f;
    for (int c = 0; c < NCH; ++c) mx = fmaxf(mx, pb[c * PARTF + 1024 + rr]);
    float l = 0.f;
    for (int c = 0; c < NCH; ++c) {
      float w = __expf(pb[c * PARTF + 1024 + rr] - mx);
      wgt[tid][c] = w;
      l += w * pb[c * PARTF + 1040 + rr];
    }
    sinvl[tid] = 1.0f / l;
  }
  __syncthreads();
  for (int e = tid; e < Gg * 64; e += 256) {
    int row = e >> 6, d = e & 63;
    int qt = row >> 4, rr = row & 15;
    const float* pb = part + ((size_t)(bh * 3 + qt) * NCH) * PARTF + rr * 64 + d;
    float acc = 0.f;
    #pragma unroll
    for (int c = 0; c < NCH; ++c) acc += wgt[row][c] * pb[c * PARTF];
    int pos = gpos[b * Gg + row];
    ctx[((size_t)b * Ss + pos) * Dd + h * 64 + d] = f2bf(acc * sinvl[row]);
  }
}

// ---------------- classifier ------------------------------------------------
__global__ __launch_bounds__(64)
void cls_kernel(const float* __restrict__ x, const float* __restrict__ W,
                const float* __restrict__ bias, const int* __restrict__ gpos,
                float* __restrict__ out) {
  int r = blockIdx.x;  // b*32 + i
  int b = r >> 5, i = r & 31;
  int pos = gpos[b * Gg + 1 + i];
  int lane = threadIdx.x;
  const float* xr = x + ((size_t)b * Ss + pos) * Dd;
  float acc[NCLSn] = {0.f, 0.f, 0.f, 0.f, 0.f};
  for (int k = lane; k < Dd; k += 64) {
    float xv = xr[k];
    #pragma unroll
    for (int c = 0; c < NCLSn; ++c) acc[c] += xv * W[c * Dd + k];
  }
  #pragma unroll
  for (int c = 0; c < NCLSn; ++c) {
    #pragma unroll
    for (int off = 1; off < 64; off <<= 1) acc[c] += __shfl_xor(acc[c], off);
  }
  if (lane == 0) {
    #pragma unroll
    for (int c = 0; c < NCLSn; ++c) out[r * NCLSn + c] = acc[c] + bias[c];
  }
}

// ---------------------------------------------------------------------------
extern "C" void kernel_launch(void* const* d_in, const int* in_sizes, int n_in,
                              void* d_out, int out_size, void* d_ws, size_t ws_size,
                              hipStream_t stream) {
  const int* ids     = (const int*)d_in[0];
  const int* amask   = (const int*)d_in[1];
  const float* we    = (const float*)d_in[2];
  const float* pe    = (const float*)d_in[3];
  const float* te    = (const float*)d_in[4];
  const float* embln = (const float*)d_in[5];
  const float* Wqkv  = (const float*)d_in[6];
  const float* bqkv  = (const float*)d_in[7];
  const float* Wqkvg = (const float*)d_in[8];
  const float* bqkvg = (const float*)d_in[9];
  const float* Wo    = (const float*)d_in[10];
  const float* bo    = (const float*)d_in[11];
  const float* ln1   = (const float*)d_in[12];
  const float* Wff1  = (const float*)d_in[13];
  const float* bff1  = (const float*)d_in[14];
  const float* Wff2  = (const float*)d_in[15];
  const float* bff2  = (const float*)d_in[16];
  const float* ln2   = (const float*)d_in[17];
  const float* clsW  = (const float*)d_in[18];
  const float* clsb  = (const float*)d_in[19];
  float* out = (float*)d_out;

  char* ws = (char*)d_ws;
  size_t off = 0;
  auto alloc = [&](size_t bytes) { size_t o = off; off += (bytes + 255) & ~(size_t)255; return o; };

  const size_t DD = (size_t)Dd * Dd;        // 589824
  const size_t DF = (size_t)Dd * 4 * Dd;    // 2359296
  const size_t WL = 7 * DD + 2 * DF;        // elems per layer

  size_t o_cnt  = alloc(Bb * 4);
  size_t o_list = alloc(Bb * 64 * 4);
  size_t o_gpos = alloc(Bb * Gg * 4);
  size_t o_w    = alloc(WL * Ll * 2);
  size_t o_x    = alloc((size_t)Bb * Ss * Dd * 4);
  size_t o_xb   = alloc((size_t)Bb * Ss * Dd * 2);
  size_t o_qpk  = alloc((size_t)Bb * Hh * Ss * 64 * 2);
  size_t o_kpk  = alloc((size_t)Bb * Hh * SPAD * 64 * 2);
  size_t o_vtpk = alloc((size_t)Bb * Hh * 64 * SPAD * 2);
  size_t o_kg   = alloc((size_t)Bb * Hh * 64 * 64 * 2);
  size_t o_vgt  = alloc((size_t)Bb * Hh * 64 * 64 * 2);
  size_t o_xg   = alloc((size_t)128 * Dd * 2);
  size_t o_qg   = alloc((size_t)128 * Dd * 2);
  size_t o_kgf  = alloc((size_t)Bb * Hh * Ss * 64 * 2);
  size_t o_vgf  = alloc((size_t)Bb * Hh * Ss * 64 * 2);
  size_t o_part = alloc((size_t)Bb * Hh * 3 * NCH * PARTF * 4);
  size_t o_f1b  = o_qpk;  // FFN hidden aliases the (dead-by-then) attention buffers
  {
    size_t f1b_bytes = (size_t)Bb * Ss * 4 * Dd * 2;
    if (off - o_qpk < f1b_bytes) off = o_qpk + ((f1b_bytes + 255) & ~(size_t)255);
  }
  size_t o_ctx = alloc((size_t)Bb * Ss * Dd * 2);
  size_t o_acc = alloc((size_t)Bb * Ss * Dd * 4);
  if (ws_size < off) return;  // workspace too small -> fail visibly

  u16* Wb = (u16*)(ws + o_w);
  int* gposp = (int*)(ws + o_gpos);

  (void)hipMemsetAsync(ws + o_cnt, 0, Bb * 4, stream);
  // zero padded K / V^T so first-call pads are finite (later calls: finite stale bf16)
  (void)hipMemsetAsync(ws + o_kpk, 0, (size_t)Bb * Hh * SPAD * 64 * 2, stream);
  (void)hipMemsetAsync(ws + o_vtpk, 0, (size_t)Bb * Hh * 64 * SPAD * 2, stream);

  sep_find_kernel<<<(Bb * Ss + 255) / 256, 256, 0, stream>>>(ids, (int*)(ws + o_cnt), (int*)(ws + o_list));
  sep_sort_kernel<<<Bb, 64, 0, stream>>>((int*)(ws + o_cnt), (int*)(ws + o_list), gposp);

  // weight conversions
  for (int l = 0; l < Ll; ++l) {
    size_t wb = (size_t)l * WL;
    for (int i = 0; i < 3; ++i)
      wconv_kernel<<<dim3(Dd / 32, Dd / 32), 256, 0, stream>>>(Wqkv + ((size_t)l * 3 + i) * DD, Wb + wb + i * DD, Dd, Dd);
    for (int i = 0; i < 3; ++i)
      wconv_kernel<<<dim3(Dd / 32, Dd / 32), 256, 0, stream>>>(Wqkvg + ((size_t)l * 3 + i) * DD, Wb + wb + (3 + i) * DD, Dd, Dd);
    wconv_kernel<<<dim3(Dd / 32, Dd / 32), 256, 0, stream>>>(Wo + (size_t)l * DD, Wb + wb + 6 * DD, Dd, Dd);
    wconv_kernel<<<dim3(4 * Dd / 32, Dd / 32), 256, 0, stream>>>(Wff1 + (size_t)l * DF, Wb + wb + 7 * DD, Dd, 4 * Dd);
    wconv_kernel<<<dim3(Dd / 32, 4 * Dd / 32), 256, 0, stream>>>(Wff2 + (size_t)l * DF, Wb + wb + 7 * DD + DF, 4 * Dd, Dd);
  }

  embed_ln_kernel<<<Bb * Ss, 256, 0, stream>>>(ids, we, pe, te, embln, (float*)(ws + o_x), (u16*)(ws + o_xb));

  for (int l = 0; l < Ll; ++l) {
    size_t wb = (size_t)l * WL;
    u16* xb = (u16*)(ws + o_xb);
    // Q/K/V projections
    gemm_kernel<2, false><<<dim3(6, 64), 256, 0, stream>>>(xb, Wb + wb + 0 * DD, bqkv + (size_t)(l * 3 + 0) * Dd, nullptr, (u16*)(ws + o_qpk), Bb * Ss, Dd, Dd, 0.125f);
    gemm_kernel<3, false><<<dim3(6, 64), 256, 0, stream>>>(xb, Wb + wb + 1 * DD, bqkv + (size_t)(l * 3 + 1) * Dd, nullptr, (u16*)(ws + o_kpk), Bb * Ss, Dd, Dd, 1.0f);
    gemm_kernel<4, false><<<dim3(6, 64), 256, 0, stream>>>(xb, Wb + wb + 2 * DD, bqkv + (size_t)(l * 3 + 2) * Dd, nullptr, (u16*)(ws + o_vtpk), Bb * Ss, Dd, Dd, 1.0f);
    gather_glob_kernel<<<Bb * Hh, 256, 0, stream>>>((u16*)(ws + o_kpk), (u16*)(ws + o_vtpk), gposp, (u16*)(ws + o_kg), (u16*)(ws + o_vgt));
    gather_xg_kernel<<<Bb * Gg, 256, 0, stream>>>(xb, gposp, (u16*)(ws + o_xg));
    // global projections: q_g bf16 [B*G][768]; k_gf packed; v_gf packed-T
    gemm_kernel<1, false><<<dim3(6, 1), 256, 0, stream>>>((u16*)(ws + o_xg), Wb + wb + 3 * DD, bqkvg + (size_t)(l * 3 + 0) * Dd, nullptr, (u16*)(ws + o_qg), Bb * Gg, Dd, Dd, 0.125f);
    gemm_kernel<2, false><<<dim3(6, 64), 256, 0, stream>>>(xb, Wb + wb + 4 * DD, bqkvg + (size_t)(l * 3 + 1) * Dd, nullptr, (u16*)(ws + o_kgf), Bb * Ss, Dd, Dd, 1.0f);
    gemm_kernel<5, false><<<dim3(6, 64), 256, 0, stream>>>(xb, Wb + wb + 5 * DD, bqkvg + (size_t)(l * 3 + 2) * Dd, nullptr, (u16*)(ws + o_vgf), Bb * Ss, Dd, Dd, 1.0f);
    // attention
    attn_local_kernel<<<Bb * Hh * (Ss / 16), 64, 0, stream>>>((u16*)(ws + o_qpk), (u16*)(ws + o_kpk), (u16*)(ws + o_vtpk), (u16*)(ws + o_kg), (u16*)(ws + o_vgt), amask, (u16*)(ws + o_ctx));
    attn_globalq_kernel<<<Bb * Hh * NCH, 192, 0, stream>>>((u16*)(ws + o_qg), (u16*)(ws + o_kgf), (u16*)(ws + o_vgf), amask, (float*)(ws + o_part));
    attn_gmerge_kernel<<<Bb * Hh, 256, 0, stream>>>((float*)(ws + o_part), gposp, (u16*)(ws + o_ctx));
    // output projection + LN
    gemm_kernel<0, false><<<dim3(6, 64), 256, 0, stream>>>((u16*)(ws + o_ctx), Wb + wb + 6 * DD, bo + (size_t)l * Dd, (float*)(ws + o_acc), nullptr, Bb * Ss, Dd, Dd, 1.0f);
    add_ln_kernel<<<Bb * Ss, 256, 0, stream>>>((float*)(ws + o_x), (float*)(ws + o_acc), ln1 + (size_t)l * 2 * Dd, (float*)(ws + o_x), xb);
    // FFN
    gemm_kernel<1, true><<<dim3(24, 64), 256, 0, stream>>>(xb, Wb + wb + 7 * DD, bff1 + (size_t)l * 4 * Dd, nullptr, (u16*)(ws + o_f1b), Bb * Ss, 4 * Dd, Dd, 1.0f);
    gemm_kernel<0, false><<<dim3(6, 64), 256, 0, stream>>>((u16*)(ws + o_f1b), Wb + wb + 7 * DD + DF, bff2 + (size_t)l * Dd, (float*)(ws + o_acc), nullptr, Bb * Ss, Dd, 4 * Dd, 1.0f);
    add_ln_kernel<<<Bb * Ss, 256, 0, stream>>>((float*)(ws + o_x), (float*)(ws + o_acc), ln2 + (size_t)l * 2 * Dd, (float*)(ws + o_x), xb);
  }

  cls_kernel<<<Bb * NSEPn, 64, 0, stream>>>((float*)(ws + o_x), clsW, clsb, gposp, out);
}

// Round 3
// 1234.471 us; speedup vs baseline: 1.7189x; 1.1683x over previous
//
#include <hip/hip_runtime.h>

// ---------------------------------------------------------------------------
// Longformer (2-layer) forward, MI355X.
// R2: attn_local coarsened to 4 waves/64 queries per block + XCD-aware
//     bijective swizzle for per-XCD L2 locality (fix 22x HBM over-fetch).
// ---------------------------------------------------------------------------

#define Bb 2
#define Ss 4096
#define Dd 768
#define Hh 12
#define Gg 33
#define NSEPn 32
#define Ll 2
#define SPAD 4640   // S + 544 (PADL=256 left, 288 right)
#define PADL 256
#define NCLSn 5
#define NCH 16      // key chunks for global-q attention (256 keys each)
#define PARTF 1056  // floats per (bh,qt,chunk) partial: 16*64 o + 16 m + 16 l

typedef unsigned short u16;
typedef __attribute__((ext_vector_type(8))) short bv8;   // 8 x bf16
typedef __attribute__((ext_vector_type(4))) short sv4;   // 4 x bf16
typedef __attribute__((ext_vector_type(4))) float f32x4;

__device__ __forceinline__ float bf2f(u16 u) {
  unsigned v = ((unsigned)u) << 16;
  return __builtin_bit_cast(float, v);
}
__device__ __forceinline__ u16 f2bf(float f) {
  unsigned u = __builtin_bit_cast(unsigned, f);
  u += 0x7fffu + ((u >> 16) & 1u);
  return (u16)(u >> 16);
}

// ---------------- sep finding --------------------------------------------
__global__ void sep_find_kernel(const int* __restrict__ ids, int* __restrict__ cnt,
                                int* __restrict__ list) {
  int i = blockIdx.x * 256 + threadIdx.x;
  if (i >= Bb * Ss) return;
  int b = i >> 12;
  if (ids[i] == 2) {
    int idx = atomicAdd(&cnt[b], 1);
    if (idx < 64) list[b * 64 + idx] = i & (Ss - 1);
  }
}

__global__ void sep_sort_kernel(const int* __restrict__ cnt, const int* __restrict__ list,
                                int* __restrict__ gpos) {
  int b = blockIdx.x;
  int t = threadIdx.x;
  int n = cnt[b]; if (n > 64) n = 64;
  if (t < Gg) gpos[b * Gg + t] = (t == 0) ? 0 : (Ss - 1);
  __syncthreads();
  if (t < n) {
    int v = list[b * 64 + t];
    int rank = 0;
    for (int j = 0; j < n; ++j) rank += (list[b * 64 + j] < v) ? 1 : 0;
    if (rank < NSEPn) gpos[b * Gg + 1 + rank] = v;
  }
}

// ---------------- weight fp32 (K,N) -> bf16 (N,K) --------------------------
__global__ __launch_bounds__(256)
void wconv_kernel(const float* __restrict__ src, u16* __restrict__ dst, int K, int N) {
  __shared__ float t[32][33];
  int n0 = blockIdx.x * 32, k0 = blockIdx.y * 32;
  int tx = threadIdx.x & 31, ty = threadIdx.x >> 5;  // ty 0..7
  #pragma unroll
  for (int i = 0; i < 4; ++i)
    t[ty + i * 8][tx] = src[(size_t)(k0 + ty + i * 8) * N + n0 + tx];
  __syncthreads();
  #pragma unroll
  for (int i = 0; i < 4; ++i)
    dst[(size_t)(n0 + ty + i * 8) * K + k0 + tx] = f2bf(t[tx][ty + i * 8]);
}

// ---------------- embedding + LN -------------------------------------------
__global__ __launch_bounds__(256)
void embed_ln_kernel(const int* __restrict__ ids, const float* __restrict__ we,
                     const float* __restrict__ pe, const float* __restrict__ te,
                     const float* __restrict__ lnp, float* __restrict__ x,
                     u16* __restrict__ xb) {
  int row = blockIdx.x;
  int s = row & (Ss - 1);
  int id = ids[row];
  int tid = threadIdx.x;
  float v[3]; float sm = 0.f, s2 = 0.f;
  #pragma unroll
  for (int i = 0; i < 3; ++i) {
    int c = tid + i * 256;
    float t = we[(size_t)id * Dd + c] + pe[(size_t)(s + 2) * Dd + c] + te[c];
    v[i] = t; sm += t; s2 += t * t;
  }
  __shared__ float r1[256], r2[256];
  r1[tid] = sm; r2[tid] = s2; __syncthreads();
  for (int o = 128; o; o >>= 1) {
    if (tid < o) { r1[tid] += r1[tid + o]; r2[tid] += r2[tid + o]; }
    __syncthreads();
  }
  float mean = r1[0] * (1.f / 768.f);
  float var  = r2[0] * (1.f / 768.f) - mean * mean;
  float rs = rsqrtf(var + 1e-5f);
  #pragma unroll
  for (int i = 0; i < 3; ++i) {
    int c = tid + i * 256;
    float o = (v[i] - mean) * rs * lnp[c] + lnp[Dd + c];
    x[(size_t)row * Dd + c] = o;
    xb[(size_t)row * Dd + c] = f2bf(o);
  }
}

// ---------------- residual + LN --------------------------------------------
__global__ __launch_bounds__(256)
void add_ln_kernel(const float* __restrict__ xin, const float* __restrict__ y,
                   const float* __restrict__ lnp, float* __restrict__ xout,
                   u16* __restrict__ xbout) {
  int row = blockIdx.x;
  int tid = threadIdx.x;
  float v[3]; float sm = 0.f, s2 = 0.f;
  #pragma unroll
  for (int i = 0; i < 3; ++i) {
    int c = tid + i * 256;
    float t = xin[(size_t)row * Dd + c] + y[(size_t)row * Dd + c];
    v[i] = t; sm += t; s2 += t * t;
  }
  __shared__ float r1[256], r2[256];
  r1[tid] = sm; r2[tid] = s2; __syncthreads();
  for (int o = 128; o; o >>= 1) {
    if (tid < o) { r1[tid] += r1[tid + o]; r2[tid] += r2[tid + o]; }
    __syncthreads();
  }
  float mean = r1[0] * (1.f / 768.f);
  float var  = r2[0] * (1.f / 768.f) - mean * mean;
  float rs = rsqrtf(var + 1e-5f);
  #pragma unroll
  for (int i = 0; i < 3; ++i) {
    int c = tid + i * 256;
    float o = (v[i] - mean) * rs * lnp[c] + lnp[Dd + c];
    xout[(size_t)row * Dd + c] = o;
    xbout[(size_t)row * Dd + c] = f2bf(o);
  }
}

// ---------------- GEMM: C = (A(bf16 MxK) @ Bt(bf16 NxK)^T + bias) * scale ---
// MODE 0: fp32 [M][N]; 1: bf16 [M][N]; 2: bf16 packed [b][h][s][64];
// 3: bf16 packed padded [b][h][PADL+s][64]; 4: bf16 packed-T padded [b][h][64][PADL+s]
// 5: bf16 packed-T non-padded [b][h][64][Ss]
#define LDAP 40
template <int MODE, bool GELU_>
__global__ __launch_bounds__(256)
void gemm_kernel(const u16* __restrict__ A, const u16* __restrict__ Bt,
                 const float* __restrict__ bias, float* __restrict__ outf,
                 u16* __restrict__ outb, int M, int N, int K, float scale) {
  __shared__ u16 la[128 * LDAP], lb[128 * LDAP];
  int tid = threadIdx.x;
  int wave = tid >> 6, lane = tid & 63;
  int wr = wave >> 1, wc = wave & 1;
  int lg = lane >> 4, lc = lane & 15;
  int row0 = blockIdx.y * 128, col0 = blockIdx.x * 128;
  f32x4 acc[4][4];
  #pragma unroll
  for (int m = 0; m < 4; ++m)
    #pragma unroll
    for (int n = 0; n < 4; ++n) acc[m][n] = (f32x4){0.f, 0.f, 0.f, 0.f};
  int sr = tid >> 2, sc = tid & 3;

  for (int k0 = 0; k0 < K; k0 += 32) {
    #pragma unroll
    for (int i = 0; i < 2; ++i) {
      int r = sr + 64 * i;
      int gr = row0 + r;
      bv8 va = (bv8)0;
      if (gr < M) va = *reinterpret_cast<const bv8*>(A + (size_t)gr * K + k0 + sc * 8);
      *reinterpret_cast<bv8*>(la + r * LDAP + sc * 8) = va;
      bv8 vb = *reinterpret_cast<const bv8*>(Bt + (size_t)(col0 + r) * K + k0 + sc * 8);
      *reinterpret_cast<bv8*>(lb + r * LDAP + sc * 8) = vb;
    }
    __syncthreads();
    bv8 af[4], bfr[4];
    #pragma unroll
    for (int m = 0; m < 4; ++m)
      af[m] = *reinterpret_cast<const bv8*>(la + (wr * 64 + m * 16 + lc) * LDAP + lg * 8);
    #pragma unroll
    for (int n = 0; n < 4; ++n)
      bfr[n] = *reinterpret_cast<const bv8*>(lb + (wc * 64 + n * 16 + lc) * LDAP + lg * 8);
    #pragma unroll
    for (int m = 0; m < 4; ++m)
      #pragma unroll
      for (int n = 0; n < 4; ++n)
        acc[m][n] = __builtin_amdgcn_mfma_f32_16x16x32_bf16(af[m], bfr[n], acc[m][n], 0, 0, 0);
    __syncthreads();
  }

  #pragma unroll
  for (int m = 0; m < 4; ++m) {
    int grow0 = row0 + wr * 64 + m * 16 + lg * 4;
    #pragma unroll
    for (int n = 0; n < 4; ++n) {
      int gcol = col0 + wc * 64 + n * 16 + lc;
      float bvl = bias[gcol];
      if (MODE == 4 || MODE == 5) {
        if (grow0 + 3 < M) {
          int bb = grow0 >> 12, s = grow0 & (Ss - 1);
          int hh = gcol >> 6, d = gcol & 63;
          sv4 pk;
          #pragma unroll
          for (int r = 0; r < 4; ++r) {
            float v = (acc[m][n][r] + bvl) * scale;
            pk[r] = (short)f2bf(v);
          }
          if (MODE == 4)
            *reinterpret_cast<sv4*>(outb + (((size_t)(bb * Hh + hh)) * 64 + d) * SPAD + PADL + s) = pk;
          else
            *reinterpret_cast<sv4*>(outb + (((size_t)(bb * Hh + hh)) * 64 + d) * Ss + s) = pk;
        }
      } else {
        #pragma unroll
        for (int r = 0; r < 4; ++r) {
          int grow = grow0 + r;
          if (grow >= M) continue;
          float v = (acc[m][n][r] + bvl) * scale;
          if (GELU_) v = 0.5f * v * (1.0f + erff(v * 0.70710678118654752f));
          if (MODE == 0) {
            outf[(size_t)grow * N + gcol] = v;
          } else if (MODE == 1) {
            outb[(size_t)grow * N + gcol] = f2bf(v);
          } else {
            int bb = grow >> 12, s = grow & (Ss - 1);
            int hh = gcol >> 6, d = gcol & 63;
            if (MODE == 2)
              outb[(((size_t)(bb * Hh + hh)) * Ss + s) * 64 + d] = f2bf(v);
            else
              outb[(((size_t)(bb * Hh + hh)) * SPAD + PADL + s) * 64 + d] = f2bf(v);
          }
        }
      }
    }
  }
}

// ---------------- gathers ---------------------------------------------------
__global__ __launch_bounds__(256)
void gather_glob_kernel(const u16* __restrict__ kpk, const u16* __restrict__ vtpk,
                        const int* __restrict__ gpos, u16* __restrict__ kg,
                        u16* __restrict__ vgt) {
  int bh = blockIdx.x;
  int b = bh / Hh;
  int tid = threadIdx.x;
  for (int idx = tid; idx < 64 * 64; idx += 256) {
    int g = idx >> 6, d = idx & 63;
    u16 kv = 0, vv = 0;
    if (g < Gg) {
      int p = gpos[b * Gg + g];
      kv = kpk[((size_t)bh * SPAD + PADL + p) * 64 + d];
      vv = vtpk[((size_t)bh * 64 + d) * SPAD + PADL + p];
    }
    kg[(size_t)bh * 4096 + idx] = kv;
    vgt[((size_t)bh * 64 + d) * 64 + g] = vv;
  }
}

__global__ __launch_bounds__(256)
void gather_xg_kernel(const u16* __restrict__ xb, const int* __restrict__ gpos,
                      u16* __restrict__ xg) {
  int rg = blockIdx.x;  // b*G+g
  int b = rg / Gg;
  int p = gpos[rg];
  int tid = threadIdx.x;
  for (int c = tid; c < Dd; c += 256)
    xg[(size_t)rg * Dd + c] = xb[((size_t)b * Ss + p) * Dd + c];
}

// ---------------- local (sliding window + global-key) attention -------------
// 4 waves/block, 64 consecutive queries; XCD-aware bijective swizzle.
#define LOCAL_NB (Bb * Hh * (Ss / 64))   // 1536 blocks, %8 == 0
__global__ __launch_bounds__(256)
void attn_local_kernel(const u16* __restrict__ qpk, const u16* __restrict__ kpk,
                       const u16* __restrict__ vtpk, const u16* __restrict__ kg,
                       const u16* __restrict__ vgt, const int* __restrict__ amask,
                       u16* __restrict__ ctx) {
  __shared__ u16 Plds[4][16 * 32];
  // XCD swizzle: each XCD gets a contiguous chunk of work ids (3 bh of K/V
  // ~= 3.6 MB, fits the 4 MB per-XCD L2).
  int bid = blockIdx.x;
  int swz = (bid & 7) * (LOCAL_NB / 8) + (bid >> 3);
  int qb = swz & 63;        // 64-query block index within bh
  int bh = swz >> 6;
  int b = bh / Hh;
  int h = bh - b * Hh;
  int wv = threadIdx.x >> 6;
  int q0 = qb * 64 + wv * 16;
  int lane = threadIdx.x & 63;
  int lg = lane >> 4, lc = lane & 15;

  const u16* qbase = qpk + (((size_t)bh) * Ss + q0) * 64;
  bv8 aq0 = *reinterpret_cast<const bv8*>(qbase + (size_t)lc * 64 + lg * 8);
  bv8 aq1 = *reinterpret_cast<const bv8*>(qbase + (size_t)lc * 64 + 32 + lg * 8);

  f32x4 o[4];
  float mrun[4], lrun[4];
  #pragma unroll
  for (int i = 0; i < 4; ++i) { o[i] = (f32x4){0.f,0.f,0.f,0.f}; mrun[i] = -1e30f; lrun[i] = 0.f; }

  const u16* kgb = kg + ((size_t)bh) * 64 * 64;
  const u16* vgb = vgt + ((size_t)bh) * 64 * 64;
  const u16* kb = kpk + ((size_t)bh) * SPAD * 64;
  const u16* vb = vtpk + ((size_t)bh) * 64 * SPAD;
  const int* amb = amask + b * Ss;

  for (int step = 0; step < 19; ++step) {
    bool isg = (step < 2);
    int ks = isg ? (step * 32) : (q0 - 256 + (step - 2) * 32);
    f32x4 sc0, sc1;
    {
      const u16* kr0 = isg ? (kgb + (size_t)(ks + lc) * 64)
                           : (kb + (size_t)(PADL + ks + lc) * 64);
      const u16* kr1 = kr0 + 16 * 64;
      bv8 b00 = *reinterpret_cast<const bv8*>(kr0 + lg * 8);
      bv8 b01 = *reinterpret_cast<const bv8*>(kr0 + 32 + lg * 8);
      bv8 b10 = *reinterpret_cast<const bv8*>(kr1 + lg * 8);
      bv8 b11 = *reinterpret_cast<const bv8*>(kr1 + 32 + lg * 8);
      f32x4 z = (f32x4){0.f,0.f,0.f,0.f};
      sc0 = __builtin_amdgcn_mfma_f32_16x16x32_bf16(aq0, b00, z, 0, 0, 0);
      sc0 = __builtin_amdgcn_mfma_f32_16x16x32_bf16(aq1, b01, sc0, 0, 0, 0);
      sc1 = __builtin_amdgcn_mfma_f32_16x16x32_bf16(aq0, b10, z, 0, 0, 0);
      sc1 = __builtin_amdgcn_mfma_f32_16x16x32_bf16(aq1, b11, sc1, 0, 0, 0);
    }
    int ka0 = ks + lc, ka1 = ks + 16 + lc;
    bool v0, v1;
    if (isg) {
      v0 = ka0 < Gg; v1 = ka1 < Gg;
    } else {
      v0 = (ka0 >= 0 && ka0 < Ss) ? (amb[ka0] > 0) : false;
      v1 = (ka1 >= 0 && ka1 < Ss) ? (amb[ka1] > 0) : false;
    }
    #pragma unroll
    for (int r = 0; r < 4; ++r) {
      int q = q0 + lg * 4 + r;
      float s0 = sc0[r], s1 = sc1[r];
      bool b0 = v0, b1 = v1;
      if (!isg) {
        b0 = b0 && (ka0 - q >= -256) && (ka0 - q <= 256);
        b1 = b1 && (ka1 - q >= -256) && (ka1 - q <= 256);
      }
      s0 = b0 ? s0 : -1e9f;
      s1 = b1 ? s1 : -1e9f;
      float rm = fmaxf(s0, s1);
      #pragma unroll
      for (int off = 1; off < 16; off <<= 1) rm = fmaxf(rm, __shfl_xor(rm, off));
      float nm = fmaxf(mrun[r], rm);
      float scal = __expf(mrun[r] - nm);
      float p0 = __expf(s0 - nm);
      float p1 = __expf(s1 - nm);
      float ps = p0 + p1;
      #pragma unroll
      for (int off = 1; off < 16; off <<= 1) ps += __shfl_xor(ps, off);
      lrun[r] = lrun[r] * scal + ps;
      mrun[r] = nm;
      #pragma unroll
      for (int nt = 0; nt < 4; ++nt) o[nt][r] *= scal;
      int prow = lg * 4 + r;
      Plds[wv][prow * 32 + lc] = f2bf(p0);
      Plds[wv][prow * 32 + 16 + lc] = f2bf(p1);
    }
    bv8 ap = *reinterpret_cast<const bv8*>(&Plds[wv][lc * 32 + lg * 8]);
    #pragma unroll
    for (int nt = 0; nt < 4; ++nt) {
      const u16* vr = isg ? (vgb + (size_t)(nt * 16 + lc) * 64 + ks)
                          : (vb + (size_t)(nt * 16 + lc) * SPAD + PADL + ks);
      bv8 bvv = *reinterpret_cast<const bv8*>(vr + lg * 8);
      o[nt] = __builtin_amdgcn_mfma_f32_16x16x32_bf16(ap, bvv, o[nt], 0, 0, 0);
    }
  }
  #pragma unroll
  for (int r = 0; r < 4; ++r) {
    float inv = 1.0f / lrun[r];
    size_t rowoff = ((size_t)b * Ss + q0 + lg * 4 + r) * Dd + h * 64;
    #pragma unroll
    for (int nt = 0; nt < 4; ++nt)
      ctx[rowoff + nt * 16 + lc] = f2bf(o[nt][r] * inv);
  }
}

// ---------------- global-query attention: chunked flash MFMA ----------------
// grid: bh * NCH; block 192 (3 waves, one 16-q-row tile each; rows>=33 padded)
__global__ __launch_bounds__(192)
void attn_globalq_kernel(const u16* __restrict__ qgb, const u16* __restrict__ kgf,
                         const u16* __restrict__ vgt, const int* __restrict__ amask,
                         float* __restrict__ part) {
  __shared__ u16 Plds[3][16 * 32];
  int blk = blockIdx.x;
  int ch = blk & (NCH - 1);
  int bh = blk / NCH;
  int b = bh / Hh, h = bh - b * Hh;
  int wv = threadIdx.x >> 6;  // q-tile 0..2
  int lane = threadIdx.x & 63;
  int lg = lane >> 4, lc = lane & 15;

  int qrow = wv * 16 + lc;
  bv8 aq0 = (bv8)0, aq1 = (bv8)0;
  if (qrow < Gg) {
    const u16* qr = qgb + (size_t)(b * Gg + qrow) * Dd + h * 64;
    aq0 = *reinterpret_cast<const bv8*>(qr + lg * 8);
    aq1 = *reinterpret_cast<const bv8*>(qr + 32 + lg * 8);
  }

  f32x4 o[4];
  float mrun[4], lrun[4];
  #pragma unroll
  for (int i = 0; i < 4; ++i) { o[i] = (f32x4){0.f,0.f,0.f,0.f}; mrun[i] = -1e30f; lrun[i] = 0.f; }

  const u16* kb = kgf + ((size_t)bh) * Ss * 64;
  const u16* vb = vgt + ((size_t)bh) * 64 * Ss;
  const int* amb = amask + b * Ss;
  int ks0 = ch * (Ss / NCH);

  for (int st = 0; st < (Ss / NCH) / 32; ++st) {
    int ks = ks0 + st * 32;
    f32x4 sc0, sc1;
    {
      const u16* kr0 = kb + (size_t)(ks + lc) * 64;
      const u16* kr1 = kr0 + 16 * 64;
      bv8 b00 = *reinterpret_cast<const bv8*>(kr0 + lg * 8);
      bv8 b01 = *reinterpret_cast<const bv8*>(kr0 + 32 + lg * 8);
      bv8 b10 = *reinterpret_cast<const bv8*>(kr1 + lg * 8);
      bv8 b11 = *reinterpret_cast<const bv8*>(kr1 + 32 + lg * 8);
      f32x4 z = (f32x4){0.f,0.f,0.f,0.f};
      sc0 = __builtin_amdgcn_mfma_f32_16x16x32_bf16(aq0, b00, z, 0, 0, 0);
      sc0 = __builtin_amdgcn_mfma_f32_16x16x32_bf16(aq1, b01, sc0, 0, 0, 0);
      sc1 = __builtin_amdgcn_mfma_f32_16x16x32_bf16(aq0, b10, z, 0, 0, 0);
      sc1 = __builtin_amdgcn_mfma_f32_16x16x32_bf16(aq1, b11, sc1, 0, 0, 0);
    }
    bool v0 = amb[ks + lc] > 0;
    bool v1 = amb[ks + 16 + lc] > 0;
    #pragma unroll
    for (int r = 0; r < 4; ++r) {
      float s0 = v0 ? sc0[r] : -1e9f;
      float s1 = v1 ? sc1[r] : -1e9f;
      float rm = fmaxf(s0, s1);
      #pragma unroll
      for (int off = 1; off < 16; off <<= 1) rm = fmaxf(rm, __shfl_xor(rm, off));
      float nm = fmaxf(mrun[r], rm);
      float scal = __expf(mrun[r] - nm);
      float p0 = __expf(s0 - nm);
      float p1 = __expf(s1 - nm);
      float ps = p0 + p1;
      #pragma unroll
      for (int off = 1; off < 16; off <<= 1) ps += __shfl_xor(ps, off);
      lrun[r] = lrun[r] * scal + ps;
      mrun[r] = nm;
      #pragma unroll
      for (int nt = 0; nt < 4; ++nt) o[nt][r] *= scal;
      int prow = lg * 4 + r;
      Plds[wv][prow * 32 + lc] = f2bf(p0);
      Plds[wv][prow * 32 + 16 + lc] = f2bf(p1);
    }
    bv8 ap = *reinterpret_cast<const bv8*>(&Plds[wv][lc * 32 + lg * 8]);
    #pragma unroll
    for (int nt = 0; nt < 4; ++nt) {
      const u16* vr = vb + (size_t)(nt * 16 + lc) * Ss + ks;
      bv8 bvv = *reinterpret_cast<const bv8*>(vr + lg * 8);
      o[nt] = __builtin_amdgcn_mfma_f32_16x16x32_bf16(ap, bvv, o[nt], 0, 0, 0);
    }
  }

  float* pb = part + ((size_t)(bh * 3 + wv) * NCH + ch) * PARTF;
  #pragma unroll
  for (int r = 0; r < 4; ++r) {
    int row = lg * 4 + r;
    #pragma unroll
    for (int nt = 0; nt < 4; ++nt)
      pb[row * 64 + nt * 16 + lc] = o[nt][r];
    if (lc == 0) {
      pb[1024 + row] = mrun[r];
      pb[1040 + row] = lrun[r];
    }
  }
}

// merge NCH chunk-partials and scatter into ctx rows at gpos
__global__ __launch_bounds__(256)
void attn_gmerge_kernel(const float* __restrict__ part, const int* __restrict__ gpos,
                        u16* __restrict__ ctx) {
  __shared__ float wgt[Gg][NCH];
  __shared__ float sinvl[Gg];
  int bh = blockIdx.x;
  int b = bh / Hh, h = bh - b * Hh;
  int tid = threadIdx.x;
  if (tid < Gg) {
    int qt = tid >> 4, rr = tid & 15;
    const float* pb = part + ((size_t)(bh * 3 + qt) * NCH) * PARTF;
    float mx = -1e30f;
    for (int c = 0; c < NCH; ++c) mx = fmaxf(mx, pb[c * PARTF + 1024 + rr]);
    float l = 0.f;
    for (int c = 0; c < NCH; ++c) {
      float w = __expf(pb[c * PARTF + 1024 + rr] - mx);
      wgt[tid][c] = w;
      l += w * pb[c * PARTF + 1040 + rr];
    }
    sinvl[tid] = 1.0f / l;
  }
  __syncthreads();
  for (int e = tid; e < Gg * 64; e += 256) {
    int row = e >> 6, d = e & 63;
    int qt = row >> 4, rr = row & 15;
    const float* pb = part + ((size_t)(bh * 3 + qt) * NCH) * PARTF + rr * 64 + d;
    float acc = 0.f;
    #pragma unroll
    for (int c = 0; c < NCH; ++c) acc += wgt[row][c] * pb[c * PARTF];
    int pos = gpos[b * Gg + row];
    ctx[((size_t)b * Ss + pos) * Dd + h * 64 + d] = f2bf(acc * sinvl[row]);
  }
}

// ---------------- classifier ------------------------------------------------
__global__ __launch_bounds__(64)
void cls_kernel(const float* __restrict__ x, const float* __restrict__ W,
                const float* __restrict__ bias, const int* __restrict__ gpos,
                float* __restrict__ out) {
  int r = blockIdx.x;  // b*32 + i
  int b = r >> 5, i = r & 31;
  int pos = gpos[b * Gg + 1 + i];
  int lane = threadIdx.x;
  const float* xr = x + ((size_t)b * Ss + pos) * Dd;
  float acc[NCLSn] = {0.f, 0.f, 0.f, 0.f, 0.f};
  for (int k = lane; k < Dd; k += 64) {
    float xv = xr[k];
    #pragma unroll
    for (int c = 0; c < NCLSn; ++c) acc[c] += xv * W[c * Dd + k];
  }
  #pragma unroll
  for (int c = 0; c < NCLSn; ++c) {
    #pragma unroll
    for (int off = 1; off < 64; off <<= 1) acc[c] += __shfl_xor(acc[c], off);
  }
  if (lane == 0) {
    #pragma unroll
    for (int c = 0; c < NCLSn; ++c) out[r * NCLSn + c] = acc[c] + bias[c];
  }
}

// ---------------------------------------------------------------------------
extern "C" void kernel_launch(void* const* d_in, const int* in_sizes, int n_in,
                              void* d_out, int out_size, void* d_ws, size_t ws_size,
                              hipStream_t stream) {
  const int* ids     = (const int*)d_in[0];
  const int* amask   = (const int*)d_in[1];
  const float* we    = (const float*)d_in[2];
  const float* pe    = (const float*)d_in[3];
  const float* te    = (const float*)d_in[4];
  const float* embln = (const float*)d_in[5];
  const float* Wqkv  = (const float*)d_in[6];
  const float* bqkv  = (const float*)d_in[7];
  const float* Wqkvg = (const float*)d_in[8];
  const float* bqkvg = (const float*)d_in[9];
  const float* Wo    = (const float*)d_in[10];
  const float* bo    = (const float*)d_in[11];
  const float* ln1   = (const float*)d_in[12];
  const float* Wff1  = (const float*)d_in[13];
  const float* bff1  = (const float*)d_in[14];
  const float* Wff2  = (const float*)d_in[15];
  const float* bff2  = (const float*)d_in[16];
  const float* ln2   = (const float*)d_in[17];
  const float* clsW  = (const float*)d_in[18];
  const float* clsb  = (const float*)d_in[19];
  float* out = (float*)d_out;

  char* ws = (char*)d_ws;
  size_t off = 0;
  auto alloc = [&](size_t bytes) { size_t o = off; off += (bytes + 255) & ~(size_t)255; return o; };

  const size_t DD = (size_t)Dd * Dd;        // 589824
  const size_t DF = (size_t)Dd * 4 * Dd;    // 2359296
  const size_t WL = 7 * DD + 2 * DF;        // elems per layer

  size_t o_cnt  = alloc(Bb * 4);
  size_t o_list = alloc(Bb * 64 * 4);
  size_t o_gpos = alloc(Bb * Gg * 4);
  size_t o_w    = alloc(WL * Ll * 2);
  size_t o_x    = alloc((size_t)Bb * Ss * Dd * 4);
  size_t o_xb   = alloc((size_t)Bb * Ss * Dd * 2);
  size_t o_qpk  = alloc((size_t)Bb * Hh * Ss * 64 * 2);
  size_t o_kpk  = alloc((size_t)Bb * Hh * SPAD * 64 * 2);
  size_t o_vtpk = alloc((size_t)Bb * Hh * 64 * SPAD * 2);
  size_t o_kg   = alloc((size_t)Bb * Hh * 64 * 64 * 2);
  size_t o_vgt  = alloc((size_t)Bb * Hh * 64 * 64 * 2);
  size_t o_xg   = alloc((size_t)128 * Dd * 2);
  size_t o_qg   = alloc((size_t)128 * Dd * 2);
  size_t o_kgf  = alloc((size_t)Bb * Hh * Ss * 64 * 2);
  size_t o_vgf  = alloc((size_t)Bb * Hh * Ss * 64 * 2);
  size_t o_part = alloc((size_t)Bb * Hh * 3 * NCH * PARTF * 4);
  size_t o_f1b  = o_qpk;  // FFN hidden aliases the (dead-by-then) attention buffers
  {
    size_t f1b_bytes = (size_t)Bb * Ss * 4 * Dd * 2;
    if (off - o_qpk < f1b_bytes) off = o_qpk + ((f1b_bytes + 255) & ~(size_t)255);
  }
  size_t o_ctx = alloc((size_t)Bb * Ss * Dd * 2);
  size_t o_acc = alloc((size_t)Bb * Ss * Dd * 4);
  if (ws_size < off) return;  // workspace too small -> fail visibly

  u16* Wb = (u16*)(ws + o_w);
  int* gposp = (int*)(ws + o_gpos);

  (void)hipMemsetAsync(ws + o_cnt, 0, Bb * 4, stream);
  // zero padded K / V^T so first-call pads are finite (later calls: finite stale bf16)
  (void)hipMemsetAsync(ws + o_kpk, 0, (size_t)Bb * Hh * SPAD * 64 * 2, stream);
  (void)hipMemsetAsync(ws + o_vtpk, 0, (size_t)Bb * Hh * 64 * SPAD * 2, stream);

  sep_find_kernel<<<(Bb * Ss + 255) / 256, 256, 0, stream>>>(ids, (int*)(ws + o_cnt), (int*)(ws + o_list));
  sep_sort_kernel<<<Bb, 64, 0, stream>>>((int*)(ws + o_cnt), (int*)(ws + o_list), gposp);

  // weight conversions
  for (int l = 0; l < Ll; ++l) {
    size_t wb = (size_t)l * WL;
    for (int i = 0; i < 3; ++i)
      wconv_kernel<<<dim3(Dd / 32, Dd / 32), 256, 0, stream>>>(Wqkv + ((size_t)l * 3 + i) * DD, Wb + wb + i * DD, Dd, Dd);
    for (int i = 0; i < 3; ++i)
      wconv_kernel<<<dim3(Dd / 32, Dd / 32), 256, 0, stream>>>(Wqkvg + ((size_t)l * 3 + i) * DD, Wb + wb + (3 + i) * DD, Dd, Dd);
    wconv_kernel<<<dim3(Dd / 32, Dd / 32), 256, 0, stream>>>(Wo + (size_t)l * DD, Wb + wb + 6 * DD, Dd, Dd);
    wconv_kernel<<<dim3(4 * Dd / 32, Dd / 32), 256, 0, stream>>>(Wff1 + (size_t)l * DF, Wb + wb + 7 * DD, Dd, 4 * Dd);
    wconv_kernel<<<dim3(Dd / 32, 4 * Dd / 32), 256, 0, stream>>>(Wff2 + (size_t)l * DF, Wb + wb + 7 * DD + DF, 4 * Dd, Dd);
  }

  embed_ln_kernel<<<Bb * Ss, 256, 0, stream>>>(ids, we, pe, te, embln, (float*)(ws + o_x), (u16*)(ws + o_xb));

  for (int l = 0; l < Ll; ++l) {
    size_t wb = (size_t)l * WL;
    u16* xb = (u16*)(ws + o_xb);
    // Q/K/V projections
    gemm_kernel<2, false><<<dim3(6, 64), 256, 0, stream>>>(xb, Wb + wb + 0 * DD, bqkv + (size_t)(l * 3 + 0) * Dd, nullptr, (u16*)(ws + o_qpk), Bb * Ss, Dd, Dd, 0.125f);
    gemm_kernel<3, false><<<dim3(6, 64), 256, 0, stream>>>(xb, Wb + wb + 1 * DD, bqkv + (size_t)(l * 3 + 1) * Dd, nullptr, (u16*)(ws + o_kpk), Bb * Ss, Dd, Dd, 1.0f);
    gemm_kernel<4, false><<<dim3(6, 64), 256, 0, stream>>>(xb, Wb + wb + 2 * DD, bqkv + (size_t)(l * 3 + 2) * Dd, nullptr, (u16*)(ws + o_vtpk), Bb * Ss, Dd, Dd, 1.0f);
    gather_glob_kernel<<<Bb * Hh, 256, 0, stream>>>((u16*)(ws + o_kpk), (u16*)(ws + o_vtpk), gposp, (u16*)(ws + o_kg), (u16*)(ws + o_vgt));
    gather_xg_kernel<<<Bb * Gg, 256, 0, stream>>>(xb, gposp, (u16*)(ws + o_xg));
    // global projections: q_g bf16 [B*G][768]; k_gf packed; v_gf packed-T
    gemm_kernel<1, false><<<dim3(6, 1), 256, 0, stream>>>((u16*)(ws + o_xg), Wb + wb + 3 * DD, bqkvg + (size_t)(l * 3 + 0) * Dd, nullptr, (u16*)(ws + o_qg), Bb * Gg, Dd, Dd, 0.125f);
    gemm_kernel<2, false><<<dim3(6, 64), 256, 0, stream>>>(xb, Wb + wb + 4 * DD, bqkvg + (size_t)(l * 3 + 1) * Dd, nullptr, (u16*)(ws + o_kgf), Bb * Ss, Dd, Dd, 1.0f);
    gemm_kernel<5, false><<<dim3(6, 64), 256, 0, stream>>>(xb, Wb + wb + 5 * DD, bqkvg + (size_t)(l * 3 + 2) * Dd, nullptr, (u16*)(ws + o_vgf), Bb * Ss, Dd, Dd, 1.0f);
    // attention
    attn_local_kernel<<<LOCAL_NB, 256, 0, stream>>>((u16*)(ws + o_qpk), (u16*)(ws + o_kpk), (u16*)(ws + o_vtpk), (u16*)(ws + o_kg), (u16*)(ws + o_vgt), amask, (u16*)(ws + o_ctx));
    attn_globalq_kernel<<<Bb * Hh * NCH, 192, 0, stream>>>((u16*)(ws + o_qg), (u16*)(ws + o_kgf), (u16*)(ws + o_vgf), amask, (float*)(ws + o_part));
    attn_gmerge_kernel<<<Bb * Hh, 256, 0, stream>>>((float*)(ws + o_part), gposp, (u16*)(ws + o_ctx));
    // output projection + LN
    gemm_kernel<0, false><<<dim3(6, 64), 256, 0, stream>>>((u16*)(ws + o_ctx), Wb + wb + 6 * DD, bo + (size_t)l * Dd, (float*)(ws + o_acc), nullptr, Bb * Ss, Dd, Dd, 1.0f);
    add_ln_kernel<<<Bb * Ss, 256, 0, stream>>>((float*)(ws + o_x), (float*)(ws + o_acc), ln1 + (size_t)l * 2 * Dd, (float*)(ws + o_x), xb);
    // FFN
    gemm_kernel<1, true><<<dim3(24, 64), 256, 0, stream>>>(xb, Wb + wb + 7 * DD, bff1 + (size_t)l * 4 * Dd, nullptr, (u16*)(ws + o_f1b), Bb * Ss, 4 * Dd, Dd, 1.0f);
    gemm_kernel<0, false><<<dim3(6, 64), 256, 0, stream>>>((u16*)(ws + o_f1b), Wb + wb + 7 * DD + DF, bff2 + (size_t)l * Dd, (float*)(ws + o_acc), nullptr, Bb * Ss, Dd, 4 * Dd, 1.0f);
    add_ln_kernel<<<Bb * Ss, 256, 0, stream>>>((float*)(ws + o_x), (float*)(ws + o_acc), ln2 + (size_t)l * 2 * Dd, (float*)(ws + o_x), xb);
  }

  cls_kernel<<<Bb * NSEPn, 64, 0, stream>>>((float*)(ws + o_x), clsW, clsb, gposp, out);
}

// Round 4
// 1009.560 us; speedup vs baseline: 2.1018x; 1.2228x over previous
//
#include <hip/hip_runtime.h>

// ---------------------------------------------------------------------------
// Longformer (2-layer) forward, MI355X.
// R3: (a) swapped-QK^T lane-local softmax in attn_local (2 shuffles/step vs 32)
//     (b) GEMMs rebuilt with global_load_lds width-16 staging, fused QKV
//         (N=2304) and fused global-KV (N=1536) epilogues, batched wconv.
// ---------------------------------------------------------------------------

#define Bb 2
#define Ss 4096
#define Dd 768
#define Hh 12
#define Gg 33
#define NSEPn 32
#define Ll 2
#define SPAD 4640   // S + 544 (PADL=256 left, 288 right)
#define PADL 256
#define NCLSn 5
#define NCH 16      // key chunks for global-q attention (256 keys each)
#define PARTF 1056  // floats per (bh,qt,chunk) partial: 16*64 o + 16 m + 16 l

typedef unsigned short u16;
typedef __attribute__((ext_vector_type(8))) short bv8;   // 8 x bf16
typedef __attribute__((ext_vector_type(4))) short sv4;   // 4 x bf16
typedef __attribute__((ext_vector_type(4))) float f32x4;

__device__ __forceinline__ float bf2f(u16 u) {
  unsigned v = ((unsigned)u) << 16;
  return __builtin_bit_cast(float, v);
}
__device__ __forceinline__ u16 f2bf(float f) {
  unsigned u = __builtin_bit_cast(unsigned, f);
  u += 0x7fffu + ((u >> 16) & 1u);
  return (u16)(u >> 16);
}
__device__ __forceinline__ void glds16(const void* g, void* l) {
  __builtin_amdgcn_global_load_lds(
      (const __attribute__((address_space(1))) void*)g,
      (__attribute__((address_space(3))) void*)l, 16, 0, 0);
}

// ---------------- sep finding --------------------------------------------
__global__ void sep_find_kernel(const int* __restrict__ ids, int* __restrict__ cnt,
                                int* __restrict__ list) {
  int i = blockIdx.x * 256 + threadIdx.x;
  if (i >= Bb * Ss) return;
  int b = i >> 12;
  if (ids[i] == 2) {
    int idx = atomicAdd(&cnt[b], 1);
    if (idx < 64) list[b * 64 + idx] = i & (Ss - 1);
  }
}

__global__ void sep_sort_kernel(const int* __restrict__ cnt, const int* __restrict__ list,
                                int* __restrict__ gpos) {
  int b = blockIdx.x;
  int t = threadIdx.x;
  int n = cnt[b]; if (n > 64) n = 64;
  if (t < Gg) gpos[b * Gg + t] = (t == 0) ? 0 : (Ss - 1);
  __syncthreads();
  if (t < n) {
    int v = list[b * 64 + t];
    int rank = 0;
    for (int j = 0; j < n; ++j) rank += (list[b * 64 + j] < v) ? 1 : 0;
    if (rank < NSEPn) gpos[b * Gg + 1 + rank] = v;
  }
}

// ---------------- weight fp32 (K,N) -> bf16 (N,K), batched over z -----------
__global__ __launch_bounds__(256)
void wconv_kernel(const float* __restrict__ src0, u16* __restrict__ dst0,
                  int K, int N, int grp, long unit, long WLs) {
  __shared__ float t[32][33];
  int z = blockIdx.z;
  const float* src = src0 + (size_t)z * K * N;
  u16* dst = dst0 + (size_t)(z / grp) * WLs + (size_t)(z % grp) * unit;
  int n0 = blockIdx.x * 32, k0 = blockIdx.y * 32;
  int tx = threadIdx.x & 31, ty = threadIdx.x >> 5;  // ty 0..7
  #pragma unroll
  for (int i = 0; i < 4; ++i)
    t[ty + i * 8][tx] = src[(size_t)(k0 + ty + i * 8) * N + n0 + tx];
  __syncthreads();
  #pragma unroll
  for (int i = 0; i < 4; ++i)
    dst[(size_t)(n0 + ty + i * 8) * K + k0 + tx] = f2bf(t[tx][ty + i * 8]);
}

// ---------------- embedding + LN -------------------------------------------
__global__ __launch_bounds__(256)
void embed_ln_kernel(const int* __restrict__ ids, const float* __restrict__ we,
                     const float* __restrict__ pe, const float* __restrict__ te,
                     const float* __restrict__ lnp, float* __restrict__ x,
                     u16* __restrict__ xb) {
  int row = blockIdx.x;
  int s = row & (Ss - 1);
  int id = ids[row];
  int tid = threadIdx.x;
  float v[3]; float sm = 0.f, s2 = 0.f;
  #pragma unroll
  for (int i = 0; i < 3; ++i) {
    int c = tid + i * 256;
    float t = we[(size_t)id * Dd + c] + pe[(size_t)(s + 2) * Dd + c] + te[c];
    v[i] = t; sm += t; s2 += t * t;
  }
  __shared__ float r1[256], r2[256];
  r1[tid] = sm; r2[tid] = s2; __syncthreads();
  for (int o = 128; o; o >>= 1) {
    if (tid < o) { r1[tid] += r1[tid + o]; r2[tid] += r2[tid + o]; }
    __syncthreads();
  }
  float mean = r1[0] * (1.f / 768.f);
  float var  = r2[0] * (1.f / 768.f) - mean * mean;
  float rs = rsqrtf(var + 1e-5f);
  #pragma unroll
  for (int i = 0; i < 3; ++i) {
    int c = tid + i * 256;
    float o = (v[i] - mean) * rs * lnp[c] + lnp[Dd + c];
    x[(size_t)row * Dd + c] = o;
    xb[(size_t)row * Dd + c] = f2bf(o);
  }
}

// ---------------- residual + LN --------------------------------------------
__global__ __launch_bounds__(256)
void add_ln_kernel(const float* __restrict__ xin, const float* __restrict__ y,
                   const float* __restrict__ lnp, float* __restrict__ xout,
                   u16* __restrict__ xbout) {
  int row = blockIdx.x;
  int tid = threadIdx.x;
  float v[3]; float sm = 0.f, s2 = 0.f;
  #pragma unroll
  for (int i = 0; i < 3; ++i) {
    int c = tid + i * 256;
    float t = xin[(size_t)row * Dd + c] + y[(size_t)row * Dd + c];
    v[i] = t; sm += t; s2 += t * t;
  }
  __shared__ float r1[256], r2[256];
  r1[tid] = sm; r2[tid] = s2; __syncthreads();
  for (int o = 128; o; o >>= 1) {
    if (tid < o) { r1[tid] += r1[tid + o]; r2[tid] += r2[tid + o]; }
    __syncthreads();
  }
  float mean = r1[0] * (1.f / 768.f);
  float var  = r2[0] * (1.f / 768.f) - mean * mean;
  float rs = rsqrtf(var + 1e-5f);
  #pragma unroll
  for (int i = 0; i < 3; ++i) {
    int c = tid + i * 256;
    float o = (v[i] - mean) * rs * lnp[c] + lnp[Dd + c];
    xout[(size_t)row * Dd + c] = o;
    xbout[(size_t)row * Dd + c] = f2bf(o);
  }
}

// ---------------- GEMM2: glds-staged 128x128xK, M % 128 == 0 ---------------
// MODE 0: fp32 [M][N] (+bias)
// MODE 1: bf16 [M][N], exact gelu
// MODE 2: fused QKV: N=2304; sec0->q packed (scale), sec1->k padded, sec2->v^T padded
// MODE 3: fused gKV:  N=1536; sec0->k packed, sec1->v^T [bh][64][Ss]
// MODE 4: bf16 [M][N] * scale
template <int MODE>
__global__ __launch_bounds__(256)
void gemm2_kernel(const u16* __restrict__ A, const u16* __restrict__ Bt,
                  const float* __restrict__ bias, float* __restrict__ outf,
                  u16* __restrict__ o0, u16* __restrict__ o1, u16* __restrict__ o2,
                  int N, int K, float scale) {
  __shared__ u16 la[128 * 32], lb[128 * 32];
  int tid = threadIdx.x;
  int wave = tid >> 6, lane = tid & 63;
  int wr = wave >> 1, wc = wave & 1;
  int lg = lane >> 4, lc = lane & 15;
  int row0 = blockIdx.y * 128, col0 = blockIdx.x * 128;

  const u16* Ag = A + (size_t)(row0 + wave * 32 + (lane >> 2)) * K + (lane & 3) * 8;
  const u16* Bg = Bt + (size_t)(col0 + wave * 32 + (lane >> 2)) * K + (lane & 3) * 8;
  u16* lA = la + wave * 1024;
  u16* lB = lb + wave * 1024;

  f32x4 acc[4][4];
  #pragma unroll
  for (int m = 0; m < 4; ++m)
    #pragma unroll
    for (int n = 0; n < 4; ++n) acc[m][n] = (f32x4){0.f, 0.f, 0.f, 0.f};

  for (int k0 = 0; k0 < K; k0 += 32) {
    glds16(Ag + k0, lA);
    glds16(Ag + (size_t)16 * K + k0, lA + 512);
    glds16(Bg + k0, lB);
    glds16(Bg + (size_t)16 * K + k0, lB + 512);
    __syncthreads();
    bv8 af[4], bf_[4];
    #pragma unroll
    for (int m = 0; m < 4; ++m)
      af[m] = *reinterpret_cast<const bv8*>(la + (wr * 64 + m * 16 + lc) * 32 + lg * 8);
    #pragma unroll
    for (int n = 0; n < 4; ++n)
      bf_[n] = *reinterpret_cast<const bv8*>(lb + (wc * 64 + n * 16 + lc) * 32 + lg * 8);
    #pragma unroll
    for (int m = 0; m < 4; ++m)
      #pragma unroll
      for (int n = 0; n < 4; ++n)
        acc[m][n] = __builtin_amdgcn_mfma_f32_16x16x32_bf16(af[m], bf_[n], acc[m][n], 0, 0, 0);
    __syncthreads();
  }

  #pragma unroll
  for (int m = 0; m < 4; ++m) {
    int grow0 = row0 + wr * 64 + m * 16 + lg * 4;
    #pragma unroll
    for (int n = 0; n < 4; ++n) {
      int gcol = col0 + wc * 64 + n * 16 + lc;
      float bvl = bias[gcol];
      if (MODE == 0) {
        #pragma unroll
        for (int r = 0; r < 4; ++r)
          outf[(size_t)(grow0 + r) * N + gcol] = acc[m][n][r] + bvl;
      } else if (MODE == 1) {
        #pragma unroll
        for (int r = 0; r < 4; ++r) {
          float v = acc[m][n][r] + bvl;
          v = 0.5f * v * (1.0f + erff(v * 0.70710678118654752f));
          o0[(size_t)(grow0 + r) * N + gcol] = f2bf(v);
        }
      } else if (MODE == 4) {
        #pragma unroll
        for (int r = 0; r < 4; ++r)
          o0[(size_t)(grow0 + r) * N + gcol] = f2bf((acc[m][n][r] + bvl) * scale);
      } else if (MODE == 2) {
        int sec = col0 >= 1536 ? 2 : (col0 >= 768 ? 1 : 0);
        int colr = gcol - sec * 768;
        int hh = colr >> 6, d = colr & 63;
        int bb = grow0 >> 12, s = grow0 & (Ss - 1);
        size_t bhh = (size_t)(bb * Hh + hh);
        if (sec == 0) {
          #pragma unroll
          for (int r = 0; r < 4; ++r)
            o0[(bhh * Ss + s + r) * 64 + d] = f2bf((acc[m][n][r] + bvl) * scale);
        } else if (sec == 1) {
          #pragma unroll
          for (int r = 0; r < 4; ++r)
            o1[(bhh * SPAD + PADL + s + r) * 64 + d] = f2bf(acc[m][n][r] + bvl);
        } else {
          sv4 pk;
          #pragma unroll
          for (int r = 0; r < 4; ++r) pk[r] = (short)f2bf(acc[m][n][r] + bvl);
          *reinterpret_cast<sv4*>(o2 + (bhh * 64 + d) * SPAD + PADL + s) = pk;
        }
      } else if (MODE == 3) {
        int sec = col0 >= 768 ? 1 : 0;
        int colr = gcol - sec * 768;
        int hh = colr >> 6, d = colr & 63;
        int bb = grow0 >> 12, s = grow0 & (Ss - 1);
        size_t bhh = (size_t)(bb * Hh + hh);
        if (sec == 0) {
          #pragma unroll
          for (int r = 0; r < 4; ++r)
            o0[(bhh * Ss + s + r) * 64 + d] = f2bf(acc[m][n][r] + bvl);
        } else {
          sv4 pk;
          #pragma unroll
          for (int r = 0; r < 4; ++r) pk[r] = (short)f2bf(acc[m][n][r] + bvl);
          *reinterpret_cast<sv4*>(o1 + (bhh * 64 + d) * Ss + s) = pk;
        }
      }
    }
  }
}

// ---------------- gathers ---------------------------------------------------
__global__ __launch_bounds__(256)
void gather_glob_kernel(const u16* __restrict__ kpk, const u16* __restrict__ vtpk,
                        const int* __restrict__ gpos, u16* __restrict__ kg,
                        u16* __restrict__ vgt) {
  int bh = blockIdx.x;
  int b = bh / Hh;
  int tid = threadIdx.x;
  for (int idx = tid; idx < 64 * 64; idx += 256) {
    int g = idx >> 6, d = idx & 63;
    u16 kv = 0, vv = 0;
    if (g < Gg) {
      int p = gpos[b * Gg + g];
      kv = kpk[((size_t)bh * SPAD + PADL + p) * 64 + d];
      vv = vtpk[((size_t)bh * 64 + d) * SPAD + PADL + p];
    }
    kg[(size_t)bh * 4096 + idx] = kv;
    vgt[((size_t)bh * 64 + d) * 64 + g] = vv;
  }
}

__global__ __launch_bounds__(256)
void gather_xg_kernel(const u16* __restrict__ xb, const int* __restrict__ gpos,
                      u16* __restrict__ xg) {
  int rg = blockIdx.x;  // b*G+g
  int b = rg / Gg;
  int p = gpos[rg];
  int tid = threadIdx.x;
  for (int c = tid; c < Dd; c += 256)
    xg[(size_t)rg * Dd + c] = xb[((size_t)b * Ss + p) * Dd + c];
}

// ---------------- local (sliding window + global-key) attention -------------
// 4 waves/block, 64 consecutive queries; XCD swizzle; swapped-QK^T softmax:
// mfma(K,Q) => S^T (row=key, col=query) so each lane owns ONE query and the
// key-reduction is in-register + 2 shuffles instead of 32.
#define LOCAL_NB (Bb * Hh * (Ss / 64))   // 1536 blocks, %8 == 0
__global__ __launch_bounds__(256)
void attn_local_kernel(const u16* __restrict__ qpk, const u16* __restrict__ kpk,
                       const u16* __restrict__ vtpk, const u16* __restrict__ kg,
                       const u16* __restrict__ vgt, const int* __restrict__ amask,
                       u16* __restrict__ ctx) {
  __shared__ u16 Plds[4][16 * 32];
  int bid = blockIdx.x;
  int swz = (bid & 7) * (LOCAL_NB / 8) + (bid >> 3);
  int qb = swz & 63;
  int bh = swz >> 6;
  int b = bh / Hh;
  int h = bh - b * Hh;
  int wv = threadIdx.x >> 6;
  int q0 = qb * 64 + wv * 16;
  int lane = threadIdx.x & 63;
  int lg = lane >> 4, lc = lane & 15;
  int lg4 = lg * 4;

  const u16* qbase = qpk + (((size_t)bh) * Ss + q0) * 64;
  bv8 aq0 = *reinterpret_cast<const bv8*>(qbase + (size_t)lc * 64 + lg * 8);
  bv8 aq1 = *reinterpret_cast<const bv8*>(qbase + (size_t)lc * 64 + 32 + lg * 8);

  f32x4 o[4];
  #pragma unroll
  for (int i = 0; i < 4; ++i) o[i] = (f32x4){0.f, 0.f, 0.f, 0.f};
  float mrun = -1e30f, lrun = 0.f;   // softmax state for query q0+lc
  int q = q0 + lc;

  const u16* kgb = kg + ((size_t)bh) * 64 * 64;
  const u16* vgb = vgt + ((size_t)bh) * 64 * 64;
  const u16* kb = kpk + ((size_t)bh) * SPAD * 64;
  const u16* vb = vtpk + ((size_t)bh) * 64 * SPAD;
  const int* amb = amask + b * Ss;

  for (int step = 0; step < 19; ++step) {
    bool isg = (step < 2);
    int ks = isg ? (step * 32) : (q0 - 256 + (step - 2) * 32);
    f32x4 sc0, sc1;
    {
      const u16* kr0 = isg ? (kgb + (size_t)(ks + lc) * 64)
                           : (kb + (size_t)(PADL + ks + lc) * 64);
      const u16* kr1 = kr0 + 16 * 64;
      bv8 b00 = *reinterpret_cast<const bv8*>(kr0 + lg * 8);
      bv8 b01 = *reinterpret_cast<const bv8*>(kr0 + 32 + lg * 8);
      bv8 b10 = *reinterpret_cast<const bv8*>(kr1 + lg * 8);
      bv8 b11 = *reinterpret_cast<const bv8*>(kr1 + 32 + lg * 8);
      f32x4 z = (f32x4){0.f, 0.f, 0.f, 0.f};
      // swapped operands: A=K rows (m=key), B=Q rows (n=query)
      sc0 = __builtin_amdgcn_mfma_f32_16x16x32_bf16(b00, aq0, z, 0, 0, 0);
      sc0 = __builtin_amdgcn_mfma_f32_16x16x32_bf16(b01, aq1, sc0, 0, 0, 0);
      sc1 = __builtin_amdgcn_mfma_f32_16x16x32_bf16(b10, aq0, z, 0, 0, 0);
      sc1 = __builtin_amdgcn_mfma_f32_16x16x32_bf16(b11, aq1, sc1, 0, 0, 0);
    }
    // mask (this lane's query = q; element r has key ks+lg4+r / +16)
    float mloc = -1e30f;
    #pragma unroll
    for (int r = 0; r < 4; ++r) {
      int k0r = ks + lg4 + r, k1r = k0r + 16;
      bool b0, b1;
      if (isg) {
        b0 = k0r < Gg; b1 = k1r < Gg;
      } else {
        int kc0 = min(max(k0r, 0), Ss - 1);
        int kc1 = min(max(k1r, 0), Ss - 1);
        b0 = ((unsigned)(k0r - q + 256) <= 512u) && (k0r >= 0) && (k0r < Ss) && (amb[kc0] > 0);
        b1 = ((unsigned)(k1r - q + 256) <= 512u) && (k1r >= 0) && (k1r < Ss) && (amb[kc1] > 0);
      }
      sc0[r] = b0 ? sc0[r] : -1e9f;
      sc1[r] = b1 ? sc1[r] : -1e9f;
      mloc = fmaxf(mloc, fmaxf(sc0[r], sc1[r]));
    }
    mloc = fmaxf(mloc, __shfl_xor(mloc, 16));
    mloc = fmaxf(mloc, __shfl_xor(mloc, 32));
    if (__any(mloc > mrun)) {
      float nm = fmaxf(mrun, mloc);
      float scal = __expf(mrun - nm);
      mrun = nm;
      lrun *= scal;
      #pragma unroll
      for (int r = 0; r < 4; ++r) {
        float sr = __shfl(scal, lg4 + r);
        #pragma unroll
        for (int nt = 0; nt < 4; ++nt) o[nt][r] *= sr;
      }
    }
    float psum = 0.f;
    sv4 pk0, pk1;
    #pragma unroll
    for (int r = 0; r < 4; ++r) {
      float p0 = __expf(sc0[r] - mrun);
      float p1 = __expf(sc1[r] - mrun);
      psum += p0 + p1;
      pk0[r] = (short)f2bf(p0);
      pk1[r] = (short)f2bf(p1);
    }
    *reinterpret_cast<sv4*>(&Plds[wv][lc * 32 + lg4]) = pk0;
    *reinterpret_cast<sv4*>(&Plds[wv][lc * 32 + 16 + lg4]) = pk1;
    psum += __shfl_xor(psum, 16);
    psum += __shfl_xor(psum, 32);
    lrun += psum;
    bv8 ap = *reinterpret_cast<const bv8*>(&Plds[wv][lc * 32 + lg * 8]);
    #pragma unroll
    for (int nt = 0; nt < 4; ++nt) {
      const u16* vr = isg ? (vgb + (size_t)(nt * 16 + lc) * 64 + ks)
                          : (vb + (size_t)(nt * 16 + lc) * SPAD + PADL + ks);
      bv8 bvv = *reinterpret_cast<const bv8*>(vr + lg * 8);
      o[nt] = __builtin_amdgcn_mfma_f32_16x16x32_bf16(ap, bvv, o[nt], 0, 0, 0);
    }
  }
  float inv = 1.0f / lrun;
  #pragma unroll
  for (int r = 0; r < 4; ++r) {
    float invr = __shfl(inv, lg4 + r);
    size_t rowoff = ((size_t)b * Ss + q0 + lg4 + r) * Dd + h * 64;
    #pragma unroll
    for (int nt = 0; nt < 4; ++nt)
      ctx[rowoff + nt * 16 + lc] = f2bf(o[nt][r] * invr);
  }
}

// ---------------- global-query attention: chunked flash MFMA ----------------
__global__ __launch_bounds__(192)
void attn_globalq_kernel(const u16* __restrict__ qgb, const u16* __restrict__ kgf,
                         const u16* __restrict__ vgt, const int* __restrict__ amask,
                         float* __restrict__ part) {
  __shared__ u16 Plds[3][16 * 32];
  int blk = blockIdx.x;
  int ch = blk & (NCH - 1);
  int bh = blk / NCH;
  int b = bh / Hh, h = bh - b * Hh;
  int wv = threadIdx.x >> 6;  // q-tile 0..2
  int lane = threadIdx.x & 63;
  int lg = lane >> 4, lc = lane & 15;

  int qrow = wv * 16 + lc;
  bv8 aq0 = (bv8)0, aq1 = (bv8)0;
  if (qrow < Gg) {
    const u16* qr = qgb + (size_t)(b * Gg + qrow) * Dd + h * 64;
    aq0 = *reinterpret_cast<const bv8*>(qr + lg * 8);
    aq1 = *reinterpret_cast<const bv8*>(qr + 32 + lg * 8);
  }

  f32x4 o[4];
  float mrun[4], lrun[4];
  #pragma unroll
  for (int i = 0; i < 4; ++i) { o[i] = (f32x4){0.f,0.f,0.f,0.f}; mrun[i] = -1e30f; lrun[i] = 0.f; }

  const u16* kb = kgf + ((size_t)bh) * Ss * 64;
  const u16* vb = vgt + ((size_t)bh) * 64 * Ss;
  const int* amb = amask + b * Ss;
  int ks0 = ch * (Ss / NCH);

  for (int st = 0; st < (Ss / NCH) / 32; ++st) {
    int ks = ks0 + st * 32;
    f32x4 sc0, sc1;
    {
      const u16* kr0 = kb + (size_t)(ks + lc) * 64;
      const u16* kr1 = kr0 + 16 * 64;
      bv8 b00 = *reinterpret_cast<const bv8*>(kr0 + lg * 8);
      bv8 b01 = *reinterpret_cast<const bv8*>(kr0 + 32 + lg * 8);
      bv8 b10 = *reinterpret_cast<const bv8*>(kr1 + lg * 8);
      bv8 b11 = *reinterpret_cast<const bv8*>(kr1 + 32 + lg * 8);
      f32x4 z = (f32x4){0.f,0.f,0.f,0.f};
      sc0 = __builtin_amdgcn_mfma_f32_16x16x32_bf16(aq0, b00, z, 0, 0, 0);
      sc0 = __builtin_amdgcn_mfma_f32_16x16x32_bf16(aq1, b01, sc0, 0, 0, 0);
      sc1 = __builtin_amdgcn_mfma_f32_16x16x32_bf16(aq0, b10, z, 0, 0, 0);
      sc1 = __builtin_amdgcn_mfma_f32_16x16x32_bf16(aq1, b11, sc1, 0, 0, 0);
    }
    bool v0 = amb[ks + lc] > 0;
    bool v1 = amb[ks + 16 + lc] > 0;
    #pragma unroll
    for (int r = 0; r < 4; ++r) {
      float s0 = v0 ? sc0[r] : -1e9f;
      float s1 = v1 ? sc1[r] : -1e9f;
      float rm = fmaxf(s0, s1);
      #pragma unroll
      for (int off = 1; off < 16; off <<= 1) rm = fmaxf(rm, __shfl_xor(rm, off));
      float nm = fmaxf(mrun[r], rm);
      float scal = __expf(mrun[r] - nm);
      float p0 = __expf(s0 - nm);
      float p1 = __expf(s1 - nm);
      float ps = p0 + p1;
      #pragma unroll
      for (int off = 1; off < 16; off <<= 1) ps += __shfl_xor(ps, off);
      lrun[r] = lrun[r] * scal + ps;
      mrun[r] = nm;
      #pragma unroll
      for (int nt = 0; nt < 4; ++nt) o[nt][r] *= scal;
      int prow = lg * 4 + r;
      Plds[wv][prow * 32 + lc] = f2bf(p0);
      Plds[wv][prow * 32 + 16 + lc] = f2bf(p1);
    }
    bv8 ap = *reinterpret_cast<const bv8*>(&Plds[wv][lc * 32 + lg * 8]);
    #pragma unroll
    for (int nt = 0; nt < 4; ++nt) {
      const u16* vr = vb + (size_t)(nt * 16 + lc) * Ss + ks;
      bv8 bvv = *reinterpret_cast<const bv8*>(vr + lg * 8);
      o[nt] = __builtin_amdgcn_mfma_f32_16x16x32_bf16(ap, bvv, o[nt], 0, 0, 0);
    }
  }

  float* pb = part + ((size_t)(bh * 3 + wv) * NCH + ch) * PARTF;
  #pragma unroll
  for (int r = 0; r < 4; ++r) {
    int row = lg * 4 + r;
    #pragma unroll
    for (int nt = 0; nt < 4; ++nt)
      pb[row * 64 + nt * 16 + lc] = o[nt][r];
    if (lc == 0) {
      pb[1024 + row] = mrun[r];
      pb[1040 + row] = lrun[r];
    }
  }
}

// merge NCH chunk-partials and scatter into ctx rows at gpos
__global__ __launch_bounds__(256)
void attn_gmerge_kernel(const float* __restrict__ part, const int* __restrict__ gpos,
                        u16* __restrict__ ctx) {
  __shared__ float wgt[Gg][NCH];
  __shared__ float sinvl[Gg];
  int bh = blockIdx.x;
  int b = bh / Hh, h = bh - b * Hh;
  int tid = threadIdx.x;
  if (tid < Gg) {
    int qt = tid >> 4, rr = tid & 15;
    const float* pb = part + ((size_t)(bh * 3 + qt) * NCH) * PARTF;
    float mx = -1e30f;
    for (int c = 0; c < NCH; ++c) mx = fmaxf(mx, pb[c * PARTF + 1024 + rr]);
    float l = 0.f;
    for (int c = 0; c < NCH; ++c) {
      float w = __expf(pb[c * PARTF + 1024 + rr] - mx);
      wgt[tid][c] = w;
      l += w * pb[c * PARTF + 1040 + rr];
    }
    sinvl[tid] = 1.0f / l;
  }
  __syncthreads();
  for (int e = tid; e < Gg * 64; e += 256) {
    int row = e >> 6, d = e & 63;
    int qt = row >> 4, rr = row & 15;
    const float* pb = part + ((size_t)(bh * 3 + qt) * NCH) * PARTF + rr * 64 + d;
    float acc = 0.f;
    #pragma unroll
    for (int c = 0; c < NCH; ++c) acc += wgt[row][c] * pb[c * PARTF];
    int pos = gpos[b * Gg + row];
    ctx[((size_t)b * Ss + pos) * Dd + h * 64 + d] = f2bf(acc * sinvl[row]);
  }
}

// ---------------- classifier ------------------------------------------------
__global__ __launch_bounds__(64)
void cls_kernel(const float* __restrict__ x, const float* __restrict__ W,
                const float* __restrict__ bias, const int* __restrict__ gpos,
                float* __restrict__ out) {
  int r = blockIdx.x;  // b*32 + i
  int b = r >> 5, i = r & 31;
  int pos = gpos[b * Gg + 1 + i];
  int lane = threadIdx.x;
  const float* xr = x + ((size_t)b * Ss + pos) * Dd;
  float acc[NCLSn] = {0.f, 0.f, 0.f, 0.f, 0.f};
  for (int k = lane; k < Dd; k += 64) {
    float xv = xr[k];
    #pragma unroll
    for (int c = 0; c < NCLSn; ++c) acc[c] += xv * W[c * Dd + k];
  }
  #pragma unroll
  for (int c = 0; c < NCLSn; ++c) {
    #pragma unroll
    for (int off = 1; off < 64; off <<= 1) acc[c] += __shfl_xor(acc[c], off);
  }
  if (lane == 0) {
    #pragma unroll
    for (int c = 0; c < NCLSn; ++c) out[r * NCLSn + c] = acc[c] + bias[c];
  }
}

// ---------------------------------------------------------------------------
extern "C" void kernel_launch(void* const* d_in, const int* in_sizes, int n_in,
                              void* d_out, int out_size, void* d_ws, size_t ws_size,
                              hipStream_t stream) {
  const int* ids     = (const int*)d_in[0];
  const int* amask   = (const int*)d_in[1];
  const float* we    = (const float*)d_in[2];
  const float* pe    = (const float*)d_in[3];
  const float* te    = (const float*)d_in[4];
  const float* embln = (const float*)d_in[5];
  const float* Wqkv  = (const float*)d_in[6];
  const float* bqkv  = (const float*)d_in[7];
  const float* Wqkvg = (const float*)d_in[8];
  const float* bqkvg = (const float*)d_in[9];
  const float* Wo    = (const float*)d_in[10];
  const float* bo    = (const float*)d_in[11];
  const float* ln1   = (const float*)d_in[12];
  const float* Wff1  = (const float*)d_in[13];
  const float* bff1  = (const float*)d_in[14];
  const float* Wff2  = (const float*)d_in[15];
  const float* bff2  = (const float*)d_in[16];
  const float* ln2   = (const float*)d_in[17];
  const float* clsW  = (const float*)d_in[18];
  const float* clsb  = (const float*)d_in[19];
  float* out = (float*)d_out;

  char* ws = (char*)d_ws;
  size_t off = 0;
  auto alloc = [&](size_t bytes) { size_t o = off; off += (bytes + 255) & ~(size_t)255; return o; };

  const size_t DD = (size_t)Dd * Dd;        // 589824
  const size_t DF = (size_t)Dd * 4 * Dd;    // 2359296
  const size_t WL = 7 * DD + 2 * DF;        // elems per layer

  size_t o_cnt  = alloc(Bb * 4);
  size_t o_list = alloc(Bb * 64 * 4);
  size_t o_gpos = alloc(Bb * Gg * 4);
  size_t o_w    = alloc(WL * Ll * 2);
  size_t o_x    = alloc((size_t)Bb * Ss * Dd * 4);
  size_t o_xb   = alloc((size_t)Bb * Ss * Dd * 2);
  size_t o_qpk  = alloc((size_t)Bb * Hh * Ss * 64 * 2);
  size_t o_kpk  = alloc((size_t)Bb * Hh * SPAD * 64 * 2);
  size_t o_vtpk = alloc((size_t)Bb * Hh * 64 * SPAD * 2);
  size_t o_kg   = alloc((size_t)Bb * Hh * 64 * 64 * 2);
  size_t o_vgt  = alloc((size_t)Bb * Hh * 64 * 64 * 2);
  size_t o_xg   = alloc((size_t)128 * Dd * 2);
  size_t o_qg   = alloc((size_t)128 * Dd * 2);
  size_t o_kgf  = alloc((size_t)Bb * Hh * Ss * 64 * 2);
  size_t o_vgf  = alloc((size_t)Bb * Hh * Ss * 64 * 2);
  size_t o_part = alloc((size_t)Bb * Hh * 3 * NCH * PARTF * 4);
  size_t o_f1b  = o_qpk;  // FFN hidden aliases the (dead-by-then) attention buffers
  {
    size_t f1b_bytes = (size_t)Bb * Ss * 4 * Dd * 2;
    if (off - o_qpk < f1b_bytes) off = o_qpk + ((f1b_bytes + 255) & ~(size_t)255);
  }
  size_t o_ctx = alloc((size_t)Bb * Ss * Dd * 2);
  size_t o_acc = alloc((size_t)Bb * Ss * Dd * 4);
  if (ws_size < off) return;  // workspace too small -> fail visibly

  u16* Wb = (u16*)(ws + o_w);
  int* gposp = (int*)(ws + o_gpos);

  (void)hipMemsetAsync(ws + o_cnt, 0, Bb * 4, stream);
  // zero padded K / V^T so first-call pads are finite (later calls: finite stale bf16)
  (void)hipMemsetAsync(ws + o_kpk, 0, (size_t)Bb * Hh * SPAD * 64 * 2, stream);
  (void)hipMemsetAsync(ws + o_vtpk, 0, (size_t)Bb * Hh * 64 * SPAD * 2, stream);
  (void)hipMemsetAsync(ws + o_xg, 0, (size_t)128 * Dd * 2, stream);

  sep_find_kernel<<<(Bb * Ss + 255) / 256, 256, 0, stream>>>(ids, (int*)(ws + o_cnt), (int*)(ws + o_list));
  sep_sort_kernel<<<Bb, 64, 0, stream>>>((int*)(ws + o_cnt), (int*)(ws + o_list), gposp);

  // weight conversions (batched over z)
  wconv_kernel<<<dim3(24, 24, 6), 256, 0, stream>>>(Wqkv,  Wb,          Dd, Dd, 3, (long)DD, (long)WL);
  wconv_kernel<<<dim3(24, 24, 6), 256, 0, stream>>>(Wqkvg, Wb + 3 * DD, Dd, Dd, 3, (long)DD, (long)WL);
  wconv_kernel<<<dim3(24, 24, 2), 256, 0, stream>>>(Wo,    Wb + 6 * DD, Dd, Dd, 1, 0L, (long)WL);
  wconv_kernel<<<dim3(96, 24, 2), 256, 0, stream>>>(Wff1,  Wb + 7 * DD, Dd, 4 * Dd, 1, 0L, (long)WL);
  wconv_kernel<<<dim3(24, 96, 2), 256, 0, stream>>>(Wff2,  Wb + 7 * DD + DF, 4 * Dd, Dd, 1, 0L, (long)WL);

  embed_ln_kernel<<<Bb * Ss, 256, 0, stream>>>(ids, we, pe, te, embln, (float*)(ws + o_x), (u16*)(ws + o_xb));

  for (int l = 0; l < Ll; ++l) {
    size_t wb = (size_t)l * WL;
    u16* xb = (u16*)(ws + o_xb);
    // fused QKV projection (N=2304)
    gemm2_kernel<2><<<dim3(18, 64), 256, 0, stream>>>(xb, Wb + wb, bqkv + (size_t)l * 3 * Dd, nullptr,
        (u16*)(ws + o_qpk), (u16*)(ws + o_kpk), (u16*)(ws + o_vtpk), 2304, Dd, 0.125f);
    gather_glob_kernel<<<Bb * Hh, 256, 0, stream>>>((u16*)(ws + o_kpk), (u16*)(ws + o_vtpk), gposp, (u16*)(ws + o_kg), (u16*)(ws + o_vgt));
    gather_xg_kernel<<<Bb * Gg, 256, 0, stream>>>(xb, gposp, (u16*)(ws + o_xg));
    // global q projection (M=128 padded rows)
    gemm2_kernel<4><<<dim3(6, 1), 256, 0, stream>>>((u16*)(ws + o_xg), Wb + wb + 3 * DD, bqkvg + (size_t)l * 3 * Dd, nullptr,
        (u16*)(ws + o_qg), nullptr, nullptr, Dd, Dd, 0.125f);
    // fused global K/V (N=1536)
    gemm2_kernel<3><<<dim3(12, 64), 256, 0, stream>>>(xb, Wb + wb + 4 * DD, bqkvg + (size_t)(l * 3 + 1) * Dd, nullptr,
        (u16*)(ws + o_kgf), (u16*)(ws + o_vgf), nullptr, 1536, Dd, 1.0f);
    // attention
    attn_local_kernel<<<LOCAL_NB, 256, 0, stream>>>((u16*)(ws + o_qpk), (u16*)(ws + o_kpk), (u16*)(ws + o_vtpk), (u16*)(ws + o_kg), (u16*)(ws + o_vgt), amask, (u16*)(ws + o_ctx));
    attn_globalq_kernel<<<Bb * Hh * NCH, 192, 0, stream>>>((u16*)(ws + o_qg), (u16*)(ws + o_kgf), (u16*)(ws + o_vgf), amask, (float*)(ws + o_part));
    attn_gmerge_kernel<<<Bb * Hh, 256, 0, stream>>>((float*)(ws + o_part), gposp, (u16*)(ws + o_ctx));
    // output projection + LN
    gemm2_kernel<0><<<dim3(6, 64), 256, 0, stream>>>((u16*)(ws + o_ctx), Wb + wb + 6 * DD, bo + (size_t)l * Dd, (float*)(ws + o_acc),
        nullptr, nullptr, nullptr, Dd, Dd, 1.0f);
    add_ln_kernel<<<Bb * Ss, 256, 0, stream>>>((float*)(ws + o_x), (float*)(ws + o_acc), ln1 + (size_t)l * 2 * Dd, (float*)(ws + o_x), xb);
    // FFN
    gemm2_kernel<1><<<dim3(24, 64), 256, 0, stream>>>(xb, Wb + wb + 7 * DD, bff1 + (size_t)l * 4 * Dd, nullptr,
        (u16*)(ws + o_f1b), nullptr, nullptr, 4 * Dd, Dd, 1.0f);
    gemm2_kernel<0><<<dim3(6, 64), 256, 0, stream>>>((u16*)(ws + o_f1b), Wb + wb + 7 * DD + DF, bff2 + (size_t)l * Dd, (float*)(ws + o_acc),
        nullptr, nullptr, nullptr, Dd, 4 * Dd, 1.0f);
    add_ln_kernel<<<Bb * Ss, 256, 0, stream>>>((float*)(ws + o_x), (float*)(ws + o_acc), ln2 + (size_t)l * 2 * Dd, (float*)(ws + o_x), xb);
  }

  cls_kernel<<<Bb * NSEPn, 64, 0, stream>>>((float*)(ws + o_x), clsW, clsb, gposp, out);
}

// Round 5
// 940.185 us; speedup vs baseline: 2.2569x; 1.0738x over previous
//
#include <hip/hip_runtime.h>

// ---------------------------------------------------------------------------
// Longformer (2-layer) forward, MI355X.
// R4: attn_local rebuilt: 64-key steps, ballot masking, padded Plds (stride 72)
//     -> kills 7M LDS bank conflicts + halves per-step softmax overhead.
//     gemm2: double-buffered 2-phase (prefetch next K-tile under MFMA).
// ---------------------------------------------------------------------------

#define Bb 2
#define Ss 4096
#define Dd 768
#define Hh 12
#define Gg 33
#define NSEPn 32
#define Ll 2
#define SPAD 4640   // S + 544 (PADL=256 left, 288 right)
#define PADL 256
#define NCLSn 5
#define NCH 16      // key chunks for global-q attention (256 keys each)
#define PARTF 1056  // floats per (bh,qt,chunk) partial: 16*64 o + 16 m + 16 l
#define PSTR 72     // Plds row stride in u16 (144B: 16B-aligned, bank-spread)

typedef unsigned short u16;
typedef __attribute__((ext_vector_type(8))) short bv8;   // 8 x bf16
typedef __attribute__((ext_vector_type(4))) short sv4;   // 4 x bf16
typedef __attribute__((ext_vector_type(4))) float f32x4;

__device__ __forceinline__ float bf2f(u16 u) {
  unsigned v = ((unsigned)u) << 16;
  return __builtin_bit_cast(float, v);
}
__device__ __forceinline__ u16 f2bf(float f) {
  unsigned u = __builtin_bit_cast(unsigned, f);
  u += 0x7fffu + ((u >> 16) & 1u);
  return (u16)(u >> 16);
}
__device__ __forceinline__ void glds16(const void* g, void* l) {
  __builtin_amdgcn_global_load_lds(
      (const __attribute__((address_space(1))) void*)g,
      (__attribute__((address_space(3))) void*)l, 16, 0, 0);
}

// ---------------- sep finding --------------------------------------------
__global__ void sep_find_kernel(const int* __restrict__ ids, int* __restrict__ cnt,
                                int* __restrict__ list) {
  int i = blockIdx.x * 256 + threadIdx.x;
  if (i >= Bb * Ss) return;
  int b = i >> 12;
  if (ids[i] == 2) {
    int idx = atomicAdd(&cnt[b], 1);
    if (idx < 64) list[b * 64 + idx] = i & (Ss - 1);
  }
}

__global__ void sep_sort_kernel(const int* __restrict__ cnt, const int* __restrict__ list,
                                int* __restrict__ gpos) {
  int b = blockIdx.x;
  int t = threadIdx.x;
  int n = cnt[b]; if (n > 64) n = 64;
  if (t < Gg) gpos[b * Gg + t] = (t == 0) ? 0 : (Ss - 1);
  __syncthreads();
  if (t < n) {
    int v = list[b * 64 + t];
    int rank = 0;
    for (int j = 0; j < n; ++j) rank += (list[b * 64 + j] < v) ? 1 : 0;
    if (rank < NSEPn) gpos[b * Gg + 1 + rank] = v;
  }
}

// ---------------- weight fp32 (K,N) -> bf16 (N,K), batched over z -----------
__global__ __launch_bounds__(256)
void wconv_kernel(const float* __restrict__ src0, u16* __restrict__ dst0,
                  int K, int N, int grp, long unit, long WLs) {
  __shared__ float t[32][33];
  int z = blockIdx.z;
  const float* src = src0 + (size_t)z * K * N;
  u16* dst = dst0 + (size_t)(z / grp) * WLs + (size_t)(z % grp) * unit;
  int n0 = blockIdx.x * 32, k0 = blockIdx.y * 32;
  int tx = threadIdx.x & 31, ty = threadIdx.x >> 5;  // ty 0..7
  #pragma unroll
  for (int i = 0; i < 4; ++i)
    t[ty + i * 8][tx] = src[(size_t)(k0 + ty + i * 8) * N + n0 + tx];
  __syncthreads();
  #pragma unroll
  for (int i = 0; i < 4; ++i)
    dst[(size_t)(n0 + ty + i * 8) * K + k0 + tx] = f2bf(t[tx][ty + i * 8]);
}

// ---------------- embedding + LN -------------------------------------------
__global__ __launch_bounds__(256)
void embed_ln_kernel(const int* __restrict__ ids, const float* __restrict__ we,
                     const float* __restrict__ pe, const float* __restrict__ te,
                     const float* __restrict__ lnp, float* __restrict__ x,
                     u16* __restrict__ xb) {
  int row = blockIdx.x;
  int s = row & (Ss - 1);
  int id = ids[row];
  int tid = threadIdx.x;
  float v[3]; float sm = 0.f, s2 = 0.f;
  #pragma unroll
  for (int i = 0; i < 3; ++i) {
    int c = tid + i * 256;
    float t = we[(size_t)id * Dd + c] + pe[(size_t)(s + 2) * Dd + c] + te[c];
    v[i] = t; sm += t; s2 += t * t;
  }
  __shared__ float r1[256], r2[256];
  r1[tid] = sm; r2[tid] = s2; __syncthreads();
  for (int o = 128; o; o >>= 1) {
    if (tid < o) { r1[tid] += r1[tid + o]; r2[tid] += r2[tid + o]; }
    __syncthreads();
  }
  float mean = r1[0] * (1.f / 768.f);
  float var  = r2[0] * (1.f / 768.f) - mean * mean;
  float rs = rsqrtf(var + 1e-5f);
  #pragma unroll
  for (int i = 0; i < 3; ++i) {
    int c = tid + i * 256;
    float o = (v[i] - mean) * rs * lnp[c] + lnp[Dd + c];
    x[(size_t)row * Dd + c] = o;
    xb[(size_t)row * Dd + c] = f2bf(o);
  }
}

// ---------------- residual + LN --------------------------------------------
__global__ __launch_bounds__(256)
void add_ln_kernel(const float* __restrict__ xin, const float* __restrict__ y,
                   const float* __restrict__ lnp, float* __restrict__ xout,
                   u16* __restrict__ xbout) {
  int row = blockIdx.x;
  int tid = threadIdx.x;
  float v[3]; float sm = 0.f, s2 = 0.f;
  #pragma unroll
  for (int i = 0; i < 3; ++i) {
    int c = tid + i * 256;
    float t = xin[(size_t)row * Dd + c] + y[(size_t)row * Dd + c];
    v[i] = t; sm += t; s2 += t * t;
  }
  __shared__ float r1[256], r2[256];
  r1[tid] = sm; r2[tid] = s2; __syncthreads();
  for (int o = 128; o; o >>= 1) {
    if (tid < o) { r1[tid] += r1[tid + o]; r2[tid] += r2[tid + o]; }
    __syncthreads();
  }
  float mean = r1[0] * (1.f / 768.f);
  float var  = r2[0] * (1.f / 768.f) - mean * mean;
  float rs = rsqrtf(var + 1e-5f);
  #pragma unroll
  for (int i = 0; i < 3; ++i) {
    int c = tid + i * 256;
    float o = (v[i] - mean) * rs * lnp[c] + lnp[Dd + c];
    xout[(size_t)row * Dd + c] = o;
    xbout[(size_t)row * Dd + c] = f2bf(o);
  }
}

// ---------------- GEMM2: glds-staged dbuf 128x128xK, M % 128 == 0 ----------
// MODE 0: fp32 [M][N] (+bias)
// MODE 1: bf16 [M][N], exact gelu
// MODE 2: fused QKV: N=2304; sec0->q packed (scale), sec1->k padded, sec2->v^T padded
// MODE 3: fused gKV:  N=1536; sec0->k packed, sec1->v^T [bh][64][Ss]
// MODE 4: bf16 [M][N] * scale
template <int MODE>
__global__ __launch_bounds__(256)
void gemm2_kernel(const u16* __restrict__ A, const u16* __restrict__ Bt,
                  const float* __restrict__ bias, float* __restrict__ outf,
                  u16* __restrict__ o0, u16* __restrict__ o1, u16* __restrict__ o2,
                  int N, int K, float scale) {
  __shared__ u16 la[2][128 * 32], lb[2][128 * 32];
  int tid = threadIdx.x;
  int wave = tid >> 6, lane = tid & 63;
  int wr = wave >> 1, wc = wave & 1;
  int lg = lane >> 4, lc = lane & 15;
  int row0 = blockIdx.y * 128, col0 = blockIdx.x * 128;

  const u16* Ag = A + (size_t)(row0 + wave * 32 + (lane >> 2)) * K + (lane & 3) * 8;
  const u16* Bg = Bt + (size_t)(col0 + wave * 32 + (lane >> 2)) * K + (lane & 3) * 8;
  int wofs = wave * 1024;

  f32x4 acc[4][4];
  #pragma unroll
  for (int m = 0; m < 4; ++m)
    #pragma unroll
    for (int n = 0; n < 4; ++n) acc[m][n] = (f32x4){0.f, 0.f, 0.f, 0.f};

  // prologue: stage K-tile 0 into buf 0
  glds16(Ag, la[0] + wofs);
  glds16(Ag + (size_t)16 * K, la[0] + wofs + 512);
  glds16(Bg, lb[0] + wofs);
  glds16(Bg + (size_t)16 * K, lb[0] + wofs + 512);
  __syncthreads();

  int nk = K >> 5;
  for (int t = 0; t < nk; ++t) {
    int cur = t & 1;
    if (t + 1 < nk) {  // prefetch next tile into other buffer (flies under MFMA)
      int k1 = (t + 1) << 5;
      glds16(Ag + k1, la[cur ^ 1] + wofs);
      glds16(Ag + (size_t)16 * K + k1, la[cur ^ 1] + wofs + 512);
      glds16(Bg + k1, lb[cur ^ 1] + wofs);
      glds16(Bg + (size_t)16 * K + k1, lb[cur ^ 1] + wofs + 512);
    }
    bv8 af[4], bf_[4];
    #pragma unroll
    for (int m = 0; m < 4; ++m)
      af[m] = *reinterpret_cast<const bv8*>(la[cur] + (wr * 64 + m * 16 + lc) * 32 + lg * 8);
    #pragma unroll
    for (int n = 0; n < 4; ++n)
      bf_[n] = *reinterpret_cast<const bv8*>(lb[cur] + (wc * 64 + n * 16 + lc) * 32 + lg * 8);
    #pragma unroll
    for (int m = 0; m < 4; ++m)
      #pragma unroll
      for (int n = 0; n < 4; ++n)
        acc[m][n] = __builtin_amdgcn_mfma_f32_16x16x32_bf16(af[m], bf_[n], acc[m][n], 0, 0, 0);
    __syncthreads();  // drains prefetch (vmcnt0) + joins waves
  }

  #pragma unroll
  for (int m = 0; m < 4; ++m) {
    int grow0 = row0 + wr * 64 + m * 16 + lg * 4;
    #pragma unroll
    for (int n = 0; n < 4; ++n) {
      int gcol = col0 + wc * 64 + n * 16 + lc;
      float bvl = bias[gcol];
      if (MODE == 0) {
        #pragma unroll
        for (int r = 0; r < 4; ++r)
          outf[(size_t)(grow0 + r) * N + gcol] = acc[m][n][r] + bvl;
      } else if (MODE == 1) {
        #pragma unroll
        for (int r = 0; r < 4; ++r) {
          float v = acc[m][n][r] + bvl;
          v = 0.5f * v * (1.0f + erff(v * 0.70710678118654752f));
          o0[(size_t)(grow0 + r) * N + gcol] = f2bf(v);
        }
      } else if (MODE == 4) {
        #pragma unroll
        for (int r = 0; r < 4; ++r)
          o0[(size_t)(grow0 + r) * N + gcol] = f2bf((acc[m][n][r] + bvl) * scale);
      } else if (MODE == 2) {
        int sec = col0 >= 1536 ? 2 : (col0 >= 768 ? 1 : 0);
        int colr = gcol - sec * 768;
        int hh = colr >> 6, d = colr & 63;
        int bb = grow0 >> 12, s = grow0 & (Ss - 1);
        size_t bhh = (size_t)(bb * Hh + hh);
        if (sec == 0) {
          #pragma unroll
          for (int r = 0; r < 4; ++r)
            o0[(bhh * Ss + s + r) * 64 + d] = f2bf((acc[m][n][r] + bvl) * scale);
        } else if (sec == 1) {
          #pragma unroll
          for (int r = 0; r < 4; ++r)
            o1[(bhh * SPAD + PADL + s + r) * 64 + d] = f2bf(acc[m][n][r] + bvl);
        } else {
          sv4 pk;
          #pragma unroll
          for (int r = 0; r < 4; ++r) pk[r] = (short)f2bf(acc[m][n][r] + bvl);
          *reinterpret_cast<sv4*>(o2 + (bhh * 64 + d) * SPAD + PADL + s) = pk;
        }
      } else if (MODE == 3) {
        int sec = col0 >= 768 ? 1 : 0;
        int colr = gcol - sec * 768;
        int hh = colr >> 6, d = colr & 63;
        int bb = grow0 >> 12, s = grow0 & (Ss - 1);
        size_t bhh = (size_t)(bb * Hh + hh);
        if (sec == 0) {
          #pragma unroll
          for (int r = 0; r < 4; ++r)
            o0[(bhh * Ss + s + r) * 64 + d] = f2bf(acc[m][n][r] + bvl);
        } else {
          sv4 pk;
          #pragma unroll
          for (int r = 0; r < 4; ++r) pk[r] = (short)f2bf(acc[m][n][r] + bvl);
          *reinterpret_cast<sv4*>(o1 + (bhh * 64 + d) * Ss + s) = pk;
        }
      }
    }
  }
}

// ---------------- gathers ---------------------------------------------------
__global__ __launch_bounds__(256)
void gather_glob_kernel(const u16* __restrict__ kpk, const u16* __restrict__ vtpk,
                        const int* __restrict__ gpos, u16* __restrict__ kg,
                        u16* __restrict__ vgt) {
  int bh = blockIdx.x;
  int b = bh / Hh;
  int tid = threadIdx.x;
  for (int idx = tid; idx < 64 * 64; idx += 256) {
    int g = idx >> 6, d = idx & 63;
    u16 kv = 0, vv = 0;
    if (g < Gg) {
      int p = gpos[b * Gg + g];
      kv = kpk[((size_t)bh * SPAD + PADL + p) * 64 + d];
      vv = vtpk[((size_t)bh * 64 + d) * SPAD + PADL + p];
    }
    kg[(size_t)bh * 4096 + idx] = kv;
    vgt[((size_t)bh * 64 + d) * 64 + g] = vv;
  }
}

__global__ __launch_bounds__(256)
void gather_xg_kernel(const u16* __restrict__ xb, const int* __restrict__ gpos,
                      u16* __restrict__ xg) {
  int rg = blockIdx.x;  // b*G+g
  int b = rg / Gg;
  int p = gpos[rg];
  int tid = threadIdx.x;
  for (int c = tid; c < Dd; c += 256)
    xg[(size_t)rg * Dd + c] = xb[((size_t)b * Ss + p) * Dd + c];
}

// ---------------- local (sliding window + global-key) attention -------------
// 4 waves/block, 64 queries/block; XCD swizzle. 64-key steps: step 0 = global
// keys (33 valid), steps 1..9 = local window q0-256..q0+320. Swapped QK^T:
// lane owns query lc; masking via one ballot per step; Plds stride 72.
#define LOCAL_NB (Bb * Hh * (Ss / 64))   // 1536 blocks, %8 == 0
__global__ __launch_bounds__(256)
void attn_local_kernel(const u16* __restrict__ qpk, const u16* __restrict__ kpk,
                       const u16* __restrict__ vtpk, const u16* __restrict__ kg,
                       const u16* __restrict__ vgt, const int* __restrict__ amask,
                       u16* __restrict__ ctx) {
  __shared__ u16 Plds[4][16 * PSTR];
  int bid = blockIdx.x;
  int swz = (bid & 7) * (LOCAL_NB / 8) + (bid >> 3);
  int qb = swz & 63;
  int bh = swz >> 6;
  int b = bh / Hh;
  int h = bh - b * Hh;
  int wv = threadIdx.x >> 6;
  int q0 = qb * 64 + wv * 16;
  int lane = threadIdx.x & 63;
  int lg = lane >> 4, lc = lane & 15;
  int lg4 = lg * 4;
  int q = q0 + lc;   // query owned by this lane for softmax state

  const u16* qbase = qpk + (((size_t)bh) * Ss + q0) * 64;
  bv8 aq0 = *reinterpret_cast<const bv8*>(qbase + (size_t)lc * 64 + lg * 8);
  bv8 aq1 = *reinterpret_cast<const bv8*>(qbase + (size_t)lc * 64 + 32 + lg * 8);

  f32x4 o[4];
  #pragma unroll
  for (int i = 0; i < 4; ++i) o[i] = (f32x4){0.f, 0.f, 0.f, 0.f};
  float mrun = -1e30f, lrun = 0.f;

  const u16* kgb = kg + ((size_t)bh) * 64 * 64;
  const u16* vgb = vgt + ((size_t)bh) * 64 * 64;
  const u16* kb = kpk + ((size_t)bh) * SPAD * 64;
  const u16* vb = vtpk + ((size_t)bh) * 64 * SPAD;
  const int* amb = amask + b * Ss;
  u16* P = &Plds[wv][0];

  for (int step = 0; step < 10; ++step) {
    bool isg = (step == 0);
    int ks = isg ? 0 : (q0 - 256 + (step - 1) * 64);
    // 64-bit key-validity mask (bounds & amask; global: g < Gg)
    unsigned long long kmask;
    if (isg) {
      kmask = (1ull << Gg) - 1;
    } else {
      int kidx = ks + lane;
      int kcl = min(max(kidx, 0), Ss - 1);
      bool kok = (kidx >= 0) & (kidx < Ss) & (amb[kcl] > 0);
      kmask = __ballot(kok);
    }
    // QK^T (swapped): sc[j] = scores for keys ks+j*16+lg4..+3, query lc
    f32x4 sc[4];
    #pragma unroll
    for (int j = 0; j < 4; ++j) {
      const u16* kr = isg ? (kgb + (size_t)(j * 16 + lc) * 64)
                          : (kb + (size_t)(PADL + ks + j * 16 + lc) * 64);
      bv8 k0f = *reinterpret_cast<const bv8*>(kr + lg * 8);
      bv8 k1f = *reinterpret_cast<const bv8*>(kr + 32 + lg * 8);
      f32x4 z = (f32x4){0.f, 0.f, 0.f, 0.f};
      sc[j] = __builtin_amdgcn_mfma_f32_16x16x32_bf16(k0f, aq0, z, 0, 0, 0);
      sc[j] = __builtin_amdgcn_mfma_f32_16x16x32_bf16(k1f, aq1, sc[j], 0, 0, 0);
    }
    // masking: steps 2..8 with full kmask are band-safe for all 16 queries
    float mloc = -1e30f;
    bool fast = (!isg) && (step >= 2) && (step <= 8) && (kmask == ~0ull);
    if (fast) {
      #pragma unroll
      for (int j = 0; j < 4; ++j)
        #pragma unroll
        for (int r = 0; r < 4; ++r) mloc = fmaxf(mloc, sc[j][r]);
    } else {
      #pragma unroll
      for (int j = 0; j < 4; ++j)
        #pragma unroll
        for (int r = 0; r < 4; ++r) {
          int kk = ks + j * 16 + lg4 + r;
          bool ok = (kmask >> (j * 16 + lg4 + r)) & 1;
          if (!isg) ok = ok && ((unsigned)(kk - q + 256) <= 512u);
          sc[j][r] = ok ? sc[j][r] : -1e9f;
          mloc = fmaxf(mloc, sc[j][r]);
        }
    }
    mloc = fmaxf(mloc, __shfl_xor(mloc, 16));
    mloc = fmaxf(mloc, __shfl_xor(mloc, 32));
    if (__any(mloc > mrun)) {
      float nm = fmaxf(mrun, mloc);
      float scal = __expf(mrun - nm);
      mrun = nm;
      lrun *= scal;
      #pragma unroll
      for (int r = 0; r < 4; ++r) {
        float sr = __shfl(scal, lg4 + r);  // scal of query lg4+r (lane<16 owner)
        #pragma unroll
        for (int nt = 0; nt < 4; ++nt) o[nt][r] *= sr;
      }
    }
    float psum = 0.f;
    #pragma unroll
    for (int j = 0; j < 4; ++j) {
      sv4 pk;
      #pragma unroll
      for (int r = 0; r < 4; ++r) {
        float p = __expf(sc[j][r] - mrun);
        psum += p;
        pk[r] = (short)f2bf(p);
      }
      *reinterpret_cast<sv4*>(P + lc * PSTR + j * 16 + lg4) = pk;
    }
    psum += __shfl_xor(psum, 16);
    psum += __shfl_xor(psum, 32);
    lrun += psum;
    // PV: o[nt] += P[:, j2*32..] @ V^T rows (d = nt*16+lc)
    #pragma unroll
    for (int j2 = 0; j2 < 2; ++j2) {
      bv8 ap = *reinterpret_cast<const bv8*>(P + lc * PSTR + j2 * 32 + lg * 8);
      #pragma unroll
      for (int nt = 0; nt < 4; ++nt) {
        const u16* vr = isg ? (vgb + (size_t)(nt * 16 + lc) * 64 + j2 * 32)
                            : (vb + (size_t)(nt * 16 + lc) * SPAD + PADL + ks + j2 * 32);
        bv8 bvv = *reinterpret_cast<const bv8*>(vr + lg * 8);
        o[nt] = __builtin_amdgcn_mfma_f32_16x16x32_bf16(ap, bvv, o[nt], 0, 0, 0);
      }
    }
  }
  float inv = 1.0f / lrun;
  #pragma unroll
  for (int r = 0; r < 4; ++r) {
    float invr = __shfl(inv, lg4 + r);
    size_t rowoff = ((size_t)b * Ss + q0 + lg4 + r) * Dd + h * 64;
    #pragma unroll
    for (int nt = 0; nt < 4; ++nt)
      ctx[rowoff + nt * 16 + lc] = f2bf(o[nt][r] * invr);
  }
}

// ---------------- global-query attention: chunked flash MFMA ----------------
__global__ __launch_bounds__(192)
void attn_globalq_kernel(const u16* __restrict__ qgb, const u16* __restrict__ kgf,
                         const u16* __restrict__ vgt, const int* __restrict__ amask,
                         float* __restrict__ part) {
  __shared__ u16 Plds[3][16 * 32];
  int blk = blockIdx.x;
  int ch = blk & (NCH - 1);
  int bh = blk / NCH;
  int b = bh / Hh, h = bh - b * Hh;
  int wv = threadIdx.x >> 6;  // q-tile 0..2
  int lane = threadIdx.x & 63;
  int lg = lane >> 4, lc = lane & 15;

  int qrow = wv * 16 + lc;
  bv8 aq0 = (bv8)0, aq1 = (bv8)0;
  if (qrow < Gg) {
    const u16* qr = qgb + (size_t)(b * Gg + qrow) * Dd + h * 64;
    aq0 = *reinterpret_cast<const bv8*>(qr + lg * 8);
    aq1 = *reinterpret_cast<const bv8*>(qr + 32 + lg * 8);
  }

  f32x4 o[4];
  float mrun[4], lrun[4];
  #pragma unroll
  for (int i = 0; i < 4; ++i) { o[i] = (f32x4){0.f,0.f,0.f,0.f}; mrun[i] = -1e30f; lrun[i] = 0.f; }

  const u16* kb = kgf + ((size_t)bh) * Ss * 64;
  const u16* vb = vgt + ((size_t)bh) * 64 * Ss;
  const int* amb = amask + b * Ss;
  int ks0 = ch * (Ss / NCH);

  for (int st = 0; st < (Ss / NCH) / 32; ++st) {
    int ks = ks0 + st * 32;
    f32x4 sc0, sc1;
    {
      const u16* kr0 = kb + (size_t)(ks + lc) * 64;
      const u16* kr1 = kr0 + 16 * 64;
      bv8 b00 = *reinterpret_cast<const bv8*>(kr0 + lg * 8);
      bv8 b01 = *reinterpret_cast<const bv8*>(kr0 + 32 + lg * 8);
      bv8 b10 = *reinterpret_cast<const bv8*>(kr1 + lg * 8);
      bv8 b11 = *reinterpret_cast<const bv8*>(kr1 + 32 + lg * 8);
      f32x4 z = (f32x4){0.f,0.f,0.f,0.f};
      sc0 = __builtin_amdgcn_mfma_f32_16x16x32_bf16(aq0, b00, z, 0, 0, 0);
      sc0 = __builtin_amdgcn_mfma_f32_16x16x32_bf16(aq1, b01, sc0, 0, 0, 0);
      sc1 = __builtin_amdgcn_mfma_f32_16x16x32_bf16(aq0, b10, z, 0, 0, 0);
      sc1 = __builtin_amdgcn_mfma_f32_16x16x32_bf16(aq1, b11, sc1, 0, 0, 0);
    }
    bool v0 = amb[ks + lc] > 0;
    bool v1 = amb[ks + 16 + lc] > 0;
    #pragma unroll
    for (int r = 0; r < 4; ++r) {
      float s0 = v0 ? sc0[r] : -1e9f;
      float s1 = v1 ? sc1[r] : -1e9f;
      float rm = fmaxf(s0, s1);
      #pragma unroll
      for (int off = 1; off < 16; off <<= 1) rm = fmaxf(rm, __shfl_xor(rm, off));
      float nm = fmaxf(mrun[r], rm);
      float scal = __expf(mrun[r] - nm);
      float p0 = __expf(s0 - nm);
      float p1 = __expf(s1 - nm);
      float ps = p0 + p1;
      #pragma unroll
      for (int off = 1; off < 16; off <<= 1) ps += __shfl_xor(ps, off);
      lrun[r] = lrun[r] * scal + ps;
      mrun[r] = nm;
      #pragma unroll
      for (int nt = 0; nt < 4; ++nt) o[nt][r] *= scal;
      int prow = lg * 4 + r;
      Plds[wv][prow * 32 + lc] = f2bf(p0);
      Plds[wv][prow * 32 + 16 + lc] = f2bf(p1);
    }
    bv8 ap = *reinterpret_cast<const bv8*>(&Plds[wv][lc * 32 + lg * 8]);
    #pragma unroll
    for (int nt = 0; nt < 4; ++nt) {
      const u16* vr = vb + (size_t)(nt * 16 + lc) * Ss + ks;
      bv8 bvv = *reinterpret_cast<const bv8*>(vr + lg * 8);
      o[nt] = __builtin_amdgcn_mfma_f32_16x16x32_bf16(ap, bvv, o[nt], 0, 0, 0);
    }
  }

  float* pb = part + ((size_t)(bh * 3 + wv) * NCH + ch) * PARTF;
  #pragma unroll
  for (int r = 0; r < 4; ++r) {
    int row = lg * 4 + r;
    #pragma unroll
    for (int nt = 0; nt < 4; ++nt)
      pb[row * 64 + nt * 16 + lc] = o[nt][r];
    if (lc == 0) {
      pb[1024 + row] = mrun[r];
      pb[1040 + row] = lrun[r];
    }
  }
}

// merge NCH chunk-partials and scatter into ctx rows at gpos
__global__ __launch_bounds__(256)
void attn_gmerge_kernel(const float* __restrict__ part, const int* __restrict__ gpos,
                        u16* __restrict__ ctx) {
  __shared__ float wgt[Gg][NCH];
  __shared__ float sinvl[Gg];
  int bh = blockIdx.x;
  int b = bh / Hh, h = bh - b * Hh;
  int tid = threadIdx.x;
  if (tid < Gg) {
    int qt = tid >> 4, rr = tid & 15;
    const float* pb = part + ((size_t)(bh * 3 + qt) * NCH) * PARTF;
    float mx = -1e30f;
    for (int c = 0; c < NCH; ++c) mx = fmaxf(mx, pb[c * PARTF + 1024 + rr]);
    float l = 0.f;
    for (int c = 0; c < NCH; ++c) {
      float w = __expf(pb[c * PARTF + 1024 + rr] - mx);
      wgt[tid][c] = w;
      l += w * pb[c * PARTF + 1040 + rr];
    }
    sinvl[tid] = 1.0f / l;
  }
  __syncthreads();
  for (int e = tid; e < Gg * 64; e += 256) {
    int row = e >> 6, d = e & 63;
    int qt = row >> 4, rr = row & 15;
    const float* pb = part + ((size_t)(bh * 3 + qt) * NCH) * PARTF + rr * 64 + d;
    float acc = 0.f;
    #pragma unroll
    for (int c = 0; c < NCH; ++c) acc += wgt[row][c] * pb[c * PARTF];
    int pos = gpos[b * Gg + row];
    ctx[((size_t)b * Ss + pos) * Dd + h * 64 + d] = f2bf(acc * sinvl[row]);
  }
}

// ---------------- classifier ------------------------------------------------
__global__ __launch_bounds__(64)
void cls_kernel(const float* __restrict__ x, const float* __restrict__ W,
                const float* __restrict__ bias, const int* __restrict__ gpos,
                float* __restrict__ out) {
  int r = blockIdx.x;  // b*32 + i
  int b = r >> 5, i = r & 31;
  int pos = gpos[b * Gg + 1 + i];
  int lane = threadIdx.x;
  const float* xr = x + ((size_t)b * Ss + pos) * Dd;
  float acc[NCLSn] = {0.f, 0.f, 0.f, 0.f, 0.f};
  for (int k = lane; k < Dd; k += 64) {
    float xv = xr[k];
    #pragma unroll
    for (int c = 0; c < NCLSn; ++c) acc[c] += xv * W[c * Dd + k];
  }
  #pragma unroll
  for (int c = 0; c < NCLSn; ++c) {
    #pragma unroll
    for (int off = 1; off < 64; off <<= 1) acc[c] += __shfl_xor(acc[c], off);
  }
  if (lane == 0) {
    #pragma unroll
    for (int c = 0; c < NCLSn; ++c) out[r * NCLSn + c] = acc[c] + bias[c];
  }
}

// ---------------------------------------------------------------------------
extern "C" void kernel_launch(void* const* d_in, const int* in_sizes, int n_in,
                              void* d_out, int out_size, void* d_ws, size_t ws_size,
                              hipStream_t stream) {
  const int* ids     = (const int*)d_in[0];
  const int* amask   = (const int*)d_in[1];
  const float* we    = (const float*)d_in[2];
  const float* pe    = (const float*)d_in[3];
  const float* te    = (const float*)d_in[4];
  const float* embln = (const float*)d_in[5];
  const float* Wqkv  = (const float*)d_in[6];
  const float* bqkv  = (const float*)d_in[7];
  const float* Wqkvg = (const float*)d_in[8];
  const float* bqkvg = (const float*)d_in[9];
  const float* Wo    = (const float*)d_in[10];
  const float* bo    = (const float*)d_in[11];
  const float* ln1   = (const float*)d_in[12];
  const float* Wff1  = (const float*)d_in[13];
  const float* bff1  = (const float*)d_in[14];
  const float* Wff2  = (const float*)d_in[15];
  const float* bff2  = (const float*)d_in[16];
  const float* ln2   = (const float*)d_in[17];
  const float* clsW  = (const float*)d_in[18];
  const float* clsb  = (const float*)d_in[19];
  float* out = (float*)d_out;

  char* ws = (char*)d_ws;
  size_t off = 0;
  auto alloc = [&](size_t bytes) { size_t o = off; off += (bytes + 255) & ~(size_t)255; return o; };

  const size_t DD = (size_t)Dd * Dd;        // 589824
  const size_t DF = (size_t)Dd * 4 * Dd;    // 2359296
  const size_t WL = 7 * DD + 2 * DF;        // elems per layer

  size_t o_cnt  = alloc(Bb * 4);
  size_t o_list = alloc(Bb * 64 * 4);
  size_t o_gpos = alloc(Bb * Gg * 4);
  size_t o_w    = alloc(WL * Ll * 2);
  size_t o_x    = alloc((size_t)Bb * Ss * Dd * 4);
  size_t o_xb   = alloc((size_t)Bb * Ss * Dd * 2);
  size_t o_qpk  = alloc((size_t)Bb * Hh * Ss * 64 * 2);
  size_t o_kpk  = alloc((size_t)Bb * Hh * SPAD * 64 * 2);
  size_t o_vtpk = alloc((size_t)Bb * Hh * 64 * SPAD * 2);
  size_t o_kg   = alloc((size_t)Bb * Hh * 64 * 64 * 2);
  size_t o_vgt  = alloc((size_t)Bb * Hh * 64 * 64 * 2);
  size_t o_xg   = alloc((size_t)128 * Dd * 2);
  size_t o_qg   = alloc((size_t)128 * Dd * 2);
  size_t o_kgf  = alloc((size_t)Bb * Hh * Ss * 64 * 2);
  size_t o_vgf  = alloc((size_t)Bb * Hh * Ss * 64 * 2);
  size_t o_part = alloc((size_t)Bb * Hh * 3 * NCH * PARTF * 4);
  size_t o_f1b  = o_qpk;  // FFN hidden aliases the (dead-by-then) attention buffers
  {
    size_t f1b_bytes = (size_t)Bb * Ss * 4 * Dd * 2;
    if (off - o_qpk < f1b_bytes) off = o_qpk + ((f1b_bytes + 255) & ~(size_t)255);
  }
  size_t o_ctx = alloc((size_t)Bb * Ss * Dd * 2);
  size_t o_acc = alloc((size_t)Bb * Ss * Dd * 4);
  if (ws_size < off) return;  // workspace too small -> fail visibly

  u16* Wb = (u16*)(ws + o_w);
  int* gposp = (int*)(ws + o_gpos);

  (void)hipMemsetAsync(ws + o_cnt, 0, Bb * 4, stream);
  // zero padded K / V^T so first-call pads are finite (later calls: finite stale bf16)
  (void)hipMemsetAsync(ws + o_kpk, 0, (size_t)Bb * Hh * SPAD * 64 * 2, stream);
  (void)hipMemsetAsync(ws + o_vtpk, 0, (size_t)Bb * Hh * 64 * SPAD * 2, stream);
  (void)hipMemsetAsync(ws + o_xg, 0, (size_t)128 * Dd * 2, stream);

  sep_find_kernel<<<(Bb * Ss + 255) / 256, 256, 0, stream>>>(ids, (int*)(ws + o_cnt), (int*)(ws + o_list));
  sep_sort_kernel<<<Bb, 64, 0, stream>>>((int*)(ws + o_cnt), (int*)(ws + o_list), gposp);

  // weight conversions (batched over z)
  wconv_kernel<<<dim3(24, 24, 6), 256, 0, stream>>>(Wqkv,  Wb,          Dd, Dd, 3, (long)DD, (long)WL);
  wconv_kernel<<<dim3(24, 24, 6), 256, 0, stream>>>(Wqkvg, Wb + 3 * DD, Dd, Dd, 3, (long)DD, (long)WL);
  wconv_kernel<<<dim3(24, 24, 2), 256, 0, stream>>>(Wo,    Wb + 6 * DD, Dd, Dd, 1, 0L, (long)WL);
  wconv_kernel<<<dim3(96, 24, 2), 256, 0, stream>>>(Wff1,  Wb + 7 * DD, Dd, 4 * Dd, 1, 0L, (long)WL);
  wconv_kernel<<<dim3(24, 96, 2), 256, 0, stream>>>(Wff2,  Wb + 7 * DD + DF, 4 * Dd, Dd, 1, 0L, (long)WL);

  embed_ln_kernel<<<Bb * Ss, 256, 0, stream>>>(ids, we, pe, te, embln, (float*)(ws + o_x), (u16*)(ws + o_xb));

  for (int l = 0; l < Ll; ++l) {
    size_t wb = (size_t)l * WL;
    u16* xb = (u16*)(ws + o_xb);
    // fused QKV projection (N=2304)
    gemm2_kernel<2><<<dim3(18, 64), 256, 0, stream>>>(xb, Wb + wb, bqkv + (size_t)l * 3 * Dd, nullptr,
        (u16*)(ws + o_qpk), (u16*)(ws + o_kpk), (u16*)(ws + o_vtpk), 2304, Dd, 0.125f);
    gather_glob_kernel<<<Bb * Hh, 256, 0, stream>>>((u16*)(ws + o_kpk), (u16*)(ws + o_vtpk), gposp, (u16*)(ws + o_kg), (u16*)(ws + o_vgt));
    gather_xg_kernel<<<Bb * Gg, 256, 0, stream>>>(xb, gposp, (u16*)(ws + o_xg));
    // global q projection (M=128 padded rows)
    gemm2_kernel<4><<<dim3(6, 1), 256, 0, stream>>>((u16*)(ws + o_xg), Wb + wb + 3 * DD, bqkvg + (size_t)l * 3 * Dd, nullptr,
        (u16*)(ws + o_qg), nullptr, nullptr, Dd, Dd, 0.125f);
    // fused global K/V (N=1536)
    gemm2_kernel<3><<<dim3(12, 64), 256, 0, stream>>>(xb, Wb + wb + 4 * DD, bqkvg + (size_t)(l * 3 + 1) * Dd, nullptr,
        (u16*)(ws + o_kgf), (u16*)(ws + o_vgf), nullptr, 1536, Dd, 1.0f);
    // attention
    attn_local_kernel<<<LOCAL_NB, 256, 0, stream>>>((u16*)(ws + o_qpk), (u16*)(ws + o_kpk), (u16*)(ws + o_vtpk), (u16*)(ws + o_kg), (u16*)(ws + o_vgt), amask, (u16*)(ws + o_ctx));
    attn_globalq_kernel<<<Bb * Hh * NCH, 192, 0, stream>>>((u16*)(ws + o_qg), (u16*)(ws + o_kgf), (u16*)(ws + o_vgf), amask, (float*)(ws + o_part));
    attn_gmerge_kernel<<<Bb * Hh, 256, 0, stream>>>((float*)(ws + o_part), gposp, (u16*)(ws + o_ctx));
    // output projection + LN
    gemm2_kernel<0><<<dim3(6, 64), 256, 0, stream>>>((u16*)(ws + o_ctx), Wb + wb + 6 * DD, bo + (size_t)l * Dd, (float*)(ws + o_acc),
        nullptr, nullptr, nullptr, Dd, Dd, 1.0f);
    add_ln_kernel<<<Bb * Ss, 256, 0, stream>>>((float*)(ws + o_x), (float*)(ws + o_acc), ln1 + (size_t)l * 2 * Dd, (float*)(ws + o_x), xb);
    // FFN
    gemm2_kernel<1><<<dim3(24, 64), 256, 0, stream>>>(xb, Wb + wb + 7 * DD, bff1 + (size_t)l * 4 * Dd, nullptr,
        (u16*)(ws + o_f1b), nullptr, nullptr, 4 * Dd, Dd, 1.0f);
    gemm2_kernel<0><<<dim3(6, 64), 256, 0, stream>>>((u16*)(ws + o_f1b), Wb + wb + 7 * DD + DF, bff2 + (size_t)l * Dd, (float*)(ws + o_acc),
        nullptr, nullptr, nullptr, Dd, 4 * Dd, 1.0f);
    add_ln_kernel<<<Bb * Ss, 256, 0, stream>>>((float*)(ws + o_x), (float*)(ws + o_acc), ln2 + (size_t)l * 2 * Dd, (float*)(ws + o_x), xb);
  }

  cls_kernel<<<Bb * NSEPn, 64, 0, stream>>>((float*)(ws + o_x), clsW, clsb, gposp, out);
}

// Round 6
// 889.077 us; speedup vs baseline: 2.3867x; 1.0575x over previous
//
#include <hip/hip_runtime.h>

// ---------------------------------------------------------------------------
// Longformer (2-layer) forward, MI355X.
// R5: (a) attn_local software-pipelined: K-frags prefetched one step ahead,
//         V issued at step top, setprio around MFMA clusters.
//     (b) split-K x2 for Wo/FF2 GEMMs (384->768 blocks, kills CU tail);
//         3-input add_ln; accB reuses dead kgf/vgf region.
// ---------------------------------------------------------------------------

#define Bb 2
#define Ss 4096
#define Dd 768
#define Hh 12
#define Gg 33
#define NSEPn 32
#define Ll 2
#define SPAD 4640   // S + 544 (PADL=256 left, 288 right)
#define PADL 256
#define NCLSn 5
#define NCH 16      // key chunks for global-q attention (256 keys each)
#define PARTF 1056  // floats per (bh,qt,chunk) partial: 16*64 o + 16 m + 16 l
#define PSTR 72     // Plds row stride in u16 (144B: 16B-aligned, bank-spread)

typedef unsigned short u16;
typedef __attribute__((ext_vector_type(8))) short bv8;   // 8 x bf16
typedef __attribute__((ext_vector_type(4))) short sv4;   // 4 x bf16
typedef __attribute__((ext_vector_type(4))) float f32x4;

__device__ __forceinline__ float bf2f(u16 u) {
  unsigned v = ((unsigned)u) << 16;
  return __builtin_bit_cast(float, v);
}
__device__ __forceinline__ u16 f2bf(float f) {
  unsigned u = __builtin_bit_cast(unsigned, f);
  u += 0x7fffu + ((u >> 16) & 1u);
  return (u16)(u >> 16);
}
__device__ __forceinline__ void glds16(const void* g, void* l) {
  __builtin_amdgcn_global_load_lds(
      (const __attribute__((address_space(1))) void*)g,
      (__attribute__((address_space(3))) void*)l, 16, 0, 0);
}

// ---------------- sep finding --------------------------------------------
__global__ void sep_find_kernel(const int* __restrict__ ids, int* __restrict__ cnt,
                                int* __restrict__ list) {
  int i = blockIdx.x * 256 + threadIdx.x;
  if (i >= Bb * Ss) return;
  int b = i >> 12;
  if (ids[i] == 2) {
    int idx = atomicAdd(&cnt[b], 1);
    if (idx < 64) list[b * 64 + idx] = i & (Ss - 1);
  }
}

__global__ void sep_sort_kernel(const int* __restrict__ cnt, const int* __restrict__ list,
                                int* __restrict__ gpos) {
  int b = blockIdx.x;
  int t = threadIdx.x;
  int n = cnt[b]; if (n > 64) n = 64;
  if (t < Gg) gpos[b * Gg + t] = (t == 0) ? 0 : (Ss - 1);
  __syncthreads();
  if (t < n) {
    int v = list[b * 64 + t];
    int rank = 0;
    for (int j = 0; j < n; ++j) rank += (list[b * 64 + j] < v) ? 1 : 0;
    if (rank < NSEPn) gpos[b * Gg + 1 + rank] = v;
  }
}

// ---------------- weight fp32 (K,N) -> bf16 (N,K), batched over z -----------
__global__ __launch_bounds__(256)
void wconv_kernel(const float* __restrict__ src0, u16* __restrict__ dst0,
                  int K, int N, int grp, long unit, long WLs) {
  __shared__ float t[32][33];
  int z = blockIdx.z;
  const float* src = src0 + (size_t)z * K * N;
  u16* dst = dst0 + (size_t)(z / grp) * WLs + (size_t)(z % grp) * unit;
  int n0 = blockIdx.x * 32, k0 = blockIdx.y * 32;
  int tx = threadIdx.x & 31, ty = threadIdx.x >> 5;  // ty 0..7
  #pragma unroll
  for (int i = 0; i < 4; ++i)
    t[ty + i * 8][tx] = src[(size_t)(k0 + ty + i * 8) * N + n0 + tx];
  __syncthreads();
  #pragma unroll
  for (int i = 0; i < 4; ++i)
    dst[(size_t)(n0 + ty + i * 8) * K + k0 + tx] = f2bf(t[tx][ty + i * 8]);
}

// ---------------- embedding + LN -------------------------------------------
__global__ __launch_bounds__(256)
void embed_ln_kernel(const int* __restrict__ ids, const float* __restrict__ we,
                     const float* __restrict__ pe, const float* __restrict__ te,
                     const float* __restrict__ lnp, float* __restrict__ x,
                     u16* __restrict__ xb) {
  int row = blockIdx.x;
  int s = row & (Ss - 1);
  int id = ids[row];
  int tid = threadIdx.x;
  float v[3]; float sm = 0.f, s2 = 0.f;
  #pragma unroll
  for (int i = 0; i < 3; ++i) {
    int c = tid + i * 256;
    float t = we[(size_t)id * Dd + c] + pe[(size_t)(s + 2) * Dd + c] + te[c];
    v[i] = t; sm += t; s2 += t * t;
  }
  __shared__ float r1[256], r2[256];
  r1[tid] = sm; r2[tid] = s2; __syncthreads();
  for (int o = 128; o; o >>= 1) {
    if (tid < o) { r1[tid] += r1[tid + o]; r2[tid] += r2[tid + o]; }
    __syncthreads();
  }
  float mean = r1[0] * (1.f / 768.f);
  float var  = r2[0] * (1.f / 768.f) - mean * mean;
  float rs = rsqrtf(var + 1e-5f);
  #pragma unroll
  for (int i = 0; i < 3; ++i) {
    int c = tid + i * 256;
    float o = (v[i] - mean) * rs * lnp[c] + lnp[Dd + c];
    x[(size_t)row * Dd + c] = o;
    xb[(size_t)row * Dd + c] = f2bf(o);
  }
}

// ---------------- residual(3-input) + LN ------------------------------------
__global__ __launch_bounds__(256)
void add_ln3_kernel(const float* __restrict__ xin, const float* __restrict__ y0,
                    const float* __restrict__ y1, const float* __restrict__ lnp,
                    float* __restrict__ xout, u16* __restrict__ xbout) {
  int row = blockIdx.x;
  int tid = threadIdx.x;
  float v[3]; float sm = 0.f, s2 = 0.f;
  #pragma unroll
  for (int i = 0; i < 3; ++i) {
    int c = tid + i * 256;
    size_t idx = (size_t)row * Dd + c;
    float t = xin[idx] + y0[idx] + y1[idx];
    v[i] = t; sm += t; s2 += t * t;
  }
  __shared__ float r1[256], r2[256];
  r1[tid] = sm; r2[tid] = s2; __syncthreads();
  for (int o = 128; o; o >>= 1) {
    if (tid < o) { r1[tid] += r1[tid + o]; r2[tid] += r2[tid + o]; }
    __syncthreads();
  }
  float mean = r1[0] * (1.f / 768.f);
  float var  = r2[0] * (1.f / 768.f) - mean * mean;
  float rs = rsqrtf(var + 1e-5f);
  #pragma unroll
  for (int i = 0; i < 3; ++i) {
    int c = tid + i * 256;
    float o = (v[i] - mean) * rs * lnp[c] + lnp[Dd + c];
    xout[(size_t)row * Dd + c] = o;
    xbout[(size_t)row * Dd + c] = f2bf(o);
  }
}

// ---------------- GEMM2: glds-staged dbuf 128x128, split-K capable ----------
// Ks = row stride of A/Bt (full K); Kl = K-extent per z-slice; koff = z*Kl.
// MODE 0: fp32 [M][N] (+bias on z==0); z==1 writes outf2
// MODE 1: bf16 [M][N], exact gelu
// MODE 2: fused QKV: N=2304; sec0->q packed (scale), sec1->k padded, sec2->v^T padded
// MODE 3: fused gKV:  N=1536; sec0->k packed, sec1->v^T [bh][64][Ss]
// MODE 4: bf16 [M][N] * scale
template <int MODE>
__global__ __launch_bounds__(256)
void gemm2_kernel(const u16* __restrict__ A, const u16* __restrict__ Bt,
                  const float* __restrict__ bias, float* __restrict__ outf,
                  float* __restrict__ outf2,
                  u16* __restrict__ o0, u16* __restrict__ o1, u16* __restrict__ o2,
                  int N, int Ks, int Kl, float scale) {
  __shared__ u16 la[2][128 * 32], lb[2][128 * 32];
  int tid = threadIdx.x;
  int wave = tid >> 6, lane = tid & 63;
  int wr = wave >> 1, wc = wave & 1;
  int lg = lane >> 4, lc = lane & 15;
  int row0 = blockIdx.y * 128, col0 = blockIdx.x * 128;
  int koff = blockIdx.z * Kl;

  const u16* Ag = A + (size_t)(row0 + wave * 32 + (lane >> 2)) * Ks + (lane & 3) * 8 + koff;
  const u16* Bg = Bt + (size_t)(col0 + wave * 32 + (lane >> 2)) * Ks + (lane & 3) * 8 + koff;
  int wofs = wave * 1024;

  f32x4 acc[4][4];
  #pragma unroll
  for (int m = 0; m < 4; ++m)
    #pragma unroll
    for (int n = 0; n < 4; ++n) acc[m][n] = (f32x4){0.f, 0.f, 0.f, 0.f};

  // prologue: stage K-tile 0 into buf 0
  glds16(Ag, la[0] + wofs);
  glds16(Ag + (size_t)16 * Ks, la[0] + wofs + 512);
  glds16(Bg, lb[0] + wofs);
  glds16(Bg + (size_t)16 * Ks, lb[0] + wofs + 512);
  __syncthreads();

  int nk = Kl >> 5;
  for (int t = 0; t < nk; ++t) {
    int cur = t & 1;
    if (t + 1 < nk) {  // prefetch next tile into other buffer (flies under MFMA)
      int k1 = (t + 1) << 5;
      glds16(Ag + k1, la[cur ^ 1] + wofs);
      glds16(Ag + (size_t)16 * Ks + k1, la[cur ^ 1] + wofs + 512);
      glds16(Bg + k1, lb[cur ^ 1] + wofs);
      glds16(Bg + (size_t)16 * Ks + k1, lb[cur ^ 1] + wofs + 512);
    }
    bv8 af[4], bf_[4];
    #pragma unroll
    for (int m = 0; m < 4; ++m)
      af[m] = *reinterpret_cast<const bv8*>(la[cur] + (wr * 64 + m * 16 + lc) * 32 + lg * 8);
    #pragma unroll
    for (int n = 0; n < 4; ++n)
      bf_[n] = *reinterpret_cast<const bv8*>(lb[cur] + (wc * 64 + n * 16 + lc) * 32 + lg * 8);
    __builtin_amdgcn_s_setprio(1);
    #pragma unroll
    for (int m = 0; m < 4; ++m)
      #pragma unroll
      for (int n = 0; n < 4; ++n)
        acc[m][n] = __builtin_amdgcn_mfma_f32_16x16x32_bf16(af[m], bf_[n], acc[m][n], 0, 0, 0);
    __builtin_amdgcn_s_setprio(0);
    __syncthreads();  // drains prefetch (vmcnt0) + joins waves
  }

  #pragma unroll
  for (int m = 0; m < 4; ++m) {
    int grow0 = row0 + wr * 64 + m * 16 + lg * 4;
    #pragma unroll
    for (int n = 0; n < 4; ++n) {
      int gcol = col0 + wc * 64 + n * 16 + lc;
      float bvl = bias[gcol];
      if (MODE == 0) {
        float* od = blockIdx.z ? outf2 : outf;
        float badd = blockIdx.z ? 0.f : bvl;
        #pragma unroll
        for (int r = 0; r < 4; ++r)
          od[(size_t)(grow0 + r) * N + gcol] = acc[m][n][r] + badd;
      } else if (MODE == 1) {
        #pragma unroll
        for (int r = 0; r < 4; ++r) {
          float v = acc[m][n][r] + bvl;
          v = 0.5f * v * (1.0f + erff(v * 0.70710678118654752f));
          o0[(size_t)(grow0 + r) * N + gcol] = f2bf(v);
        }
      } else if (MODE == 4) {
        #pragma unroll
        for (int r = 0; r < 4; ++r)
          o0[(size_t)(grow0 + r) * N + gcol] = f2bf((acc[m][n][r] + bvl) * scale);
      } else if (MODE == 2) {
        int sec = col0 >= 1536 ? 2 : (col0 >= 768 ? 1 : 0);
        int colr = gcol - sec * 768;
        int hh = colr >> 6, d = colr & 63;
        int bb = grow0 >> 12, s = grow0 & (Ss - 1);
        size_t bhh = (size_t)(bb * Hh + hh);
        if (sec == 0) {
          #pragma unroll
          for (int r = 0; r < 4; ++r)
            o0[(bhh * Ss + s + r) * 64 + d] = f2bf((acc[m][n][r] + bvl) * scale);
        } else if (sec == 1) {
          #pragma unroll
          for (int r = 0; r < 4; ++r)
            o1[(bhh * SPAD + PADL + s + r) * 64 + d] = f2bf(acc[m][n][r] + bvl);
        } else {
          sv4 pk;
          #pragma unroll
          for (int r = 0; r < 4; ++r) pk[r] = (short)f2bf(acc[m][n][r] + bvl);
          *reinterpret_cast<sv4*>(o2 + (bhh * 64 + d) * SPAD + PADL + s) = pk;
        }
      } else if (MODE == 3) {
        int sec = col0 >= 768 ? 1 : 0;
        int colr = gcol - sec * 768;
        int hh = colr >> 6, d = colr & 63;
        int bb = grow0 >> 12, s = grow0 & (Ss - 1);
        size_t bhh = (size_t)(bb * Hh + hh);
        if (sec == 0) {
          #pragma unroll
          for (int r = 0; r < 4; ++r)
            o0[(bhh * Ss + s + r) * 64 + d] = f2bf(acc[m][n][r] + bvl);
        } else {
          sv4 pk;
          #pragma unroll
          for (int r = 0; r < 4; ++r) pk[r] = (short)f2bf(acc[m][n][r] + bvl);
          *reinterpret_cast<sv4*>(o1 + (bhh * 64 + d) * Ss + s) = pk;
        }
      }
    }
  }
}

// ---------------- gathers ---------------------------------------------------
__global__ __launch_bounds__(256)
void gather_glob_kernel(const u16* __restrict__ kpk, const u16* __restrict__ vtpk,
                        const int* __restrict__ gpos, u16* __restrict__ kg,
                        u16* __restrict__ vgt) {
  int bh = blockIdx.x;
  int b = bh / Hh;
  int tid = threadIdx.x;
  for (int idx = tid; idx < 64 * 64; idx += 256) {
    int g = idx >> 6, d = idx & 63;
    u16 kv = 0, vv = 0;
    if (g < Gg) {
      int p = gpos[b * Gg + g];
      kv = kpk[((size_t)bh * SPAD + PADL + p) * 64 + d];
      vv = vtpk[((size_t)bh * 64 + d) * SPAD + PADL + p];
    }
    kg[(size_t)bh * 4096 + idx] = kv;
    vgt[((size_t)bh * 64 + d) * 64 + g] = vv;
  }
}

__global__ __launch_bounds__(256)
void gather_xg_kernel(const u16* __restrict__ xb, const int* __restrict__ gpos,
                      u16* __restrict__ xg) {
  int rg = blockIdx.x;  // b*G+g
  int b = rg / Gg;
  int p = gpos[rg];
  int tid = threadIdx.x;
  for (int c = tid; c < Dd; c += 256)
    xg[(size_t)rg * Dd + c] = xb[((size_t)b * Ss + p) * Dd + c];
}

// ---------------- local (sliding window + global-key) attention -------------
// 4 waves/block, 64 queries/block; XCD swizzle; 64-key steps (step 0 = global
// keys). Software pipeline: V loads issued at step top, next-step K loads
// issued before this step's compute -> one full step of latency hiding.
#define LOCAL_NB (Bb * Hh * (Ss / 64))   // 1536 blocks, %8 == 0
__global__ __launch_bounds__(256)
void attn_local_kernel(const u16* __restrict__ qpk, const u16* __restrict__ kpk,
                       const u16* __restrict__ vtpk, const u16* __restrict__ kg,
                       const u16* __restrict__ vgt, const int* __restrict__ amask,
                       u16* __restrict__ ctx) {
  __shared__ u16 Plds[4][16 * PSTR];
  int bid = blockIdx.x;
  int swz = (bid & 7) * (LOCAL_NB / 8) + (bid >> 3);
  int qb = swz & 63;
  int bh = swz >> 6;
  int b = bh / Hh;
  int h = bh - b * Hh;
  int wv = threadIdx.x >> 6;
  int q0 = qb * 64 + wv * 16;
  int lane = threadIdx.x & 63;
  int lg = lane >> 4, lc = lane & 15;
  int lg4 = lg * 4;
  int q = q0 + lc;   // query owned by this lane for softmax state

  const u16* qbase = qpk + (((size_t)bh) * Ss + q0) * 64;
  bv8 aq0 = *reinterpret_cast<const bv8*>(qbase + (size_t)lc * 64 + lg * 8);
  bv8 aq1 = *reinterpret_cast<const bv8*>(qbase + (size_t)lc * 64 + 32 + lg * 8);

  f32x4 o[4];
  #pragma unroll
  for (int i = 0; i < 4; ++i) o[i] = (f32x4){0.f, 0.f, 0.f, 0.f};
  float mrun = -1e30f, lrun = 0.f;

  const u16* kgb = kg + ((size_t)bh) * 64 * 64;
  const u16* vgb = vgt + ((size_t)bh) * 64 * 64;
  const u16* kb = kpk + ((size_t)bh) * SPAD * 64;
  const u16* vb = vtpk + ((size_t)bh) * 64 * SPAD;
  const int* amb = amask + b * Ss;
  u16* P = &Plds[wv][0];

  // preload K frags for step 0 (global keys)
  bv8 kc[8];
  #pragma unroll
  for (int j = 0; j < 4; ++j) {
    const u16* kr = kgb + (size_t)(j * 16 + lc) * 64;
    kc[2 * j]     = *reinterpret_cast<const bv8*>(kr + lg * 8);
    kc[2 * j + 1] = *reinterpret_cast<const bv8*>(kr + 32 + lg * 8);
  }
  // prefetch amask word for step 1
  int amvN;
  { int ni = min(max(q0 - 256 + lane, 0), Ss - 1); amvN = amb[ni]; }

  for (int step = 0; step < 10; ++step) {
    bool isg = (step == 0);
    int ks = isg ? 0 : (q0 - 256 + (step - 1) * 64);
    int amvC = amvN;
    if (step < 9) { int ni = min(max(q0 - 256 + step * 64 + lane, 0), Ss - 1); amvN = amb[ni]; }

    // issue V loads for this step (consumed after softmax)
    bv8 vf[8];
    #pragma unroll
    for (int j2 = 0; j2 < 2; ++j2)
      #pragma unroll
      for (int nt = 0; nt < 4; ++nt) {
        const u16* vr = isg ? (vgb + (size_t)(nt * 16 + lc) * 64 + j2 * 32)
                            : (vb + (size_t)(nt * 16 + lc) * SPAD + PADL + ks + j2 * 32);
        vf[j2 * 4 + nt] = *reinterpret_cast<const bv8*>(vr + lg * 8);
      }
    // issue next-step K loads (steps 1..9 are always local-window)
    bv8 kn[8];
    if (step < 9) {
      int ksn = q0 - 256 + step * 64;
      #pragma unroll
      for (int j = 0; j < 4; ++j) {
        const u16* kr = kb + (size_t)(PADL + ksn + j * 16 + lc) * 64;
        kn[2 * j]     = *reinterpret_cast<const bv8*>(kr + lg * 8);
        kn[2 * j + 1] = *reinterpret_cast<const bv8*>(kr + 32 + lg * 8);
      }
    }
    // key-validity mask
    unsigned long long kmask;
    if (isg) {
      kmask = (1ull << Gg) - 1;
    } else {
      int kidx = ks + lane;
      kmask = __ballot((kidx >= 0) && (kidx < Ss) && (amvC > 0));
    }
    // QK^T (swapped operands): sc[j] = scores for keys ks+j*16+lg4..+3, query lc
    f32x4 sc[4];
    __builtin_amdgcn_s_setprio(1);
    #pragma unroll
    for (int j = 0; j < 4; ++j) {
      f32x4 z = (f32x4){0.f, 0.f, 0.f, 0.f};
      sc[j] = __builtin_amdgcn_mfma_f32_16x16x32_bf16(kc[2 * j], aq0, z, 0, 0, 0);
      sc[j] = __builtin_amdgcn_mfma_f32_16x16x32_bf16(kc[2 * j + 1], aq1, sc[j], 0, 0, 0);
    }
    __builtin_amdgcn_s_setprio(0);
    // masking: steps 2..8 with full kmask are band-safe for all 16 queries
    float mloc = -1e30f;
    bool fast = (!isg) && (step >= 2) && (step <= 8) && (kmask == ~0ull);
    if (fast) {
      #pragma unroll
      for (int j = 0; j < 4; ++j)
        #pragma unroll
        for (int r = 0; r < 4; ++r) mloc = fmaxf(mloc, sc[j][r]);
    } else {
      #pragma unroll
      for (int j = 0; j < 4; ++j)
        #pragma unroll
        for (int r = 0; r < 4; ++r) {
          int kk = ks + j * 16 + lg4 + r;
          bool ok = (kmask >> (j * 16 + lg4 + r)) & 1;
          if (!isg) ok = ok && ((unsigned)(kk - q + 256) <= 512u);
          sc[j][r] = ok ? sc[j][r] : -1e9f;
          mloc = fmaxf(mloc, sc[j][r]);
        }
    }
    mloc = fmaxf(mloc, __shfl_xor(mloc, 16));
    mloc = fmaxf(mloc, __shfl_xor(mloc, 32));
    if (__any(mloc > mrun)) {
      float nm = fmaxf(mrun, mloc);
      float scal = __expf(mrun - nm);
      mrun = nm;
      lrun *= scal;
      #pragma unroll
      for (int r = 0; r < 4; ++r) {
        float sr = __shfl(scal, lg4 + r);  // scal of query lg4+r
        #pragma unroll
        for (int nt = 0; nt < 4; ++nt) o[nt][r] *= sr;
      }
    }
    float psum = 0.f;
    #pragma unroll
    for (int j = 0; j < 4; ++j) {
      sv4 pk;
      #pragma unroll
      for (int r = 0; r < 4; ++r) {
        float p = __expf(sc[j][r] - mrun);
        psum += p;
        pk[r] = (short)f2bf(p);
      }
      *reinterpret_cast<sv4*>(P + lc * PSTR + j * 16 + lg4) = pk;
    }
    psum += __shfl_xor(psum, 16);
    psum += __shfl_xor(psum, 32);
    lrun += psum;
    // PV with prefetched V frags
    __builtin_amdgcn_s_setprio(1);
    #pragma unroll
    for (int j2 = 0; j2 < 2; ++j2) {
      bv8 ap = *reinterpret_cast<const bv8*>(P + lc * PSTR + j2 * 32 + lg * 8);
      #pragma unroll
      for (int nt = 0; nt < 4; ++nt)
        o[nt] = __builtin_amdgcn_mfma_f32_16x16x32_bf16(ap, vf[j2 * 4 + nt], o[nt], 0, 0, 0);
    }
    __builtin_amdgcn_s_setprio(0);
    if (step < 9) {
      #pragma unroll
      for (int i = 0; i < 8; ++i) kc[i] = kn[i];
    }
  }
  float inv = 1.0f / lrun;
  #pragma unroll
  for (int r = 0; r < 4; ++r) {
    float invr = __shfl(inv, lg4 + r);
    size_t rowoff = ((size_t)b * Ss + q0 + lg4 + r) * Dd + h * 64;
    #pragma unroll
    for (int nt = 0; nt < 4; ++nt)
      ctx[rowoff + nt * 16 + lc] = f2bf(o[nt][r] * invr);
  }
}

// ---------------- global-query attention: chunked flash MFMA ----------------
__global__ __launch_bounds__(192)
void attn_globalq_kernel(const u16* __restrict__ qgb, const u16* __restrict__ kgf,
                         const u16* __restrict__ vgt, const int* __restrict__ amask,
                         float* __restrict__ part) {
  __shared__ u16 Plds[3][16 * 32];
  int blk = blockIdx.x;
  int ch = blk & (NCH - 1);
  int bh = blk / NCH;
  int b = bh / Hh, h = bh - b * Hh;
  int wv = threadIdx.x >> 6;  // q-tile 0..2
  int lane = threadIdx.x & 63;
  int lg = lane >> 4, lc = lane & 15;

  int qrow = wv * 16 + lc;
  bv8 aq0 = (bv8)0, aq1 = (bv8)0;
  if (qrow < Gg) {
    const u16* qr = qgb + (size_t)(b * Gg + qrow) * Dd + h * 64;
    aq0 = *reinterpret_cast<const bv8*>(qr + lg * 8);
    aq1 = *reinterpret_cast<const bv8*>(qr + 32 + lg * 8);
  }

  f32x4 o[4];
  float mrun[4], lrun[4];
  #pragma unroll
  for (int i = 0; i < 4; ++i) { o[i] = (f32x4){0.f,0.f,0.f,0.f}; mrun[i] = -1e30f; lrun[i] = 0.f; }

  const u16* kb = kgf + ((size_t)bh) * Ss * 64;
  const u16* vb = vgt + ((size_t)bh) * 64 * Ss;
  const int* amb = amask + b * Ss;
  int ks0 = ch * (Ss / NCH);

  for (int st = 0; st < (Ss / NCH) / 32; ++st) {
    int ks = ks0 + st * 32;
    f32x4 sc0, sc1;
    {
      const u16* kr0 = kb + (size_t)(ks + lc) * 64;
      const u16* kr1 = kr0 + 16 * 64;
      bv8 b00 = *reinterpret_cast<const bv8*>(kr0 + lg * 8);
      bv8 b01 = *reinterpret_cast<const bv8*>(kr0 + 32 + lg * 8);
      bv8 b10 = *reinterpret_cast<const bv8*>(kr1 + lg * 8);
      bv8 b11 = *reinterpret_cast<const bv8*>(kr1 + 32 + lg * 8);
      f32x4 z = (f32x4){0.f,0.f,0.f,0.f};
      sc0 = __builtin_amdgcn_mfma_f32_16x16x32_bf16(aq0, b00, z, 0, 0, 0);
      sc0 = __builtin_amdgcn_mfma_f32_16x16x32_bf16(aq1, b01, sc0, 0, 0, 0);
      sc1 = __builtin_amdgcn_mfma_f32_16x16x32_bf16(aq0, b10, z, 0, 0, 0);
      sc1 = __builtin_amdgcn_mfma_f32_16x16x32_bf16(aq1, b11, sc1, 0, 0, 0);
    }
    bool v0 = amb[ks + lc] > 0;
    bool v1 = amb[ks + 16 + lc] > 0;
    #pragma unroll
    for (int r = 0; r < 4; ++r) {
      float s0 = v0 ? sc0[r] : -1e9f;
      float s1 = v1 ? sc1[r] : -1e9f;
      float rm = fmaxf(s0, s1);
      #pragma unroll
      for (int off = 1; off < 16; off <<= 1) rm = fmaxf(rm, __shfl_xor(rm, off));
      float nm = fmaxf(mrun[r], rm);
      float scal = __expf(mrun[r] - nm);
      float p0 = __expf(s0 - nm);
      float p1 = __expf(s1 - nm);
      float ps = p0 + p1;
      #pragma unroll
      for (int off = 1; off < 16; off <<= 1) ps += __shfl_xor(ps, off);
      lrun[r] = lrun[r] * scal + ps;
      mrun[r] = nm;
      #pragma unroll
      for (int nt = 0; nt < 4; ++nt) o[nt][r] *= scal;
      int prow = lg * 4 + r;
      Plds[wv][prow * 32 + lc] = f2bf(p0);
      Plds[wv][prow * 32 + 16 + lc] = f2bf(p1);
    }
    bv8 ap = *reinterpret_cast<const bv8*>(&Plds[wv][lc * 32 + lg * 8]);
    #pragma unroll
    for (int nt = 0; nt < 4; ++nt) {
      const u16* vr = vb + (size_t)(nt * 16 + lc) * Ss + ks;
      bv8 bvv = *reinterpret_cast<const bv8*>(vr + lg * 8);
      o[nt] = __builtin_amdgcn_mfma_f32_16x16x32_bf16(ap, bvv, o[nt], 0, 0, 0);
    }
  }

  float* pb = part + ((size_t)(bh * 3 + wv) * NCH + ch) * PARTF;
  #pragma unroll
  for (int r = 0; r < 4; ++r) {
    int row = lg * 4 + r;
    #pragma unroll
    for (int nt = 0; nt < 4; ++nt)
      pb[row * 64 + nt * 16 + lc] = o[nt][r];
    if (lc == 0) {
      pb[1024 + row] = mrun[r];
      pb[1040 + row] = lrun[r];
    }
  }
}

// merge NCH chunk-partials and scatter into ctx rows at gpos
__global__ __launch_bounds__(256)
void attn_gmerge_kernel(const float* __restrict__ part, const int* __restrict__ gpos,
                        u16* __restrict__ ctx) {
  __shared__ float wgt[Gg][NCH];
  __shared__ float sinvl[Gg];
  int bh = blockIdx.x;
  int b = bh / Hh, h = bh - b * Hh;
  int tid = threadIdx.x;
  if (tid < Gg) {
    int qt = tid >> 4, rr = tid & 15;
    const float* pb = part + ((size_t)(bh * 3 + qt) * NCH) * PARTF;
    float mx = -1e30f;
    for (int c = 0; c < NCH; ++c) mx = fmaxf(mx, pb[c * PARTF + 1024 + rr]);
    float l = 0.f;
    for (int c = 0; c < NCH; ++c) {
      float w = __expf(pb[c * PARTF + 1024 + rr] - mx);
      wgt[tid][c] = w;
      l += w * pb[c * PARTF + 1040 + rr];
    }
    sinvl[tid] = 1.0f / l;
  }
  __syncthreads();
  for (int e = tid; e < Gg * 64; e += 256) {
    int row = e >> 6, d = e & 63;
    int qt = row >> 4, rr = row & 15;
    const float* pb = part + ((size_t)(bh * 3 + qt) * NCH) * PARTF + rr * 64 + d;
    float acc = 0.f;
    #pragma unroll
    for (int c = 0; c < NCH; ++c) acc += wgt[row][c] * pb[c * PARTF];
    int pos = gpos[b * Gg + row];
    ctx[((size_t)b * Ss + pos) * Dd + h * 64 + d] = f2bf(acc * sinvl[row]);
  }
}

// ---------------- classifier ------------------------------------------------
__global__ __launch_bounds__(64)
void cls_kernel(const float* __restrict__ x, const float* __restrict__ W,
                const float* __restrict__ bias, const int* __restrict__ gpos,
                float* __restrict__ out) {
  int r = blockIdx.x;  // b*32 + i
  int b = r >> 5, i = r & 31;
  int pos = gpos[b * Gg + 1 + i];
  int lane = threadIdx.x;
  const float* xr = x + ((size_t)b * Ss + pos) * Dd;
  float acc[NCLSn] = {0.f, 0.f, 0.f, 0.f, 0.f};
  for (int k = lane; k < Dd; k += 64) {
    float xv = xr[k];
    #pragma unroll
    for (int c = 0; c < NCLSn; ++c) acc[c] += xv * W[c * Dd + k];
  }
  #pragma unroll
  for (int c = 0; c < NCLSn; ++c) {
    #pragma unroll
    for (int off = 1; off < 64; off <<= 1) acc[c] += __shfl_xor(acc[c], off);
  }
  if (lane == 0) {
    #pragma unroll
    for (int c = 0; c < NCLSn; ++c) out[r * NCLSn + c] = acc[c] + bias[c];
  }
}

// ---------------------------------------------------------------------------
extern "C" void kernel_launch(void* const* d_in, const int* in_sizes, int n_in,
                              void* d_out, int out_size, void* d_ws, size_t ws_size,
                              hipStream_t stream) {
  const int* ids     = (const int*)d_in[0];
  const int* amask   = (const int*)d_in[1];
  const float* we    = (const float*)d_in[2];
  const float* pe    = (const float*)d_in[3];
  const float* te    = (const float*)d_in[4];
  const float* embln = (const float*)d_in[5];
  const float* Wqkv  = (const float*)d_in[6];
  const float* bqkv  = (const float*)d_in[7];
  const float* Wqkvg = (const float*)d_in[8];
  const float* bqkvg = (const float*)d_in[9];
  const float* Wo    = (const float*)d_in[10];
  const float* bo    = (const float*)d_in[11];
  const float* ln1   = (const float*)d_in[12];
  const float* Wff1  = (const float*)d_in[13];
  const float* bff1  = (const float*)d_in[14];
  const float* Wff2  = (const float*)d_in[15];
  const float* bff2  = (const float*)d_in[16];
  const float* ln2   = (const float*)d_in[17];
  const float* clsW  = (const float*)d_in[18];
  const float* clsb  = (const float*)d_in[19];
  float* out = (float*)d_out;

  char* ws = (char*)d_ws;
  size_t off = 0;
  auto alloc = [&](size_t bytes) { size_t o = off; off += (bytes + 255) & ~(size_t)255; return o; };

  const size_t DD = (size_t)Dd * Dd;        // 589824
  const size_t DF = (size_t)Dd * 4 * Dd;    // 2359296
  const size_t WL = 7 * DD + 2 * DF;        // elems per layer

  size_t o_cnt  = alloc(Bb * 4);
  size_t o_list = alloc(Bb * 64 * 4);
  size_t o_gpos = alloc(Bb * Gg * 4);
  size_t o_w    = alloc(WL * Ll * 2);
  size_t o_x    = alloc((size_t)Bb * Ss * Dd * 4);
  size_t o_xb   = alloc((size_t)Bb * Ss * Dd * 2);
  // kgf/vgf first: their 25.17 MB doubles as split-K buffer B (dead by Wo/FF2)
  size_t o_kgf  = alloc((size_t)Bb * Hh * Ss * 64 * 2);
  size_t o_vgf  = alloc((size_t)Bb * Hh * Ss * 64 * 2);
  size_t o_accB = o_kgf;  // 2*12.58 MB = exactly 8192*768*4 bytes
  size_t o_qpk  = alloc((size_t)Bb * Hh * Ss * 64 * 2);
  size_t o_kpk  = alloc((size_t)Bb * Hh * SPAD * 64 * 2);
  size_t o_vtpk = alloc((size_t)Bb * Hh * 64 * SPAD * 2);
  size_t o_kg   = alloc((size_t)Bb * Hh * 64 * 64 * 2);
  size_t o_vgt  = alloc((size_t)Bb * Hh * 64 * 64 * 2);
  size_t o_xg   = alloc((size_t)128 * Dd * 2);
  size_t o_qg   = alloc((size_t)128 * Dd * 2);
  size_t o_part = alloc((size_t)Bb * Hh * 3 * NCH * PARTF * 4);
  size_t o_f1b  = o_qpk;  // FFN hidden aliases the (dead-by-then) attention buffers
  {
    size_t f1b_bytes = (size_t)Bb * Ss * 4 * Dd * 2;
    if (off - o_qpk < f1b_bytes) off = o_qpk + ((f1b_bytes + 255) & ~(size_t)255);
  }
  size_t o_ctx = alloc((size_t)Bb * Ss * Dd * 2);
  size_t o_acc = alloc((size_t)Bb * Ss * Dd * 4);
  if (ws_size < off) return;  // workspace too small -> fail visibly

  u16* Wb = (u16*)(ws + o_w);
  int* gposp = (int*)(ws + o_gpos);
  float* accA = (float*)(ws + o_acc);
  float* accB = (float*)(ws + o_accB);

  (void)hipMemsetAsync(ws + o_cnt, 0, Bb * 4, stream);
  // zero padded K / V^T so first-call pads are finite (later calls: finite stale bf16)
  (void)hipMemsetAsync(ws + o_kpk, 0, (size_t)Bb * Hh * SPAD * 64 * 2, stream);
  (void)hipMemsetAsync(ws + o_vtpk, 0, (size_t)Bb * Hh * 64 * SPAD * 2, stream);
  (void)hipMemsetAsync(ws + o_xg, 0, (size_t)128 * Dd * 2, stream);

  sep_find_kernel<<<(Bb * Ss + 255) / 256, 256, 0, stream>>>(ids, (int*)(ws + o_cnt), (int*)(ws + o_list));
  sep_sort_kernel<<<Bb, 64, 0, stream>>>((int*)(ws + o_cnt), (int*)(ws + o_list), gposp);

  // weight conversions (batched over z)
  wconv_kernel<<<dim3(24, 24, 6), 256, 0, stream>>>(Wqkv,  Wb,          Dd, Dd, 3, (long)DD, (long)WL);
  wconv_kernel<<<dim3(24, 24, 6), 256, 0, stream>>>(Wqkvg, Wb + 3 * DD, Dd, Dd, 3, (long)DD, (long)WL);
  wconv_kernel<<<dim3(24, 24, 2), 256, 0, stream>>>(Wo,    Wb + 6 * DD, Dd, Dd, 1, 0L, (long)WL);
  wconv_kernel<<<dim3(96, 24, 2), 256, 0, stream>>>(Wff1,  Wb + 7 * DD, Dd, 4 * Dd, 1, 0L, (long)WL);
  wconv_kernel<<<dim3(24, 96, 2), 256, 0, stream>>>(Wff2,  Wb + 7 * DD + DF, 4 * Dd, Dd, 1, 0L, (long)WL);

  embed_ln_kernel<<<Bb * Ss, 256, 0, stream>>>(ids, we, pe, te, embln, (float*)(ws + o_x), (u16*)(ws + o_xb));

  for (int l = 0; l < Ll; ++l) {
    size_t wb = (size_t)l * WL;
    u16* xb = (u16*)(ws + o_xb);
    // fused QKV projection (N=2304)
    gemm2_kernel<2><<<dim3(18, 64), 256, 0, stream>>>(xb, Wb + wb, bqkv + (size_t)l * 3 * Dd, nullptr, nullptr,
        (u16*)(ws + o_qpk), (u16*)(ws + o_kpk), (u16*)(ws + o_vtpk), 2304, Dd, Dd, 0.125f);
    gather_glob_kernel<<<Bb * Hh, 256, 0, stream>>>((u16*)(ws + o_kpk), (u16*)(ws + o_vtpk), gposp, (u16*)(ws + o_kg), (u16*)(ws + o_vgt));
    gather_xg_kernel<<<Bb * Gg, 256, 0, stream>>>(xb, gposp, (u16*)(ws + o_xg));
    // global q projection (M=128 padded rows)
    gemm2_kernel<4><<<dim3(6, 1), 256, 0, stream>>>((u16*)(ws + o_xg), Wb + wb + 3 * DD, bqkvg + (size_t)l * 3 * Dd, nullptr, nullptr,
        (u16*)(ws + o_qg), nullptr, nullptr, Dd, Dd, Dd, 0.125f);
    // fused global K/V (N=1536)
    gemm2_kernel<3><<<dim3(12, 64), 256, 0, stream>>>(xb, Wb + wb + 4 * DD, bqkvg + (size_t)(l * 3 + 1) * Dd, nullptr, nullptr,
        (u16*)(ws + o_kgf), (u16*)(ws + o_vgf), nullptr, 1536, Dd, Dd, 1.0f);
    // attention
    attn_local_kernel<<<LOCAL_NB, 256, 0, stream>>>((u16*)(ws + o_qpk), (u16*)(ws + o_kpk), (u16*)(ws + o_vtpk), (u16*)(ws + o_kg), (u16*)(ws + o_vgt), amask, (u16*)(ws + o_ctx));
    attn_globalq_kernel<<<Bb * Hh * NCH, 192, 0, stream>>>((u16*)(ws + o_qg), (u16*)(ws + o_kgf), (u16*)(ws + o_vgf), amask, (float*)(ws + o_part));
    attn_gmerge_kernel<<<Bb * Hh, 256, 0, stream>>>((float*)(ws + o_part), gposp, (u16*)(ws + o_ctx));
    // output projection (split-K x2) + LN   [kgf/vgf dead from here on]
    gemm2_kernel<0><<<dim3(6, 64, 2), 256, 0, stream>>>((u16*)(ws + o_ctx), Wb + wb + 6 * DD, bo + (size_t)l * Dd, accA, accB,
        nullptr, nullptr, nullptr, Dd, Dd, Dd / 2, 1.0f);
    add_ln3_kernel<<<Bb * Ss, 256, 0, stream>>>((float*)(ws + o_x), accA, accB, ln1 + (size_t)l * 2 * Dd, (float*)(ws + o_x), xb);
    // FFN
    gemm2_kernel<1><<<dim3(24, 64), 256, 0, stream>>>(xb, Wb + wb + 7 * DD, bff1 + (size_t)l * 4 * Dd, nullptr, nullptr,
        (u16*)(ws + o_f1b), nullptr, nullptr, 4 * Dd, Dd, Dd, 1.0f);
    gemm2_kernel<0><<<dim3(6, 64, 2), 256, 0, stream>>>((u16*)(ws + o_f1b), Wb + wb + 7 * DD + DF, bff2 + (size_t)l * Dd, accA, accB,
        nullptr, nullptr, nullptr, Dd, 4 * Dd, 2 * Dd, 1.0f);
    add_ln3_kernel<<<Bb * Ss, 256, 0, stream>>>((float*)(ws + o_x), accA, accB, ln2 + (size_t)l * 2 * Dd, (float*)(ws + o_x), xb);
  }

  cls_kernel<<<Bb * NSEPn, 64, 0, stream>>>((float*)(ws + o_x), clsW, clsb, gposp, out);
}

// Round 7
// 875.690 us; speedup vs baseline: 2.4231x; 1.0153x over previous
//
#include <hip/hip_runtime.h>

// ---------------------------------------------------------------------------
// Longformer (2-layer) forward, MI355X.
// R6: (a) attn_local register diet: single kc K-fragment buffer reloaded
//         in-place after QK^T (VGPR 100->~76, occupancy back up).
//     (b) QKV+gKV fused into one N=3840 GEMM (5 epilogue sections),
//         A read once, 1920-block grid; concat bias buffer.
// ---------------------------------------------------------------------------

#define Bb 2
#define Ss 4096
#define Dd 768
#define Hh 12
#define Gg 33
#define NSEPn 32
#define Ll 2
#define SPAD 4640   // S + 544 (PADL=256 left, 288 right)
#define PADL 256
#define NCLSn 5
#define NCH 16      // key chunks for global-q attention (256 keys each)
#define PARTF 1056  // floats per (bh,qt,chunk) partial: 16*64 o + 16 m + 16 l
#define PSTR 72     // Plds row stride in u16 (144B: 16B-aligned, bank-spread)

typedef unsigned short u16;
typedef __attribute__((ext_vector_type(8))) short bv8;   // 8 x bf16
typedef __attribute__((ext_vector_type(4))) short sv4;   // 4 x bf16
typedef __attribute__((ext_vector_type(4))) float f32x4;

__device__ __forceinline__ float bf2f(u16 u) {
  unsigned v = ((unsigned)u) << 16;
  return __builtin_bit_cast(float, v);
}
__device__ __forceinline__ u16 f2bf(float f) {
  unsigned u = __builtin_bit_cast(unsigned, f);
  u += 0x7fffu + ((u >> 16) & 1u);
  return (u16)(u >> 16);
}
__device__ __forceinline__ void glds16(const void* g, void* l) {
  __builtin_amdgcn_global_load_lds(
      (const __attribute__((address_space(1))) void*)g,
      (__attribute__((address_space(3))) void*)l, 16, 0, 0);
}

// ---------------- sep finding --------------------------------------------
__global__ void sep_find_kernel(const int* __restrict__ ids, int* __restrict__ cnt,
                                int* __restrict__ list) {
  int i = blockIdx.x * 256 + threadIdx.x;
  if (i >= Bb * Ss) return;
  int b = i >> 12;
  if (ids[i] == 2) {
    int idx = atomicAdd(&cnt[b], 1);
    if (idx < 64) list[b * 64 + idx] = i & (Ss - 1);
  }
}

__global__ void sep_sort_kernel(const int* __restrict__ cnt, const int* __restrict__ list,
                                int* __restrict__ gpos) {
  int b = blockIdx.x;
  int t = threadIdx.x;
  int n = cnt[b]; if (n > 64) n = 64;
  if (t < Gg) gpos[b * Gg + t] = (t == 0) ? 0 : (Ss - 1);
  __syncthreads();
  if (t < n) {
    int v = list[b * 64 + t];
    int rank = 0;
    for (int j = 0; j < n; ++j) rank += (list[b * 64 + j] < v) ? 1 : 0;
    if (rank < NSEPn) gpos[b * Gg + 1 + rank] = v;
  }
}

// ------- weight fp32 (K,N) -> bf16 (N,K), batched; src slice (z/grp)*sstr+z%grp
__global__ __launch_bounds__(256)
void wconv_kernel(const float* __restrict__ src0, u16* __restrict__ dst0,
                  int K, int N, int grp, int sstr, long unit, long WLs) {
  __shared__ float t[32][33];
  int z = blockIdx.z;
  const float* src = src0 + (size_t)((z / grp) * sstr + (z % grp)) * K * N;
  u16* dst = dst0 + (size_t)(z / grp) * WLs + (size_t)(z % grp) * unit;
  int n0 = blockIdx.x * 32, k0 = blockIdx.y * 32;
  int tx = threadIdx.x & 31, ty = threadIdx.x >> 5;  // ty 0..7
  #pragma unroll
  for (int i = 0; i < 4; ++i)
    t[ty + i * 8][tx] = src[(size_t)(k0 + ty + i * 8) * N + n0 + tx];
  __syncthreads();
  #pragma unroll
  for (int i = 0; i < 4; ++i)
    dst[(size_t)(n0 + ty + i * 8) * K + k0 + tx] = f2bf(t[tx][ty + i * 8]);
}

// ---------------- embedding + LN -------------------------------------------
__global__ __launch_bounds__(256)
void embed_ln_kernel(const int* __restrict__ ids, const float* __restrict__ we,
                     const float* __restrict__ pe, const float* __restrict__ te,
                     const float* __restrict__ lnp, float* __restrict__ x,
                     u16* __restrict__ xb) {
  int row = blockIdx.x;
  int s = row & (Ss - 1);
  int id = ids[row];
  int tid = threadIdx.x;
  float v[3]; float sm = 0.f, s2 = 0.f;
  #pragma unroll
  for (int i = 0; i < 3; ++i) {
    int c = tid + i * 256;
    float t = we[(size_t)id * Dd + c] + pe[(size_t)(s + 2) * Dd + c] + te[c];
    v[i] = t; sm += t; s2 += t * t;
  }
  __shared__ float r1[256], r2[256];
  r1[tid] = sm; r2[tid] = s2; __syncthreads();
  for (int o = 128; o; o >>= 1) {
    if (tid < o) { r1[tid] += r1[tid + o]; r2[tid] += r2[tid + o]; }
    __syncthreads();
  }
  float mean = r1[0] * (1.f / 768.f);
  float var  = r2[0] * (1.f / 768.f) - mean * mean;
  float rs = rsqrtf(var + 1e-5f);
  #pragma unroll
  for (int i = 0; i < 3; ++i) {
    int c = tid + i * 256;
    float o = (v[i] - mean) * rs * lnp[c] + lnp[Dd + c];
    x[(size_t)row * Dd + c] = o;
    xb[(size_t)row * Dd + c] = f2bf(o);
  }
}

// ---------------- residual(3-input) + LN ------------------------------------
__global__ __launch_bounds__(256)
void add_ln3_kernel(const float* __restrict__ xin, const float* __restrict__ y0,
                    const float* __restrict__ y1, const float* __restrict__ lnp,
                    float* __restrict__ xout, u16* __restrict__ xbout) {
  int row = blockIdx.x;
  int tid = threadIdx.x;
  float v[3]; float sm = 0.f, s2 = 0.f;
  #pragma unroll
  for (int i = 0; i < 3; ++i) {
    int c = tid + i * 256;
    size_t idx = (size_t)row * Dd + c;
    float t = xin[idx] + y0[idx] + y1[idx];
    v[i] = t; sm += t; s2 += t * t;
  }
  __shared__ float r1[256], r2[256];
  r1[tid] = sm; r2[tid] = s2; __syncthreads();
  for (int o = 128; o; o >>= 1) {
    if (tid < o) { r1[tid] += r1[tid + o]; r2[tid] += r2[tid + o]; }
    __syncthreads();
  }
  float mean = r1[0] * (1.f / 768.f);
  float var  = r2[0] * (1.f / 768.f) - mean * mean;
  float rs = rsqrtf(var + 1e-5f);
  #pragma unroll
  for (int i = 0; i < 3; ++i) {
    int c = tid + i * 256;
    float o = (v[i] - mean) * rs * lnp[c] + lnp[Dd + c];
    xout[(size_t)row * Dd + c] = o;
    xbout[(size_t)row * Dd + c] = f2bf(o);
  }
}

// ---------------- GEMM2: glds-staged dbuf 128x128, split-K capable ----------
// Ks = row stride of A/Bt (full K); Kl = K-extent per z-slice; koff = z*Kl.
// MODE 0: fp32 [M][N] (+bias on z==0); z==1 writes outf2
// MODE 1: bf16 [M][N], exact gelu
// MODE 2: fused QKV+gKV: N=3840; secs: q pk / k pad / v^T pad / gk pk / gv^T
// MODE 4: bf16 [M][N] * scale
template <int MODE>
__global__ __launch_bounds__(256)
void gemm2_kernel(const u16* __restrict__ A, const u16* __restrict__ Bt,
                  const float* __restrict__ bias, float* __restrict__ outf,
                  float* __restrict__ outf2,
                  u16* __restrict__ o0, u16* __restrict__ o1, u16* __restrict__ o2,
                  u16* __restrict__ o3, u16* __restrict__ o4,
                  int N, int Ks, int Kl, float scale) {
  __shared__ u16 la[2][128 * 32], lb[2][128 * 32];
  int tid = threadIdx.x;
  int wave = tid >> 6, lane = tid & 63;
  int wr = wave >> 1, wc = wave & 1;
  int lg = lane >> 4, lc = lane & 15;
  int row0 = blockIdx.y * 128, col0 = blockIdx.x * 128;
  int koff = blockIdx.z * Kl;

  const u16* Ag = A + (size_t)(row0 + wave * 32 + (lane >> 2)) * Ks + (lane & 3) * 8 + koff;
  const u16* Bg = Bt + (size_t)(col0 + wave * 32 + (lane >> 2)) * Ks + (lane & 3) * 8 + koff;
  int wofs = wave * 1024;

  f32x4 acc[4][4];
  #pragma unroll
  for (int m = 0; m < 4; ++m)
    #pragma unroll
    for (int n = 0; n < 4; ++n) acc[m][n] = (f32x4){0.f, 0.f, 0.f, 0.f};

  // prologue: stage K-tile 0 into buf 0
  glds16(Ag, la[0] + wofs);
  glds16(Ag + (size_t)16 * Ks, la[0] + wofs + 512);
  glds16(Bg, lb[0] + wofs);
  glds16(Bg + (size_t)16 * Ks, lb[0] + wofs + 512);
  __syncthreads();

  int nk = Kl >> 5;
  for (int t = 0; t < nk; ++t) {
    int cur = t & 1;
    if (t + 1 < nk) {  // prefetch next tile into other buffer (flies under MFMA)
      int k1 = (t + 1) << 5;
      glds16(Ag + k1, la[cur ^ 1] + wofs);
      glds16(Ag + (size_t)16 * Ks + k1, la[cur ^ 1] + wofs + 512);
      glds16(Bg + k1, lb[cur ^ 1] + wofs);
      glds16(Bg + (size_t)16 * Ks + k1, lb[cur ^ 1] + wofs + 512);
    }
    bv8 af[4], bf_[4];
    #pragma unroll
    for (int m = 0; m < 4; ++m)
      af[m] = *reinterpret_cast<const bv8*>(la[cur] + (wr * 64 + m * 16 + lc) * 32 + lg * 8);
    #pragma unroll
    for (int n = 0; n < 4; ++n)
      bf_[n] = *reinterpret_cast<const bv8*>(lb[cur] + (wc * 64 + n * 16 + lc) * 32 + lg * 8);
    __builtin_amdgcn_s_setprio(1);
    #pragma unroll
    for (int m = 0; m < 4; ++m)
      #pragma unroll
      for (int n = 0; n < 4; ++n)
        acc[m][n] = __builtin_amdgcn_mfma_f32_16x16x32_bf16(af[m], bf_[n], acc[m][n], 0, 0, 0);
    __builtin_amdgcn_s_setprio(0);
    __syncthreads();  // drains prefetch (vmcnt0) + joins waves
  }

  #pragma unroll
  for (int m = 0; m < 4; ++m) {
    int grow0 = row0 + wr * 64 + m * 16 + lg * 4;
    #pragma unroll
    for (int n = 0; n < 4; ++n) {
      int gcol = col0 + wc * 64 + n * 16 + lc;
      float bvl = bias[gcol];
      if (MODE == 0) {
        float* od = blockIdx.z ? outf2 : outf;
        float badd = blockIdx.z ? 0.f : bvl;
        #pragma unroll
        for (int r = 0; r < 4; ++r)
          od[(size_t)(grow0 + r) * N + gcol] = acc[m][n][r] + badd;
      } else if (MODE == 1) {
        #pragma unroll
        for (int r = 0; r < 4; ++r) {
          float v = acc[m][n][r] + bvl;
          v = 0.5f * v * (1.0f + erff(v * 0.70710678118654752f));
          o0[(size_t)(grow0 + r) * N + gcol] = f2bf(v);
        }
      } else if (MODE == 4) {
        #pragma unroll
        for (int r = 0; r < 4; ++r)
          o0[(size_t)(grow0 + r) * N + gcol] = f2bf((acc[m][n][r] + bvl) * scale);
      } else if (MODE == 2) {
        int sec = (col0 >> 7) / 6;        // 0..4, block-uniform
        int colr = gcol - sec * 768;
        int hh = colr >> 6, d = colr & 63;
        int bb = grow0 >> 12, s = grow0 & (Ss - 1);
        size_t bhh = (size_t)(bb * Hh + hh);
        if (sec == 0) {
          #pragma unroll
          for (int r = 0; r < 4; ++r)
            o0[(bhh * Ss + s + r) * 64 + d] = f2bf((acc[m][n][r] + bvl) * scale);
        } else if (sec == 1) {
          #pragma unroll
          for (int r = 0; r < 4; ++r)
            o1[(bhh * SPAD + PADL + s + r) * 64 + d] = f2bf(acc[m][n][r] + bvl);
        } else if (sec == 2) {
          sv4 pk;
          #pragma unroll
          for (int r = 0; r < 4; ++r) pk[r] = (short)f2bf(acc[m][n][r] + bvl);
          *reinterpret_cast<sv4*>(o2 + (bhh * 64 + d) * SPAD + PADL + s) = pk;
        } else if (sec == 3) {
          #pragma unroll
          for (int r = 0; r < 4; ++r)
            o3[(bhh * Ss + s + r) * 64 + d] = f2bf(acc[m][n][r] + bvl);
        } else {
          sv4 pk;
          #pragma unroll
          for (int r = 0; r < 4; ++r) pk[r] = (short)f2bf(acc[m][n][r] + bvl);
          *reinterpret_cast<sv4*>(o4 + (bhh * 64 + d) * Ss + s) = pk;
        }
      }
    }
  }
}

// ---------------- gathers ---------------------------------------------------
__global__ __launch_bounds__(256)
void gather_glob_kernel(const u16* __restrict__ kpk, const u16* __restrict__ vtpk,
                        const int* __restrict__ gpos, u16* __restrict__ kg,
                        u16* __restrict__ vgt) {
  int bh = blockIdx.x;
  int b = bh / Hh;
  int tid = threadIdx.x;
  for (int idx = tid; idx < 64 * 64; idx += 256) {
    int g = idx >> 6, d = idx & 63;
    u16 kv = 0, vv = 0;
    if (g < Gg) {
      int p = gpos[b * Gg + g];
      kv = kpk[((size_t)bh * SPAD + PADL + p) * 64 + d];
      vv = vtpk[((size_t)bh * 64 + d) * SPAD + PADL + p];
    }
    kg[(size_t)bh * 4096 + idx] = kv;
    vgt[((size_t)bh * 64 + d) * 64 + g] = vv;
  }
}

__global__ __launch_bounds__(256)
void gather_xg_kernel(const u16* __restrict__ xb, const int* __restrict__ gpos,
                      u16* __restrict__ xg) {
  int rg = blockIdx.x;  // b*G+g
  int b = rg / Gg;
  int p = gpos[rg];
  int tid = threadIdx.x;
  for (int c = tid; c < Dd; c += 256)
    xg[(size_t)rg * Dd + c] = xb[((size_t)b * Ss + p) * Dd + c];
}

// ---------------- local (sliding window + global-key) attention -------------
// 4 waves/block, 64 queries/block; XCD swizzle; 64-key steps (step 0 = global
// keys). Pipeline: V loads at step top; K frags reloaded IN PLACE after QK^T
// (hidden under softmax+PV) -> single kc buffer, lower VGPR.
#define LOCAL_NB (Bb * Hh * (Ss / 64))   // 1536 blocks, %8 == 0
__global__ __launch_bounds__(256)
void attn_local_kernel(const u16* __restrict__ qpk, const u16* __restrict__ kpk,
                       const u16* __restrict__ vtpk, const u16* __restrict__ kg,
                       const u16* __restrict__ vgt, const int* __restrict__ amask,
                       u16* __restrict__ ctx) {
  __shared__ u16 Plds[4][16 * PSTR];
  int bid = blockIdx.x;
  int swz = (bid & 7) * (LOCAL_NB / 8) + (bid >> 3);
  int qb = swz & 63;
  int bh = swz >> 6;
  int b = bh / Hh;
  int h = bh - b * Hh;
  int wv = threadIdx.x >> 6;
  int q0 = qb * 64 + wv * 16;
  int lane = threadIdx.x & 63;
  int lg = lane >> 4, lc = lane & 15;
  int lg4 = lg * 4;
  int q = q0 + lc;   // query owned by this lane for softmax state

  const u16* qbase = qpk + (((size_t)bh) * Ss + q0) * 64;
  bv8 aq0 = *reinterpret_cast<const bv8*>(qbase + (size_t)lc * 64 + lg * 8);
  bv8 aq1 = *reinterpret_cast<const bv8*>(qbase + (size_t)lc * 64 + 32 + lg * 8);

  f32x4 o[4];
  #pragma unroll
  for (int i = 0; i < 4; ++i) o[i] = (f32x4){0.f, 0.f, 0.f, 0.f};
  float mrun = -1e30f, lrun = 0.f;

  const u16* kgb = kg + ((size_t)bh) * 64 * 64;
  const u16* vgb = vgt + ((size_t)bh) * 64 * 64;
  const u16* kb = kpk + ((size_t)bh) * SPAD * 64;
  const u16* vb = vtpk + ((size_t)bh) * 64 * SPAD;
  const int* amb = amask + b * Ss;
  u16* P = &Plds[wv][0];

  // preload K frags for step 0 (global keys)
  bv8 kc[8];
  #pragma unroll
  for (int j = 0; j < 4; ++j) {
    const u16* kr = kgb + (size_t)(j * 16 + lc) * 64;
    kc[2 * j]     = *reinterpret_cast<const bv8*>(kr + lg * 8);
    kc[2 * j + 1] = *reinterpret_cast<const bv8*>(kr + 32 + lg * 8);
  }
  // prefetch amask word for step 1
  int amvN;
  { int ni = min(max(q0 - 256 + lane, 0), Ss - 1); amvN = amb[ni]; }

  for (int step = 0; step < 10; ++step) {
    bool isg = (step == 0);
    int ks = isg ? 0 : (q0 - 256 + (step - 1) * 64);
    int amvC = amvN;
    if (step < 9) { int ni = min(max(q0 - 256 + step * 64 + lane, 0), Ss - 1); amvN = amb[ni]; }

    // issue V loads for this step (consumed after softmax)
    bv8 vf[8];
    #pragma unroll
    for (int j2 = 0; j2 < 2; ++j2)
      #pragma unroll
      for (int nt = 0; nt < 4; ++nt) {
        const u16* vr = isg ? (vgb + (size_t)(nt * 16 + lc) * 64 + j2 * 32)
                            : (vb + (size_t)(nt * 16 + lc) * SPAD + PADL + ks + j2 * 32);
        vf[j2 * 4 + nt] = *reinterpret_cast<const bv8*>(vr + lg * 8);
      }
    // key-validity mask
    unsigned long long kmask;
    if (isg) {
      kmask = (1ull << Gg) - 1;
    } else {
      int kidx = ks + lane;
      kmask = __ballot((kidx >= 0) && (kidx < Ss) && (amvC > 0));
    }
    // QK^T (swapped operands): sc[j] = scores for keys ks+j*16+lg4..+3, query lc
    f32x4 sc[4];
    __builtin_amdgcn_s_setprio(1);
    #pragma unroll
    for (int j = 0; j < 4; ++j) {
      f32x4 z = (f32x4){0.f, 0.f, 0.f, 0.f};
      sc[j] = __builtin_amdgcn_mfma_f32_16x16x32_bf16(kc[2 * j], aq0, z, 0, 0, 0);
      sc[j] = __builtin_amdgcn_mfma_f32_16x16x32_bf16(kc[2 * j + 1], aq1, sc[j], 0, 0, 0);
    }
    __builtin_amdgcn_s_setprio(0);
    // reload kc IN PLACE for next step (WAR on QK^T; hides under softmax+PV)
    if (step < 9) {
      int ksn = q0 - 256 + step * 64;
      #pragma unroll
      for (int j = 0; j < 4; ++j) {
        const u16* kr = kb + (size_t)(PADL + ksn + j * 16 + lc) * 64;
        kc[2 * j]     = *reinterpret_cast<const bv8*>(kr + lg * 8);
        kc[2 * j + 1] = *reinterpret_cast<const bv8*>(kr + 32 + lg * 8);
      }
    }
    // masking: steps 2..8 with full kmask are band-safe for all 16 queries
    float mloc = -1e30f;
    bool fast = (!isg) && (step >= 2) && (step <= 8) && (kmask == ~0ull);
    if (fast) {
      #pragma unroll
      for (int j = 0; j < 4; ++j)
        #pragma unroll
        for (int r = 0; r < 4; ++r) mloc = fmaxf(mloc, sc[j][r]);
    } else {
      #pragma unroll
      for (int j = 0; j < 4; ++j)
        #pragma unroll
        for (int r = 0; r < 4; ++r) {
          int kk = ks + j * 16 + lg4 + r;
          bool ok = (kmask >> (j * 16 + lg4 + r)) & 1;
          if (!isg) ok = ok && ((unsigned)(kk - q + 256) <= 512u);
          sc[j][r] = ok ? sc[j][r] : -1e9f;
          mloc = fmaxf(mloc, sc[j][r]);
        }
    }
    mloc = fmaxf(mloc, __shfl_xor(mloc, 16));
    mloc = fmaxf(mloc, __shfl_xor(mloc, 32));
    if (__any(mloc > mrun)) {
      float nm = fmaxf(mrun, mloc);
      float scal = __expf(mrun - nm);
      mrun = nm;
      lrun *= scal;
      #pragma unroll
      for (int r = 0; r < 4; ++r) {
        float sr = __shfl(scal, lg4 + r);  // scal of query lg4+r
        #pragma unroll
        for (int nt = 0; nt < 4; ++nt) o[nt][r] *= sr;
      }
    }
    float psum = 0.f;
    #pragma unroll
    for (int j = 0; j < 4; ++j) {
      sv4 pk;
      #pragma unroll
      for (int r = 0; r < 4; ++r) {
        float p = __expf(sc[j][r] - mrun);
        psum += p;
        pk[r] = (short)f2bf(p);
      }
      *reinterpret_cast<sv4*>(P + lc * PSTR + j * 16 + lg4) = pk;
    }
    psum += __shfl_xor(psum, 16);
    psum += __shfl_xor(psum, 32);
    lrun += psum;
    // PV with prefetched V frags
    __builtin_amdgcn_s_setprio(1);
    #pragma unroll
    for (int j2 = 0; j2 < 2; ++j2) {
      bv8 ap = *reinterpret_cast<const bv8*>(P + lc * PSTR + j2 * 32 + lg * 8);
      #pragma unroll
      for (int nt = 0; nt < 4; ++nt)
        o[nt] = __builtin_amdgcn_mfma_f32_16x16x32_bf16(ap, vf[j2 * 4 + nt], o[nt], 0, 0, 0);
    }
    __builtin_amdgcn_s_setprio(0);
  }
  float inv = 1.0f / lrun;
  #pragma unroll
  for (int r = 0; r < 4; ++r) {
    float invr = __shfl(inv, lg4 + r);
    size_t rowoff = ((size_t)b * Ss + q0 + lg4 + r) * Dd + h * 64;
    #pragma unroll
    for (int nt = 0; nt < 4; ++nt)
      ctx[rowoff + nt * 16 + lc] = f2bf(o[nt][r] * invr);
  }
}

// ---------------- global-query attention: chunked flash MFMA ----------------
__global__ __launch_bounds__(192)
void attn_globalq_kernel(const u16* __restrict__ qgb, const u16* __restrict__ kgf,
                         const u16* __restrict__ vgt, const int* __restrict__ amask,
                         float* __restrict__ part) {
  __shared__ u16 Plds[3][16 * 32];
  int blk = blockIdx.x;
  int ch = blk & (NCH - 1);
  int bh = blk / NCH;
  int b = bh / Hh, h = bh - b * Hh;
  int wv = threadIdx.x >> 6;  // q-tile 0..2
  int lane = threadIdx.x & 63;
  int lg = lane >> 4, lc = lane & 15;

  int qrow = wv * 16 + lc;
  bv8 aq0 = (bv8)0, aq1 = (bv8)0;
  if (qrow < Gg) {
    const u16* qr = qgb + (size_t)(b * Gg + qrow) * Dd + h * 64;
    aq0 = *reinterpret_cast<const bv8*>(qr + lg * 8);
    aq1 = *reinterpret_cast<const bv8*>(qr + 32 + lg * 8);
  }

  f32x4 o[4];
  float mrun[4], lrun[4];
  #pragma unroll
  for (int i = 0; i < 4; ++i) { o[i] = (f32x4){0.f,0.f,0.f,0.f}; mrun[i] = -1e30f; lrun[i] = 0.f; }

  const u16* kb = kgf + ((size_t)bh) * Ss * 64;
  const u16* vb = vgt + ((size_t)bh) * 64 * Ss;
  const int* amb = amask + b * Ss;
  int ks0 = ch * (Ss / NCH);

  for (int st = 0; st < (Ss / NCH) / 32; ++st) {
    int ks = ks0 + st * 32;
    f32x4 sc0, sc1;
    {
      const u16* kr0 = kb + (size_t)(ks + lc) * 64;
      const u16* kr1 = kr0 + 16 * 64;
      bv8 b00 = *reinterpret_cast<const bv8*>(kr0 + lg * 8);
      bv8 b01 = *reinterpret_cast<const bv8*>(kr0 + 32 + lg * 8);
      bv8 b10 = *reinterpret_cast<const bv8*>(kr1 + lg * 8);
      bv8 b11 = *reinterpret_cast<const bv8*>(kr1 + 32 + lg * 8);
      f32x4 z = (f32x4){0.f,0.f,0.f,0.f};
      sc0 = __builtin_amdgcn_mfma_f32_16x16x32_bf16(aq0, b00, z, 0, 0, 0);
      sc0 = __builtin_amdgcn_mfma_f32_16x16x32_bf16(aq1, b01, sc0, 0, 0, 0);
      sc1 = __builtin_amdgcn_mfma_f32_16x16x32_bf16(aq0, b10, z, 0, 0, 0);
      sc1 = __builtin_amdgcn_mfma_f32_16x16x32_bf16(aq1, b11, sc1, 0, 0, 0);
    }
    bool v0 = amb[ks + lc] > 0;
    bool v1 = amb[ks + 16 + lc] > 0;
    #pragma unroll
    for (int r = 0; r < 4; ++r) {
      float s0 = v0 ? sc0[r] : -1e9f;
      float s1 = v1 ? sc1[r] : -1e9f;
      float rm = fmaxf(s0, s1);
      #pragma unroll
      for (int off = 1; off < 16; off <<= 1) rm = fmaxf(rm, __shfl_xor(rm, off));
      float nm = fmaxf(mrun[r], rm);
      float scal = __expf(mrun[r] - nm);
      float p0 = __expf(s0 - nm);
      float p1 = __expf(s1 - nm);
      float ps = p0 + p1;
      #pragma unroll
      for (int off = 1; off < 16; off <<= 1) ps += __shfl_xor(ps, off);
      lrun[r] = lrun[r] * scal + ps;
      mrun[r] = nm;
      #pragma unroll
      for (int nt = 0; nt < 4; ++nt) o[nt][r] *= scal;
      int prow = lg * 4 + r;
      Plds[wv][prow * 32 + lc] = f2bf(p0);
      Plds[wv][prow * 32 + 16 + lc] = f2bf(p1);
    }
    bv8 ap = *reinterpret_cast<const bv8*>(&Plds[wv][lc * 32 + lg * 8]);
    #pragma unroll
    for (int nt = 0; nt < 4; ++nt) {
      const u16* vr = vb + (size_t)(nt * 16 + lc) * Ss + ks;
      bv8 bvv = *reinterpret_cast<const bv8*>(vr + lg * 8);
      o[nt] = __builtin_amdgcn_mfma_f32_16x16x32_bf16(ap, bvv, o[nt], 0, 0, 0);
    }
  }

  float* pb = part + ((size_t)(bh * 3 + wv) * NCH + ch) * PARTF;
  #pragma unroll
  for (int r = 0; r < 4; ++r) {
    int row = lg * 4 + r;
    #pragma unroll
    for (int nt = 0; nt < 4; ++nt)
      pb[row * 64 + nt * 16 + lc] = o[nt][r];
    if (lc == 0) {
      pb[1024 + row] = mrun[r];
      pb[1040 + row] = lrun[r];
    }
  }
}

// merge NCH chunk-partials and scatter into ctx rows at gpos
__global__ __launch_bounds__(256)
void attn_gmerge_kernel(const float* __restrict__ part, const int* __restrict__ gpos,
                        u16* __restrict__ ctx) {
  __shared__ float wgt[Gg][NCH];
  __shared__ float sinvl[Gg];
  int bh = blockIdx.x;
  int b = bh / Hh, h = bh - b * Hh;
  int tid = threadIdx.x;
  if (tid < Gg) {
    int qt = tid >> 4, rr = tid & 15;
    const float* pb = part + ((size_t)(bh * 3 + qt) * NCH) * PARTF;
    float mx = -1e30f;
    for (int c = 0; c < NCH; ++c) mx = fmaxf(mx, pb[c * PARTF + 1024 + rr]);
    float l = 0.f;
    for (int c = 0; c < NCH; ++c) {
      float w = __expf(pb[c * PARTF + 1024 + rr] - mx);
      wgt[tid][c] = w;
      l += w * pb[c * PARTF + 1040 + rr];
    }
    sinvl[tid] = 1.0f / l;
  }
  __syncthreads();
  for (int e = tid; e < Gg * 64; e += 256) {
    int row = e >> 6, d = e & 63;
    int qt = row >> 4, rr = row & 15;
    const float* pb = part + ((size_t)(bh * 3 + qt) * NCH) * PARTF + rr * 64 + d;
    float acc = 0.f;
    #pragma unroll
    for (int c = 0; c < NCH; ++c) acc += wgt[row][c] * pb[c * PARTF];
    int pos = gpos[b * Gg + row];
    ctx[((size_t)b * Ss + pos) * Dd + h * 64 + d] = f2bf(acc * sinvl[row]);
  }
}

// ---------------- classifier ------------------------------------------------
__global__ __launch_bounds__(64)
void cls_kernel(const float* __restrict__ x, const float* __restrict__ W,
                const float* __restrict__ bias, const int* __restrict__ gpos,
                float* __restrict__ out) {
  int r = blockIdx.x;  // b*32 + i
  int b = r >> 5, i = r & 31;
  int pos = gpos[b * Gg + 1 + i];
  int lane = threadIdx.x;
  const float* xr = x + ((size_t)b * Ss + pos) * Dd;
  float acc[NCLSn] = {0.f, 0.f, 0.f, 0.f, 0.f};
  for (int k = lane; k < Dd; k += 64) {
    float xv = xr[k];
    #pragma unroll
    for (int c = 0; c < NCLSn; ++c) acc[c] += xv * W[c * Dd + k];
  }
  #pragma unroll
  for (int c = 0; c < NCLSn; ++c) {
    #pragma unroll
    for (int off = 1; off < 64; off <<= 1) acc[c] += __shfl_xor(acc[c], off);
  }
  if (lane == 0) {
    #pragma unroll
    for (int c = 0; c < NCLSn; ++c) out[r * NCLSn + c] = acc[c] + bias[c];
  }
}

// ---------------------------------------------------------------------------
extern "C" void kernel_launch(void* const* d_in, const int* in_sizes, int n_in,
                              void* d_out, int out_size, void* d_ws, size_t ws_size,
                              hipStream_t stream) {
  const int* ids     = (const int*)d_in[0];
  const int* amask   = (const int*)d_in[1];
  const float* we    = (const float*)d_in[2];
  const float* pe    = (const float*)d_in[3];
  const float* te    = (const float*)d_in[4];
  const float* embln = (const float*)d_in[5];
  const float* Wqkv  = (const float*)d_in[6];
  const float* bqkv  = (const float*)d_in[7];
  const float* Wqkvg = (const float*)d_in[8];
  const float* bqkvg = (const float*)d_in[9];
  const float* Wo    = (const float*)d_in[10];
  const float* bo    = (const float*)d_in[11];
  const float* ln1   = (const float*)d_in[12];
  const float* Wff1  = (const float*)d_in[13];
  const float* bff1  = (const float*)d_in[14];
  const float* Wff2  = (const float*)d_in[15];
  const float* bff2  = (const float*)d_in[16];
  const float* ln2   = (const float*)d_in[17];
  const float* clsW  = (const float*)d_in[18];
  const float* clsb  = (const float*)d_in[19];
  float* out = (float*)d_out;

  char* ws = (char*)d_ws;
  size_t off = 0;
  auto alloc = [&](size_t bytes) { size_t o = off; off += (bytes + 255) & ~(size_t)255; return o; };

  const size_t DD = (size_t)Dd * Dd;        // 589824
  const size_t DF = (size_t)Dd * 4 * Dd;    // 2359296
  const size_t WL = 7 * DD + 2 * DF;        // elems per layer
  // Wb layout per layer: [q,k,v, gk,gv, gq, wo, ff1, ff2]

  size_t o_cnt  = alloc(Bb * 4);
  size_t o_list = alloc(Bb * 64 * 4);
  size_t o_gpos = alloc(Bb * Gg * 4);
  size_t o_bias = alloc((size_t)Ll * 3840 * 4);
  size_t o_w    = alloc(WL * Ll * 2);
  size_t o_x    = alloc((size_t)Bb * Ss * Dd * 4);
  size_t o_xb   = alloc((size_t)Bb * Ss * Dd * 2);
  // kgf/vgf first: their 25.17 MB doubles as split-K buffer B (dead by Wo/FF2)
  size_t o_kgf  = alloc((size_t)Bb * Hh * Ss * 64 * 2);
  size_t o_vgf  = alloc((size_t)Bb * Hh * Ss * 64 * 2);
  size_t o_accB = o_kgf;  // 2*12.58 MB = exactly 8192*768*4 bytes
  size_t o_qpk  = alloc((size_t)Bb * Hh * Ss * 64 * 2);
  size_t o_kpk  = alloc((size_t)Bb * Hh * SPAD * 64 * 2);
  size_t o_vtpk = alloc((size_t)Bb * Hh * 64 * SPAD * 2);
  size_t o_kg   = alloc((size_t)Bb * Hh * 64 * 64 * 2);
  size_t o_vgt  = alloc((size_t)Bb * Hh * 64 * 64 * 2);
  size_t o_xg   = alloc((size_t)128 * Dd * 2);
  size_t o_qg   = alloc((size_t)128 * Dd * 2);
  size_t o_part = alloc((size_t)Bb * Hh * 3 * NCH * PARTF * 4);
  size_t o_f1b  = o_qpk;  // FFN hidden aliases the (dead-by-then) attention buffers
  {
    size_t f1b_bytes = (size_t)Bb * Ss * 4 * Dd * 2;
    if (off - o_qpk < f1b_bytes) off = o_qpk + ((f1b_bytes + 255) & ~(size_t)255);
  }
  size_t o_ctx = alloc((size_t)Bb * Ss * Dd * 2);
  size_t o_acc = alloc((size_t)Bb * Ss * Dd * 4);
  if (ws_size < off) return;  // workspace too small -> fail visibly

  u16* Wb = (u16*)(ws + o_w);
  int* gposp = (int*)(ws + o_gpos);
  float* accA = (float*)(ws + o_acc);
  float* accB = (float*)(ws + o_accB);

  (void)hipMemsetAsync(ws + o_cnt, 0, Bb * 4, stream);
  // zero padded K / V^T so first-call pads are finite (later calls: finite stale bf16)
  (void)hipMemsetAsync(ws + o_kpk, 0, (size_t)Bb * Hh * SPAD * 64 * 2, stream);
  (void)hipMemsetAsync(ws + o_vtpk, 0, (size_t)Bb * Hh * 64 * SPAD * 2, stream);
  (void)hipMemsetAsync(ws + o_xg, 0, (size_t)128 * Dd * 2, stream);

  // concat bias per layer: [bqkv(3x768) | bqkvg_k(768) | bqkvg_v(768)]
  for (int l = 0; l < Ll; ++l) {
    (void)hipMemcpyAsync(ws + o_bias + (size_t)l * 3840 * 4, bqkv + (size_t)l * 3 * Dd,
                         3 * Dd * 4, hipMemcpyDeviceToDevice, stream);
    (void)hipMemcpyAsync(ws + o_bias + (size_t)l * 3840 * 4 + 3 * Dd * 4,
                         bqkvg + (size_t)(l * 3 + 1) * Dd,
                         2 * Dd * 4, hipMemcpyDeviceToDevice, stream);
  }

  sep_find_kernel<<<(Bb * Ss + 255) / 256, 256, 0, stream>>>(ids, (int*)(ws + o_cnt), (int*)(ws + o_list));
  sep_sort_kernel<<<Bb, 64, 0, stream>>>((int*)(ws + o_cnt), (int*)(ws + o_list), gposp);

  // weight conversions (batched over z); Wb layout [q,k,v,gk,gv,gq,wo,ff1,ff2]
  wconv_kernel<<<dim3(24, 24, 6), 256, 0, stream>>>(Wqkv,       Wb,          Dd, Dd, 3, 3, (long)DD, (long)WL);
  wconv_kernel<<<dim3(24, 24, 2), 256, 0, stream>>>(Wqkvg + DD,     Wb + 3 * DD, Dd, Dd, 1, 3, 0L, (long)WL);  // gk
  wconv_kernel<<<dim3(24, 24, 2), 256, 0, stream>>>(Wqkvg + 2 * DD, Wb + 4 * DD, Dd, Dd, 1, 3, 0L, (long)WL);  // gv
  wconv_kernel<<<dim3(24, 24, 2), 256, 0, stream>>>(Wqkvg,          Wb + 5 * DD, Dd, Dd, 1, 3, 0L, (long)WL);  // gq
  wconv_kernel<<<dim3(24, 24, 2), 256, 0, stream>>>(Wo,         Wb + 6 * DD, Dd, Dd, 1, 1, 0L, (long)WL);
  wconv_kernel<<<dim3(96, 24, 2), 256, 0, stream>>>(Wff1,       Wb + 7 * DD, Dd, 4 * Dd, 1, 1, 0L, (long)WL);
  wconv_kernel<<<dim3(24, 96, 2), 256, 0, stream>>>(Wff2,       Wb + 7 * DD + DF, 4 * Dd, Dd, 1, 1, 0L, (long)WL);

  embed_ln_kernel<<<Bb * Ss, 256, 0, stream>>>(ids, we, pe, te, embln, (float*)(ws + o_x), (u16*)(ws + o_xb));

  for (int l = 0; l < Ll; ++l) {
    size_t wb = (size_t)l * WL;
    u16* xb = (u16*)(ws + o_xb);
    // fused QKV + global K/V projection (N=3840, 5 sections)
    gemm2_kernel<2><<<dim3(30, 64), 256, 0, stream>>>(xb, Wb + wb, (float*)(ws + o_bias) + (size_t)l * 3840,
        nullptr, nullptr,
        (u16*)(ws + o_qpk), (u16*)(ws + o_kpk), (u16*)(ws + o_vtpk),
        (u16*)(ws + o_kgf), (u16*)(ws + o_vgf), 3840, Dd, Dd, 0.125f);
    gather_glob_kernel<<<Bb * Hh, 256, 0, stream>>>((u16*)(ws + o_kpk), (u16*)(ws + o_vtpk), gposp, (u16*)(ws + o_kg), (u16*)(ws + o_vgt));
    gather_xg_kernel<<<Bb * Gg, 256, 0, stream>>>(xb, gposp, (u16*)(ws + o_xg));
    // global q projection (M=128 padded rows)
    gemm2_kernel<4><<<dim3(6, 1), 256, 0, stream>>>((u16*)(ws + o_xg), Wb + wb + 5 * DD, bqkvg + (size_t)l * 3 * Dd,
        nullptr, nullptr, (u16*)(ws + o_qg), nullptr, nullptr, nullptr, nullptr, Dd, Dd, Dd, 0.125f);
    // attention
    attn_local_kernel<<<LOCAL_NB, 256, 0, stream>>>((u16*)(ws + o_qpk), (u16*)(ws + o_kpk), (u16*)(ws + o_vtpk), (u16*)(ws + o_kg), (u16*)(ws + o_vgt), amask, (u16*)(ws + o_ctx));
    attn_globalq_kernel<<<Bb * Hh * NCH, 192, 0, stream>>>((u16*)(ws + o_qg), (u16*)(ws + o_kgf), (u16*)(ws + o_vgf), amask, (float*)(ws + o_part));
    attn_gmerge_kernel<<<Bb * Hh, 256, 0, stream>>>((float*)(ws + o_part), gposp, (u16*)(ws + o_ctx));
    // output projection (split-K x2) + LN   [kgf/vgf dead from here on]
    gemm2_kernel<0><<<dim3(6, 64, 2), 256, 0, stream>>>((u16*)(ws + o_ctx), Wb + wb + 6 * DD, bo + (size_t)l * Dd, accA, accB,
        nullptr, nullptr, nullptr, nullptr, nullptr, Dd, Dd, Dd / 2, 1.0f);
    add_ln3_kernel<<<Bb * Ss, 256, 0, stream>>>((float*)(ws + o_x), accA, accB, ln1 + (size_t)l * 2 * Dd, (float*)(ws + o_x), xb);
    // FFN
    gemm2_kernel<1><<<dim3(24, 64), 256, 0, stream>>>(xb, Wb + wb + 7 * DD, bff1 + (size_t)l * 4 * Dd, nullptr, nullptr,
        (u16*)(ws + o_f1b), nullptr, nullptr, nullptr, nullptr, 4 * Dd, Dd, Dd, 1.0f);
    gemm2_kernel<0><<<dim3(6, 64, 2), 256, 0, stream>>>((u16*)(ws + o_f1b), Wb + wb + 7 * DD + DF, bff2 + (size_t)l * Dd, accA, accB,
        nullptr, nullptr, nullptr, nullptr, nullptr, Dd, 4 * Dd, 2 * Dd, 1.0f);
    add_ln3_kernel<<<Bb * Ss, 256, 0, stream>>>((float*)(ws + o_x), accA, accB, ln2 + (size_t)l * 2 * Dd, (float*)(ws + o_x), xb);
  }

  cls_kernel<<<Bb * NSEPn, 64, 0, stream>>>((float*)(ws + o_x), clsW, clsb, gposp, out);
}